// Round 2
// baseline (2702.806 us; speedup 1.0000x reference)
//
#include <hip/hip_runtime.h>
#include <hip/hip_bf16.h>

typedef __hip_bfloat16 bf16;

// Problem constants
#define B_     8
#define N_     64
#define H_     512
#define HEADS_ 8
#define SP_    64
#define L_     4
static constexpr float INV_SCALE = 0.044194173824159216f; // 1/sqrt(512)

__device__ __forceinline__ float toF(float v) { return v; }
__device__ __forceinline__ float toF(bf16 v) { return __bfloat162float(v); }
__device__ __forceinline__ void storeC(float* p, float v) { *p = v; }
__device__ __forceinline__ void storeC(bf16* p, float v) { *p = __float2bfloat16(v); }

// ---------------------------------------------------------------- embeddings
__global__ void embed_x_kernel(const int* __restrict__ ids,
                               const float* __restrict__ emb,
                               float* __restrict__ x) {
    int idx = blockIdx.x * 256 + threadIdx.x;      // 8*64*512 = 262144
    int row = idx >> 9;                            // b*64+i
    int h   = idx & 511;
    x[idx] = emb[ids[row] * H_ + h];
}

__global__ void embed_bond_kernel(const int* __restrict__ adj,
                                  const float* __restrict__ emb,
                                  bf16* __restrict__ bond) {
    size_t idx = (size_t)blockIdx.x * 256 + threadIdx.x;  // 16.7M
    int pair = (int)(idx >> 9);
    int h    = (int)(idx & 511);
    bond[idx] = __float2bfloat16(emb[adj[pair] * H_ + h]);
}

// ---------------------------------------------------------------- LayerNorm
// one block (256 threads) per row of 512
__global__ void ln_kernel(const float* __restrict__ in, float* __restrict__ out) {
    int row = blockIdx.x;
    int tid = threadIdx.x;
    const float* r = in + (size_t)row * H_;
    float x0 = r[tid], x1 = r[tid + 256];
    float s = x0 + x1, sq = x0 * x0 + x1 * x1;
    #pragma unroll
    for (int off = 32; off; off >>= 1) {
        s  += __shfl_xor(s,  off);
        sq += __shfl_xor(sq, off);
    }
    __shared__ float ls[4], lq[4];
    int w = tid >> 6;
    if ((tid & 63) == 0) { ls[w] = s; lq[w] = sq; }
    __syncthreads();
    float S = ls[0] + ls[1] + ls[2] + ls[3];
    float Q = lq[0] + lq[1] + lq[2] + lq[3];
    float mean = S * (1.0f / H_);
    float var  = Q * (1.0f / H_) - mean * mean;
    float inv  = rsqrtf(var + 1e-5f);
    out[(size_t)row * H_ + tid]       = (x0 - mean) * inv;
    out[(size_t)row * H_ + tid + 256] = (x1 - mean) * inv;
}

// ---------------------------------------------------------------- GEMM
// C[M,N] = A[M,K] @ Bw[K,N]  (+R / relu per EPI); 64x64 tile, 256 thr, 4x4 micro
// EPI: 0 = none, 1 = add R, 2 = relu
template <typename AT, typename CT, int EPI>
__launch_bounds__(256)
__global__ void gemm64(const AT* __restrict__ A, const float* __restrict__ Bw,
                       CT* __restrict__ C, const float* __restrict__ R,
                       int M, int N, int K) {
    __shared__ float As[16][68];
    __shared__ float Bs[16][68];
    int tid = threadIdx.x;
    int tx = tid & 15, ty = tid >> 4;
    int bm = blockIdx.x * 64, bn = blockIdx.y * 64;
    float acc[4][4] = {};
    for (int k0 = 0; k0 < K; k0 += 16) {
        #pragma unroll
        for (int t = 0; t < 4; ++t) {
            int idx = tid + t * 256;           // 0..1023
            int m  = idx >> 4, kk = idx & 15;
            As[kk][m] = toF(A[(size_t)(bm + m) * K + k0 + kk]);
            int kb = idx >> 6, n = idx & 63;
            Bs[kb][n] = Bw[(size_t)(k0 + kb) * N + bn + n];
        }
        __syncthreads();
        #pragma unroll
        for (int kk = 0; kk < 16; ++kk) {
            float a[4], b[4];
            #pragma unroll
            for (int i = 0; i < 4; ++i) a[i] = As[kk][ty * 4 + i];
            #pragma unroll
            for (int j = 0; j < 4; ++j) b[j] = Bs[kk][tx + j * 16];
            #pragma unroll
            for (int i = 0; i < 4; ++i)
                #pragma unroll
                for (int j = 0; j < 4; ++j) acc[i][j] += a[i] * b[j];
        }
        __syncthreads();
    }
    #pragma unroll
    for (int i = 0; i < 4; ++i) {
        int row = bm + ty * 4 + i;
        #pragma unroll
        for (int j = 0; j < 4; ++j) {
            int col = bn + tx + j * 16;
            float v2 = acc[i][j];
            if (EPI == 1) v2 += R[(size_t)row * N + col];
            if (EPI == 2) v2 = fmaxf(v2, 0.0f);
            storeC(&C[(size_t)row * N + col], v2);
        }
    }
}

// ---------------------------------------------------------------- attention
// one 64-lane wave per (b, i, h): logits over j, softmax (mask adj==0), o
__global__ void attn_kernel(const float* __restrict__ q, const float* __restrict__ k,
                            const float* __restrict__ v, const bf16* __restrict__ ew,
                            const int* __restrict__ adj, float* __restrict__ o) {
    int bi = blockIdx.x;           // b*64 + i
    int b  = bi >> 6;
    int h  = blockIdx.y;
    int lane = threadIdx.x;        // 64
    __shared__ float qs[64], as[64];
    qs[lane] = q[(size_t)bi * H_ + h * 64 + lane];
    __syncthreads();

    int j = lane;
    const float* krow = k + ((size_t)(b * 64 + j)) * H_ + h * 64;
    const bf16*  wrow = ew + ((size_t)bi * 64 + j) * H_ + h * 64;
    float acc = 0.f;
    #pragma unroll 8
    for (int d = 0; d < 64; ++d)
        acc += qs[d] * (krow[d] + __bfloat162float(wrow[d]));
    float logit = acc * INV_SCALE;
    if (adj[(size_t)bi * 64 + j] <= 0) logit = -INFINITY;

    float m = logit;
    #pragma unroll
    for (int off = 32; off; off >>= 1) m = fmaxf(m, __shfl_xor(m, off));
    float p = expf(logit - m);
    float s = p;
    #pragma unroll
    for (int off = 32; off; off >>= 1) s += __shfl_xor(s, off);
    as[lane] = p / s;
    __syncthreads();

    const float* vbase = v + (size_t)(b * 64) * H_ + h * 64;
    float oacc = 0.f;
    int d = lane;
    #pragma unroll 8
    for (int jj = 0; jj < 64; ++jj)
        oacc += as[jj] * vbase[(size_t)jj * H_ + d];
    o[(size_t)bi * H_ + h * 64 + d] = oacc;
}

// ---------------------------------------------------------------- edge update
// one 64-lane wave per (b,i,j): softmax over {ew.ew, ew.x_i, ew.x_j}, new bond
__global__ void edge_kernel(const bf16* __restrict__ ew, const float* __restrict__ x,
                            bf16* __restrict__ bond) {
    int pair = blockIdx.x;         // (b*64+i)*64 + j
    int b = pair >> 12;
    int i = (pair >> 6) & 63;
    int j = pair & 63;
    const bf16*  e  = ew + (size_t)pair * H_;
    const float* xi = x + ((size_t)(b * 64 + i)) * H_;
    const float* xj = x + ((size_t)(b * 64 + j)) * H_;
    int lane = threadIdx.x;
    float s0 = 0.f, s1 = 0.f, s2 = 0.f;
    float ev[8], av[8], cv[8];
    #pragma unroll
    for (int t = 0; t < 8; ++t) {
        int h = lane + t * 64;
        float e_ = __bfloat162float(e[h]);
        float a_ = xi[h], c_ = xj[h];
        ev[t] = e_; av[t] = a_; cv[t] = c_;
        s0 += e_ * e_; s1 += e_ * a_; s2 += e_ * c_;
    }
    #pragma unroll
    for (int off = 32; off; off >>= 1) {
        s0 += __shfl_xor(s0, off);
        s1 += __shfl_xor(s1, off);
        s2 += __shfl_xor(s2, off);
    }
    float t0 = s0 * INV_SCALE, t1 = s1 * INV_SCALE, t2 = s2 * INV_SCALE;
    float m = fmaxf(t0, fmaxf(t1, t2));
    float e0 = expf(t0 - m), e1 = expf(t1 - m), e2 = expf(t2 - m);
    float inv = 1.0f / (e0 + e1 + e2);
    float w0 = e0 * inv, w1 = e1 * inv, w2 = e2 * inv;
    bf16* bo = bond + (size_t)pair * H_;
    #pragma unroll
    for (int t = 0; t < 8; ++t)
        bo[lane + t * 64] = __float2bfloat16(w0 * ev[t] + w1 * av[t] + w2 * cv[t]);
}

// ---------------------------------------------------------------- head
__global__ void cls_kernel(const float* __restrict__ x, const float* __restrict__ Wout,
                           float* __restrict__ cls) {
    int b = blockIdx.x, cc = blockIdx.y;
    int col = cc * 64 + threadIdx.x;
    const float* xr = x + (size_t)(b * 64) * H_;   // x[b,0,:]
    float acc = 0.f;
    for (int h = 0; h < H_; ++h)
        acc += xr[h] * Wout[(size_t)h * H_ + col];
    cls[b * H_ + col] = tanhf(acc);
}

__global__ void pred_kernel(const float* __restrict__ cls, const float* __restrict__ Wpred,
                            const float* __restrict__ bpred, float* __restrict__ out) {
    int b = blockIdx.x;
    int lane = threadIdx.x;
    const float* c = cls + (size_t)b * H_;
    float a0 = 0.f, a1 = 0.f;
    for (int h = lane; h < H_; h += 64) {
        float cvv = c[h];
        a0 += cvv * Wpred[h * 2 + 0];
        a1 += cvv * Wpred[h * 2 + 1];
    }
    #pragma unroll
    for (int off = 32; off; off >>= 1) {
        a0 += __shfl_xor(a0, off);
        a1 += __shfl_xor(a1, off);
    }
    if (lane == 0) {
        a0 += bpred[0];
        a1 += bpred[1];
        float m = fmaxf(a0, a1);
        float e0 = expf(a0 - m), e1 = expf(a1 - m);
        float inv = 1.0f / (e0 + e1);
        out[b * 2 + 0] = e0 * inv;
        out[b * 2 + 1] = e1 * inv;
    }
}

// ---------------------------------------------------------------- launch
extern "C" void kernel_launch(void* const* d_in, const int* in_sizes, int n_in,
                              void* d_out, int out_size, void* d_ws, size_t ws_size,
                              hipStream_t stream) {
    const int*   ids      = (const int*)d_in[0];
    const int*   adj      = (const int*)d_in[1];
    const float* atom_emb = (const float*)d_in[2];
    const float* bond_emb = (const float*)d_in[3];
    const float* Wq     = (const float*)d_in[4];
    const float* Wk     = (const float*)d_in[5];
    const float* Wv     = (const float*)d_in[6];
    const float* Wew    = (const float*)d_in[7];
    const float* Wstack = (const float*)d_in[8];
    const float* Wf1    = (const float*)d_in[9];
    const float* Wf2    = (const float*)d_in[10];
    const float* Wout   = (const float*)d_in[11];
    const float* Wpred  = (const float*)d_in[12];
    const float* bpred  = (const float*)d_in[13];

    char* ws = (char*)d_ws;
    size_t off = 0;
    auto alloc = [&](size_t bytes) {
        size_t o = off;
        off += (bytes + 255) & ~(size_t)255;
        return o;
    };
    const size_t ROWS = (size_t)B_ * N_;           // 512
    const size_t PAIRS = (size_t)B_ * N_ * N_;     // 32768

    float* x     = (float*)(ws + alloc(ROWS * H_ * 4));
    float* xn    = (float*)(ws + alloc(ROWS * H_ * 4));
    float* q     = (float*)(ws + alloc(ROWS * H_ * 4));
    float* k     = (float*)(ws + alloc(ROWS * H_ * 4));
    float* v     = (float*)(ws + alloc(ROWS * H_ * 4));
    float* o     = (float*)(ws + alloc(ROWS * H_ * 4));
    float* resid = (float*)(ws + alloc(ROWS * H_ * 4));
    float* ffin  = (float*)(ws + alloc(ROWS * H_ * 4));
    float* ffh   = (float*)(ws + alloc(ROWS * 4 * H_ * 4));
    float* cls   = (float*)(ws + alloc((size_t)B_ * H_ * 4));
    bf16*  bond  = (bf16*)(ws + alloc(PAIRS * H_ * 2));  // 32 MB
    bf16*  ew    = (bf16*)(ws + alloc(PAIRS * H_ * 2));  // 32 MB
    (void)ws_size;

    embed_x_kernel<<<1024, 256, 0, stream>>>(ids, atom_emb, x);
    embed_bond_kernel<<<65536, 256, 0, stream>>>(adj, bond_emb, bond);

    for (int l = 0; l < L_; ++l) {
        const float* wq = Wq + (size_t)l * H_ * H_;
        const float* wk = Wk + (size_t)l * H_ * H_;
        const float* wv = Wv + (size_t)l * H_ * H_;
        const float* we = Wew + (size_t)l * H_ * H_;
        const float* wst = Wstack + (size_t)l * H_ * H_;
        const float* wf1 = Wf1 + (size_t)l * H_ * 4 * H_;
        const float* wf2 = Wf2 + (size_t)l * 4 * H_ * H_;

        ln_kernel<<<512, 256, 0, stream>>>(x, xn);
        gemm64<float, float, 0><<<dim3(8, 8), 256, 0, stream>>>(xn, wq, q, nullptr, 512, 512, 512);
        gemm64<float, float, 0><<<dim3(8, 8), 256, 0, stream>>>(xn, wk, k, nullptr, 512, 512, 512);
        gemm64<float, float, 0><<<dim3(8, 8), 256, 0, stream>>>(xn, wv, v, nullptr, 512, 512, 512);
        // ew = bond @ Wew : [32768,512] x [512,512]
        gemm64<bf16, bf16, 0><<<dim3(512, 8), 256, 0, stream>>>(bond, we, ew, nullptr, 32768, 512, 512);
        attn_kernel<<<dim3(512, 8), 64, 0, stream>>>(q, k, v, ew, adj, o);
        // resid = o @ Wstack + xn
        gemm64<float, float, 1><<<dim3(8, 8), 256, 0, stream>>>(o, wst, resid, xn, 512, 512, 512);
        ln_kernel<<<512, 256, 0, stream>>>(resid, ffin);
        gemm64<float, float, 2><<<dim3(8, 32), 256, 0, stream>>>(ffin, wf1, ffh, nullptr, 512, 2048, 512);
        gemm64<float, float, 1><<<dim3(8, 8), 256, 0, stream>>>(ffh, wf2, x, resid, 512, 512, 2048);
        edge_kernel<<<32768, 64, 0, stream>>>(ew, x, bond);
    }

    cls_kernel<<<dim3(8, 8), 64, 0, stream>>>(x, Wout, cls);
    pred_kernel<<<8, 64, 0, stream>>>(cls, Wpred, bpred, (float*)d_out);
}

// Round 3
// 856.195 us; speedup vs baseline: 3.1568x; 3.1568x over previous
//
#include <hip/hip_runtime.h>
#include <hip/hip_bf16.h>

typedef __hip_bfloat16 bf16;

// Problem constants
#define B_     8
#define N_     64
#define H_     512
#define HEADS_ 8
#define SP_    64
#define L_     4
static constexpr float INV_SCALE = 0.044194173824159216f; // 1/sqrt(512)

// MFMA fragment types (per guide §3: short8 = 8 bf16 = 4 VGPRs)
typedef __attribute__((ext_vector_type(8))) short short8;
typedef __attribute__((ext_vector_type(4))) float f32x4;

// ---------------------------------------------------------------- embeddings
__global__ void embed_x_kernel(const int* __restrict__ ids,
                               const float* __restrict__ emb,
                               float* __restrict__ x) {
    int idx = blockIdx.x * 256 + threadIdx.x;      // 262144
    int row = idx >> 9;
    int h   = idx & 511;
    x[idx] = emb[ids[row] * H_ + h];
}

__global__ void embed_bond_kernel(const int* __restrict__ adj,
                                  const float* __restrict__ emb,
                                  bf16* __restrict__ bond) {
    size_t idx = (size_t)blockIdx.x * 256 + threadIdx.x;  // 16.7M
    int pair = (int)(idx >> 9);
    int h    = (int)(idx & 511);
    bond[idx] = __float2bfloat16(emb[adj[pair] * H_ + h]);
}

// ------------------------------------------------- weight transpose + cast
// W [Lz][K][N] fp32 -> Wt [Lz][N][K] bf16 (layer strides passed explicitly)
__global__ void transpose_w(const float* __restrict__ W, bf16* __restrict__ Wt,
                            int K, int N, long in_ls, long out_ls) {
    __shared__ float t[32][33];
    const float* Wl = W + (size_t)blockIdx.z * in_ls;
    bf16* Wtl = Wt + (size_t)blockIdx.z * out_ls;
    int k0 = blockIdx.x * 32, n0 = blockIdx.y * 32;
    int tx = threadIdx.x, ty = threadIdx.y;  // 32, 8
    #pragma unroll
    for (int r = ty; r < 32; r += 8)
        t[r][tx] = Wl[(size_t)(k0 + r) * N + n0 + tx];
    __syncthreads();
    #pragma unroll
    for (int r = ty; r < 32; r += 8)
        Wtl[(size_t)(n0 + r) * K + k0 + tx] = __float2bfloat16(t[tx][r]);
}

// ---------------------------------------------------------------- LayerNorm
// one block (256 threads) per row of 512. OUTMODE bit0: fp32 out, bit1: bf16 out
template <int OUTMODE>
__global__ void ln_kernel(const float* __restrict__ in, float* __restrict__ out32,
                          bf16* __restrict__ out16) {
    int row = blockIdx.x;
    int tid = threadIdx.x;
    const float* r = in + (size_t)row * H_;
    float x0 = r[tid], x1 = r[tid + 256];
    float s = x0 + x1, sq = x0 * x0 + x1 * x1;
    #pragma unroll
    for (int off = 32; off; off >>= 1) {
        s  += __shfl_xor(s,  off);
        sq += __shfl_xor(sq, off);
    }
    __shared__ float ls[4], lq[4];
    int w = tid >> 6;
    if ((tid & 63) == 0) { ls[w] = s; lq[w] = sq; }
    __syncthreads();
    float S = ls[0] + ls[1] + ls[2] + ls[3];
    float Q = lq[0] + lq[1] + lq[2] + lq[3];
    float mean = S * (1.0f / H_);
    float var  = Q * (1.0f / H_) - mean * mean;
    float inv  = rsqrtf(var + 1e-5f);
    float y0 = (x0 - mean) * inv, y1 = (x1 - mean) * inv;
    if (OUTMODE & 1) {
        out32[(size_t)row * H_ + tid]       = y0;
        out32[(size_t)row * H_ + tid + 256] = y1;
    }
    if (OUTMODE & 2) {
        out16[(size_t)row * H_ + tid]       = __float2bfloat16(y0);
        out16[(size_t)row * H_ + tid + 256] = __float2bfloat16(y1);
    }
}

// ---------------------------------------------------------------- MFMA GEMM
// C[M,N] = A[M,K] @ Bt[N,K]^T, all bf16 inputs, fp32 accum.
// 128x128 tile, 256 threads = 4 waves (2x2), each wave 4x4 grid of 16x16x32 MFMA.
// EPI: 0 = fp32 store, 1 = fp32 store + R, 2 = relu -> bf16, 3 = bf16 store
#define BM 128
#define BN 128
#define BK 32
#define RSTR 80   // LDS row stride bytes: 64 B data + 16 pad (bank stride 20 -> 2-way, free)

template <int EPI>
__launch_bounds__(256)
__global__ void mfma_gemm(const bf16* __restrict__ A, const bf16* __restrict__ Bt,
                          void* __restrict__ Cv, const float* __restrict__ R,
                          int M, int N, int K) {
    __shared__ __align__(16) char lds[(BM + BN) * RSTR];   // 20 KB
    char* As = lds;
    char* Bs = lds + BM * RSTR;
    const int tid = threadIdx.x;
    const int bm = blockIdx.x * BM, bn = blockIdx.y * BN;
    Bt += (size_t)blockIdx.z * N * K;   // fused-qkv weight select (z=0 otherwise)
    const int w = tid >> 6, lane = tid & 63;
    const int wr = (w >> 1) * 64, wc = (w & 1) * 64;
    const int m0 = lane & 15, q4 = lane >> 4;

    f32x4 acc[4][4] = {};

    // staging: thread handles 16B chunks f = tid and tid+256 of each 8 KB tile
    const int r0 = tid >> 2;              // 0..63
    const int r1 = r0 + 64;               // 64..127
    const int cB = (tid & 3) * 16;        // byte col in LDS row
    const int cE = (tid & 3) * 8;         // element col in global row

    for (int k0 = 0; k0 < K; k0 += BK) {
        uint4 a0 = *(const uint4*)(A  + (size_t)(bm + r0) * K + k0 + cE);
        uint4 a1 = *(const uint4*)(A  + (size_t)(bm + r1) * K + k0 + cE);
        uint4 b0 = *(const uint4*)(Bt + (size_t)(bn + r0) * K + k0 + cE);
        uint4 b1 = *(const uint4*)(Bt + (size_t)(bn + r1) * K + k0 + cE);
        __syncthreads();   // previous iter's frag reads complete before overwrite
        *(uint4*)(As + r0 * RSTR + cB) = a0;
        *(uint4*)(As + r1 * RSTR + cB) = a1;
        *(uint4*)(Bs + r0 * RSTR + cB) = b0;
        *(uint4*)(Bs + r1 * RSTR + cB) = b1;
        __syncthreads();
        short8 af[4], bfr[4];
        #pragma unroll
        for (int t = 0; t < 4; ++t) {
            af[t]  = *(const short8*)(As + (wr + t * 16 + m0) * RSTR + q4 * 16);
            bfr[t] = *(const short8*)(Bs + (wc + t * 16 + m0) * RSTR + q4 * 16);
        }
        #pragma unroll
        for (int mt = 0; mt < 4; ++mt)
            #pragma unroll
            for (int nt = 0; nt < 4; ++nt)
                acc[mt][nt] = __builtin_amdgcn_mfma_f32_16x16x32_bf16(
                    af[mt], bfr[nt], acc[mt][nt], 0, 0, 0);
    }

    // epilogue: C/D layout col = lane&15, row = quad*4 + reg  [m89/m91 verified]
    if (EPI <= 1) {
        float* C = (float*)Cv + (size_t)blockIdx.z * M * N;
        #pragma unroll
        for (int mt = 0; mt < 4; ++mt)
            #pragma unroll
            for (int i = 0; i < 4; ++i) {
                int row = bm + wr + mt * 16 + q4 * 4 + i;
                #pragma unroll
                for (int nt = 0; nt < 4; ++nt) {
                    int col = bn + wc + nt * 16 + m0;
                    float v = acc[mt][nt][i];
                    if (EPI == 1) v += R[(size_t)row * N + col];
                    C[(size_t)row * N + col] = v;
                }
            }
    } else {
        bf16* C = (bf16*)Cv;
        #pragma unroll
        for (int mt = 0; mt < 4; ++mt)
            #pragma unroll
            for (int i = 0; i < 4; ++i) {
                int row = bm + wr + mt * 16 + q4 * 4 + i;
                #pragma unroll
                for (int nt = 0; nt < 4; ++nt) {
                    int col = bn + wc + nt * 16 + m0;
                    float v = acc[mt][nt][i];
                    if (EPI == 2) v = fmaxf(v, 0.0f);
                    C[(size_t)row * N + col] = __float2bfloat16(v);
                }
            }
    }
}

// ---------------------------------------------------------------- attention
// one 64-lane wave per (b, i, h): logits over j, softmax (mask adj==0), o (bf16)
__global__ void attn_kernel(const float* __restrict__ qkv, const bf16* __restrict__ ew,
                            const int* __restrict__ adj, bf16* __restrict__ o) {
    const float* q = qkv;
    const float* k = qkv + (size_t)512 * H_;
    const float* v = qkv + (size_t)1024 * H_;
    int bi = blockIdx.x;           // b*64 + i
    int b  = bi >> 6;
    int h  = blockIdx.y;
    int lane = threadIdx.x;        // 64
    __shared__ float qs[64], as[64];
    qs[lane] = q[(size_t)bi * H_ + h * 64 + lane];
    __syncthreads();

    int j = lane;
    const float* krow = k + ((size_t)(b * 64 + j)) * H_ + h * 64;
    const bf16*  wrow = ew + ((size_t)bi * 64 + j) * H_ + h * 64;
    float acc = 0.f;
    #pragma unroll 8
    for (int d = 0; d < 64; ++d)
        acc += qs[d] * (krow[d] + __bfloat162float(wrow[d]));
    float logit = acc * INV_SCALE;
    if (adj[(size_t)bi * 64 + j] <= 0) logit = -INFINITY;

    float m = logit;
    #pragma unroll
    for (int off = 32; off; off >>= 1) m = fmaxf(m, __shfl_xor(m, off));
    float p = expf(logit - m);
    float s = p;
    #pragma unroll
    for (int off = 32; off; off >>= 1) s += __shfl_xor(s, off);
    as[lane] = p / s;
    __syncthreads();

    const float* vbase = v + (size_t)(b * 64) * H_ + h * 64;
    float oacc = 0.f;
    int d = lane;
    #pragma unroll 8
    for (int jj = 0; jj < 64; ++jj)
        oacc += as[jj] * vbase[(size_t)jj * H_ + d];
    o[(size_t)bi * H_ + h * 64 + d] = __float2bfloat16(oacc);
}

// ---------------------------------------------------------------- edge update
__global__ void edge_kernel(const bf16* __restrict__ ew, const float* __restrict__ x,
                            bf16* __restrict__ bond) {
    int pair = blockIdx.x;         // (b*64+i)*64 + j
    int b = pair >> 12;
    int i = (pair >> 6) & 63;
    int j = pair & 63;
    const bf16*  e  = ew + (size_t)pair * H_;
    const float* xi = x + ((size_t)(b * 64 + i)) * H_;
    const float* xj = x + ((size_t)(b * 64 + j)) * H_;
    int lane = threadIdx.x;
    float s0 = 0.f, s1 = 0.f, s2 = 0.f;
    float ev[8], av[8], cv[8];
    #pragma unroll
    for (int t = 0; t < 8; ++t) {
        int h = lane + t * 64;
        float e_ = __bfloat162float(e[h]);
        float a_ = xi[h], c_ = xj[h];
        ev[t] = e_; av[t] = a_; cv[t] = c_;
        s0 += e_ * e_; s1 += e_ * a_; s2 += e_ * c_;
    }
    #pragma unroll
    for (int off = 32; off; off >>= 1) {
        s0 += __shfl_xor(s0, off);
        s1 += __shfl_xor(s1, off);
        s2 += __shfl_xor(s2, off);
    }
    float t0 = s0 * INV_SCALE, t1 = s1 * INV_SCALE, t2 = s2 * INV_SCALE;
    float m = fmaxf(t0, fmaxf(t1, t2));
    float e0 = expf(t0 - m), e1 = expf(t1 - m), e2 = expf(t2 - m);
    float inv = 1.0f / (e0 + e1 + e2);
    float w0 = e0 * inv, w1 = e1 * inv, w2 = e2 * inv;
    bf16* bo = bond + (size_t)pair * H_;
    #pragma unroll
    for (int t = 0; t < 8; ++t)
        bo[lane + t * 64] = __float2bfloat16(w0 * ev[t] + w1 * av[t] + w2 * cv[t]);
}

// ---------------------------------------------------------------- head
__global__ void cls_kernel(const float* __restrict__ x, const float* __restrict__ Wout,
                           float* __restrict__ cls) {
    int b = blockIdx.x, cc = blockIdx.y;
    int col = cc * 64 + threadIdx.x;
    const float* xr = x + (size_t)(b * 64) * H_;   // x[b,0,:]
    float acc = 0.f;
    for (int h = 0; h < H_; ++h)
        acc += xr[h] * Wout[(size_t)h * H_ + col];
    cls[b * H_ + col] = tanhf(acc);
}

__global__ void pred_kernel(const float* __restrict__ cls, const float* __restrict__ Wpred,
                            const float* __restrict__ bpred, float* __restrict__ out) {
    int b = blockIdx.x;
    int lane = threadIdx.x;
    const float* c = cls + (size_t)b * H_;
    float a0 = 0.f, a1 = 0.f;
    for (int h = lane; h < H_; h += 64) {
        float cvv = c[h];
        a0 += cvv * Wpred[h * 2 + 0];
        a1 += cvv * Wpred[h * 2 + 1];
    }
    #pragma unroll
    for (int off = 32; off; off >>= 1) {
        a0 += __shfl_xor(a0, off);
        a1 += __shfl_xor(a1, off);
    }
    if (lane == 0) {
        a0 += bpred[0];
        a1 += bpred[1];
        float m = fmaxf(a0, a1);
        float e0 = expf(a0 - m), e1 = expf(a1 - m);
        float inv = 1.0f / (e0 + e1);
        out[b * 2 + 0] = e0 * inv;
        out[b * 2 + 1] = e1 * inv;
    }
}

// ---------------------------------------------------------------- launch
extern "C" void kernel_launch(void* const* d_in, const int* in_sizes, int n_in,
                              void* d_out, int out_size, void* d_ws, size_t ws_size,
                              hipStream_t stream) {
    const int*   ids      = (const int*)d_in[0];
    const int*   adj      = (const int*)d_in[1];
    const float* atom_emb = (const float*)d_in[2];
    const float* bond_emb = (const float*)d_in[3];
    const float* Wq     = (const float*)d_in[4];
    const float* Wk     = (const float*)d_in[5];
    const float* Wv     = (const float*)d_in[6];
    const float* Wew    = (const float*)d_in[7];
    const float* Wstack = (const float*)d_in[8];
    const float* Wf1    = (const float*)d_in[9];
    const float* Wf2    = (const float*)d_in[10];
    const float* Wout   = (const float*)d_in[11];
    const float* Wpred  = (const float*)d_in[12];
    const float* bpred  = (const float*)d_in[13];

    char* ws = (char*)d_ws;
    size_t off = 0;
    auto alloc = [&](size_t bytes) {
        size_t o = off;
        off += (bytes + 255) & ~(size_t)255;
        return o;
    };
    const size_t ROWS  = (size_t)B_ * N_;           // 512
    const size_t PAIRS = (size_t)B_ * N_ * N_;      // 32768
    const size_t KN    = (size_t)H_ * H_;           // 262144

    float* x       = (float*)(ws + alloc(ROWS * H_ * 4));
    float* xn      = (float*)(ws + alloc(ROWS * H_ * 4));
    bf16*  xn_bf   = (bf16*) (ws + alloc(ROWS * H_ * 2));
    float* qkv     = (float*)(ws + alloc(3 * ROWS * H_ * 4));
    bf16*  o_bf    = (bf16*) (ws + alloc(ROWS * H_ * 2));
    float* resid   = (float*)(ws + alloc(ROWS * H_ * 4));
    bf16*  ffin_bf = (bf16*) (ws + alloc(ROWS * H_ * 2));
    bf16*  ffh_bf  = (bf16*) (ws + alloc(ROWS * 4 * H_ * 2));
    float* cls     = (float*)(ws + alloc((size_t)B_ * H_ * 4));
    bf16*  bond    = (bf16*) (ws + alloc(PAIRS * H_ * 2));      // 32 MB
    bf16*  ew      = (bf16*) (ws + alloc(PAIRS * H_ * 2));      // 32 MB
    bf16*  qkvt    = (bf16*) (ws + alloc((size_t)L_ * 3 * KN * 2));   // 6 MB
    bf16*  ewt     = (bf16*) (ws + alloc((size_t)L_ * KN * 2));       // 2 MB
    bf16*  stackt  = (bf16*) (ws + alloc((size_t)L_ * KN * 2));       // 2 MB
    bf16*  f1t     = (bf16*) (ws + alloc((size_t)L_ * 4 * KN * 2));   // 8 MB
    bf16*  f2t     = (bf16*) (ws + alloc((size_t)L_ * 4 * KN * 2));   // 8 MB
    (void)ws_size;

    embed_x_kernel<<<1024, 256, 0, stream>>>(ids, atom_emb, x);
    embed_bond_kernel<<<65536, 256, 0, stream>>>(adj, bond_emb, bond);

    // one-time weight transpose + bf16 cast
    dim3 tb(32, 8);
    transpose_w<<<dim3(16, 16, 4), tb, 0, stream>>>(Wq, qkvt + 0 * KN, 512, 512, KN, 3 * KN);
    transpose_w<<<dim3(16, 16, 4), tb, 0, stream>>>(Wk, qkvt + 1 * KN, 512, 512, KN, 3 * KN);
    transpose_w<<<dim3(16, 16, 4), tb, 0, stream>>>(Wv, qkvt + 2 * KN, 512, 512, KN, 3 * KN);
    transpose_w<<<dim3(16, 16, 4), tb, 0, stream>>>(Wew, ewt, 512, 512, KN, KN);
    transpose_w<<<dim3(16, 16, 4), tb, 0, stream>>>(Wstack, stackt, 512, 512, KN, KN);
    transpose_w<<<dim3(16, 64, 4), tb, 0, stream>>>(Wf1, f1t, 512, 2048, 4 * KN, 4 * KN);
    transpose_w<<<dim3(64, 16, 4), tb, 0, stream>>>(Wf2, f2t, 2048, 512, 4 * KN, 4 * KN);

    for (int l = 0; l < L_; ++l) {
        ln_kernel<3><<<512, 256, 0, stream>>>(x, xn, xn_bf);
        // q,k,v fused: z selects weight slice and output slice
        mfma_gemm<0><<<dim3(4, 4, 3), 256, 0, stream>>>(
            xn_bf, qkvt + (size_t)l * 3 * KN, qkv, nullptr, 512, 512, 512);
        // ew = bond @ Wew
        mfma_gemm<3><<<dim3(256, 4), 256, 0, stream>>>(
            bond, ewt + (size_t)l * KN, ew, nullptr, 32768, 512, 512);
        attn_kernel<<<dim3(512, 8), 64, 0, stream>>>(qkv, ew, adj, o_bf);
        // resid = o @ Wstack + xn
        mfma_gemm<1><<<dim3(4, 4), 256, 0, stream>>>(
            o_bf, stackt + (size_t)l * KN, resid, xn, 512, 512, 512);
        ln_kernel<2><<<512, 256, 0, stream>>>(resid, nullptr, ffin_bf);
        // ffh = relu(ffin @ Wf1)
        mfma_gemm<2><<<dim3(4, 16), 256, 0, stream>>>(
            ffin_bf, f1t + (size_t)l * 4 * KN, ffh_bf, nullptr, 512, 2048, 512);
        // x = ffh @ Wf2 + resid
        mfma_gemm<1><<<dim3(4, 4), 256, 0, stream>>>(
            ffh_bf, f2t + (size_t)l * 4 * KN, x, resid, 512, 512, 2048);
        edge_kernel<<<32768, 64, 0, stream>>>(ew, x, bond);
    }

    cls_kernel<<<dim3(8, 8), 64, 0, stream>>>(x, Wout, cls);
    pred_kernel<<<8, 64, 0, stream>>>(cls, Wpred, bpred, (float*)d_out);
}

// Round 4
// 652.488 us; speedup vs baseline: 4.1423x; 1.3122x over previous
//
#include <hip/hip_runtime.h>
#include <hip/hip_bf16.h>

typedef __hip_bfloat16 bf16;

// Problem constants
#define B_     8
#define N_     64
#define H_     512
#define HEADS_ 8
#define SP_    64
#define L_     4
static constexpr float INV_SCALE = 0.044194173824159216f; // 1/sqrt(512)

// MFMA fragment types (per guide §3: short8 = 8 bf16 = 4 VGPRs)
typedef __attribute__((ext_vector_type(8))) short short8;
typedef __attribute__((ext_vector_type(4))) float f32x4;

// ---------------------------------------------------------------- embeddings
__global__ void embed_x_kernel(const int* __restrict__ ids,
                               const float* __restrict__ emb,
                               float* __restrict__ x) {
    int idx = blockIdx.x * 256 + threadIdx.x;      // 262144
    int row = idx >> 9;
    int h   = idx & 511;
    x[idx] = emb[ids[row] * H_ + h];
}

__global__ void embed_bond_kernel(const int* __restrict__ adj,
                                  const float* __restrict__ emb,
                                  bf16* __restrict__ bond) {
    size_t idx = (size_t)blockIdx.x * 256 + threadIdx.x;  // 16.7M
    int pair = (int)(idx >> 9);
    int h    = (int)(idx & 511);
    bond[idx] = __float2bfloat16(emb[adj[pair] * H_ + h]);
}

// ------------------------------------------------- weight transpose + cast
// W [Lz][K][N] fp32 -> Wt [Lz][N][K] bf16 (layer strides passed explicitly)
__global__ void transpose_w(const float* __restrict__ W, bf16* __restrict__ Wt,
                            int K, int N, long in_ls, long out_ls) {
    __shared__ float t[32][33];
    const float* Wl = W + (size_t)blockIdx.z * in_ls;
    bf16* Wtl = Wt + (size_t)blockIdx.z * out_ls;
    int k0 = blockIdx.x * 32, n0 = blockIdx.y * 32;
    int tx = threadIdx.x, ty = threadIdx.y;  // 32, 8
    #pragma unroll
    for (int r = ty; r < 32; r += 8)
        t[r][tx] = Wl[(size_t)(k0 + r) * N + n0 + tx];
    __syncthreads();
    #pragma unroll
    for (int r = ty; r < 32; r += 8)
        Wtl[(size_t)(n0 + r) * K + k0 + tx] = __float2bfloat16(t[tx][r]);
}

// ---------------------------------------------------------------- LayerNorm
// one block (256 threads) per row of 512. OUTMODE bit0: fp32 out, bit1: bf16 out
template <int OUTMODE>
__global__ void ln_kernel(const float* __restrict__ in, float* __restrict__ out32,
                          bf16* __restrict__ out16) {
    int row = blockIdx.x;
    int tid = threadIdx.x;
    const float* r = in + (size_t)row * H_;
    float x0 = r[tid], x1 = r[tid + 256];
    float s = x0 + x1, sq = x0 * x0 + x1 * x1;
    #pragma unroll
    for (int off = 32; off; off >>= 1) {
        s  += __shfl_xor(s,  off);
        sq += __shfl_xor(sq, off);
    }
    __shared__ float ls[4], lq[4];
    int w = tid >> 6;
    if ((tid & 63) == 0) { ls[w] = s; lq[w] = sq; }
    __syncthreads();
    float S = ls[0] + ls[1] + ls[2] + ls[3];
    float Q = lq[0] + lq[1] + lq[2] + lq[3];
    float mean = S * (1.0f / H_);
    float var  = Q * (1.0f / H_) - mean * mean;
    float inv  = rsqrtf(var + 1e-5f);
    float y0 = (x0 - mean) * inv, y1 = (x1 - mean) * inv;
    if (OUTMODE & 1) {
        out32[(size_t)row * H_ + tid]       = y0;
        out32[(size_t)row * H_ + tid + 256] = y1;
    }
    if (OUTMODE & 2) {
        out16[(size_t)row * H_ + tid]       = __float2bfloat16(y0);
        out16[(size_t)row * H_ + tid + 256] = __float2bfloat16(y1);
    }
}

// ---------------------------------------------------------------- MFMA GEMM (large, 128x128)
// C[M,N] = A[M,K] @ Bt[N,K]^T, all bf16 inputs, fp32 accum.
// EPI: 0 = fp32 store, 1 = fp32 store + R, 2 = relu -> bf16, 3 = bf16 store
#define BM 128
#define BN 128
#define BK 32
#define RSTR 80   // LDS row stride bytes: 64 B data + 16 pad (bank stride 20 -> 2-way, free)

template <int EPI>
__launch_bounds__(256)
__global__ void mfma_gemm(const bf16* __restrict__ A, const bf16* __restrict__ Bt,
                          void* __restrict__ Cv, const float* __restrict__ R,
                          int M, int N, int K) {
    __shared__ __align__(16) char lds[(BM + BN) * RSTR];   // 20 KB
    char* As = lds;
    char* Bs = lds + BM * RSTR;
    const int tid = threadIdx.x;
    const int bm = blockIdx.x * BM, bn = blockIdx.y * BN;
    Bt += (size_t)blockIdx.z * N * K;
    const int w = tid >> 6, lane = tid & 63;
    const int wr = (w >> 1) * 64, wc = (w & 1) * 64;
    const int m0 = lane & 15, q4 = lane >> 4;

    f32x4 acc[4][4] = {};

    const int r0 = tid >> 2;              // 0..63
    const int r1 = r0 + 64;               // 64..127
    const int cB = (tid & 3) * 16;        // byte col in LDS row
    const int cE = (tid & 3) * 8;         // element col in global row

    for (int k0 = 0; k0 < K; k0 += BK) {
        uint4 a0 = *(const uint4*)(A  + (size_t)(bm + r0) * K + k0 + cE);
        uint4 a1 = *(const uint4*)(A  + (size_t)(bm + r1) * K + k0 + cE);
        uint4 b0 = *(const uint4*)(Bt + (size_t)(bn + r0) * K + k0 + cE);
        uint4 b1 = *(const uint4*)(Bt + (size_t)(bn + r1) * K + k0 + cE);
        __syncthreads();   // previous iter's frag reads complete before overwrite
        *(uint4*)(As + r0 * RSTR + cB) = a0;
        *(uint4*)(As + r1 * RSTR + cB) = a1;
        *(uint4*)(Bs + r0 * RSTR + cB) = b0;
        *(uint4*)(Bs + r1 * RSTR + cB) = b1;
        __syncthreads();
        short8 af[4], bfr[4];
        #pragma unroll
        for (int t = 0; t < 4; ++t) {
            af[t]  = *(const short8*)(As + (wr + t * 16 + m0) * RSTR + q4 * 16);
            bfr[t] = *(const short8*)(Bs + (wc + t * 16 + m0) * RSTR + q4 * 16);
        }
        #pragma unroll
        for (int mt = 0; mt < 4; ++mt)
            #pragma unroll
            for (int nt = 0; nt < 4; ++nt)
                acc[mt][nt] = __builtin_amdgcn_mfma_f32_16x16x32_bf16(
                    af[mt], bfr[nt], acc[mt][nt], 0, 0, 0);
    }

    // epilogue: C/D layout col = lane&15, row = quad*4 + reg  [m89/m91 verified]
    if (EPI <= 1) {
        float* C = (float*)Cv + (size_t)blockIdx.z * M * N;
        #pragma unroll
        for (int mt = 0; mt < 4; ++mt)
            #pragma unroll
            for (int i = 0; i < 4; ++i) {
                int row = bm + wr + mt * 16 + q4 * 4 + i;
                #pragma unroll
                for (int nt = 0; nt < 4; ++nt) {
                    int col = bn + wc + nt * 16 + m0;
                    float v = acc[mt][nt][i];
                    if (EPI == 1) v += R[(size_t)row * N + col];
                    C[(size_t)row * N + col] = v;
                }
            }
    } else {
        bf16* C = (bf16*)Cv;
        #pragma unroll
        for (int mt = 0; mt < 4; ++mt)
            #pragma unroll
            for (int i = 0; i < 4; ++i) {
                int row = bm + wr + mt * 16 + q4 * 4 + i;
                #pragma unroll
                for (int nt = 0; nt < 4; ++nt) {
                    int col = bn + wc + nt * 16 + m0;
                    float v = acc[mt][nt][i];
                    if (EPI == 2) v = fmaxf(v, 0.0f);
                    C[(size_t)row * N + col] = __float2bfloat16(v);
                }
            }
    }
}

// ------------------------------------------- MFMA GEMM (small, 64x64, BK=64)
// For M=512 activation GEMMs: 4x more blocks, 2x fewer K-iters than 128-tile.
// 4 waves as 2x2; each wave 32x32 = 2x2 frags of 16x16x32.
// LDS layout: per matrix 2 K-planes (32 elems each) of [64 rows][80 B] -> same
// proven RSTR=80 pad as the big kernel.
// SPLIT=false: blockIdx.z = weight/output slice (fused qkv).
// SPLIT=true:  blockIdx.z = K-split slice s; fp32 partial to Cv[s*M*N + ...], EPI ignored.
template <int EPI, bool SPLIT>
__launch_bounds__(256)
__global__ void mfma_gemm_s(const bf16* __restrict__ A, const bf16* __restrict__ Bt,
                            void* __restrict__ Cv, const float* __restrict__ R,
                            int M, int N, int K) {
    __shared__ __align__(16) char lds[4 * 64 * RSTR];   // 20 KB: A planes 0,1; B planes 0,1
    char* As = lds;
    char* Bs = lds + 2 * 64 * RSTR;
    const int tid = threadIdx.x;
    const int bm = blockIdx.x * 64, bn = blockIdx.y * 64;
    int kbeg = 0, kend = K;
    if (SPLIT) {
        int ks = K / gridDim.z;
        kbeg = blockIdx.z * ks;
        kend = kbeg + ks;
    } else {
        Bt += (size_t)blockIdx.z * N * K;
    }
    const int w = tid >> 6, lane = tid & 63;
    const int wr = (w >> 1) * 32, wc = (w & 1) * 32;
    const int m0 = lane & 15, q4 = lane >> 4;

    f32x4 acc[2][2] = {};

    // staging: li in [0,512): r = li>>3 (64 rows), c = li&7 (8 x uint4 per row)
    const int rA = tid >> 3;              // 0..31  (round 0), +32 round 1
    const int cA = tid & 7;
    const int ksP = cA >> 2;              // K-plane
    const int cB = (cA & 3) * 16;         // byte col within plane row
    const int cE = cA * 8;                // element col in global row

    for (int k0 = kbeg; k0 < kend; k0 += 64) {
        uint4 a0 = *(const uint4*)(A  + (size_t)(bm + rA) * K + k0 + cE);
        uint4 a1 = *(const uint4*)(A  + (size_t)(bm + rA + 32) * K + k0 + cE);
        uint4 b0 = *(const uint4*)(Bt + (size_t)(bn + rA) * K + k0 + cE);
        uint4 b1 = *(const uint4*)(Bt + (size_t)(bn + rA + 32) * K + k0 + cE);
        __syncthreads();
        *(uint4*)(As + ksP * (64 * RSTR) + rA * RSTR + cB) = a0;
        *(uint4*)(As + ksP * (64 * RSTR) + (rA + 32) * RSTR + cB) = a1;
        *(uint4*)(Bs + ksP * (64 * RSTR) + rA * RSTR + cB) = b0;
        *(uint4*)(Bs + ksP * (64 * RSTR) + (rA + 32) * RSTR + cB) = b1;
        __syncthreads();
        short8 af[2][2], bfr[2][2];
        #pragma unroll
        for (int ks = 0; ks < 2; ++ks)
            #pragma unroll
            for (int t = 0; t < 2; ++t) {
                af[ks][t]  = *(const short8*)(As + ks * (64 * RSTR) + (wr + t * 16 + m0) * RSTR + q4 * 16);
                bfr[ks][t] = *(const short8*)(Bs + ks * (64 * RSTR) + (wc + t * 16 + m0) * RSTR + q4 * 16);
            }
        #pragma unroll
        for (int ks = 0; ks < 2; ++ks)
            #pragma unroll
            for (int mt = 0; mt < 2; ++mt)
                #pragma unroll
                for (int nt = 0; nt < 2; ++nt)
                    acc[mt][nt] = __builtin_amdgcn_mfma_f32_16x16x32_bf16(
                        af[ks][mt], bfr[ks][nt], acc[mt][nt], 0, 0, 0);
    }

    if (SPLIT) {
        float* C = (float*)Cv + (size_t)blockIdx.z * M * N;
        #pragma unroll
        for (int mt = 0; mt < 2; ++mt)
            #pragma unroll
            for (int i = 0; i < 4; ++i) {
                int row = bm + wr + mt * 16 + q4 * 4 + i;
                #pragma unroll
                for (int nt = 0; nt < 2; ++nt)
                    C[(size_t)row * N + bn + wc + nt * 16 + m0] = acc[mt][nt][i];
            }
    } else if (EPI <= 1) {
        float* C = (float*)Cv + (size_t)blockIdx.z * M * N;
        #pragma unroll
        for (int mt = 0; mt < 2; ++mt)
            #pragma unroll
            for (int i = 0; i < 4; ++i) {
                int row = bm + wr + mt * 16 + q4 * 4 + i;
                #pragma unroll
                for (int nt = 0; nt < 2; ++nt) {
                    int col = bn + wc + nt * 16 + m0;
                    float v = acc[mt][nt][i];
                    if (EPI == 1) v += R[(size_t)row * N + col];
                    C[(size_t)row * N + col] = v;
                }
            }
    } else {
        bf16* C = (bf16*)Cv;
        #pragma unroll
        for (int mt = 0; mt < 2; ++mt)
            #pragma unroll
            for (int i = 0; i < 4; ++i) {
                int row = bm + wr + mt * 16 + q4 * 4 + i;
                #pragma unroll
                for (int nt = 0; nt < 2; ++nt) {
                    int col = bn + wc + nt * 16 + m0;
                    float v = acc[mt][nt][i];
                    if (EPI == 2) v = fmaxf(v, 0.0f);
                    C[(size_t)row * N + col] = __float2bfloat16(v);
                }
            }
    }
}

// out = sum_s part[s] (+ R), fp32
__global__ void reduce_add(const float* __restrict__ part, const float* __restrict__ R,
                           float* __restrict__ out, int MN, int S) {
    int i = blockIdx.x * 256 + threadIdx.x;
    if (i >= MN) return;
    float v = R ? R[i] : 0.0f;
    for (int s = 0; s < S; ++s) v += part[(size_t)s * MN + i];
    out[i] = v;
}

// ---------------------------------------------------------------- attention
__global__ void attn_kernel(const float* __restrict__ qkv, const bf16* __restrict__ ew,
                            const int* __restrict__ adj, bf16* __restrict__ o) {
    const float* q = qkv;
    const float* k = qkv + (size_t)512 * H_;
    const float* v = qkv + (size_t)1024 * H_;
    int bi = blockIdx.x;           // b*64 + i
    int b  = bi >> 6;
    int h  = blockIdx.y;
    int lane = threadIdx.x;        // 64
    __shared__ float qs[64], as[64];
    qs[lane] = q[(size_t)bi * H_ + h * 64 + lane];
    __syncthreads();

    int j = lane;
    const float* krow = k + ((size_t)(b * 64 + j)) * H_ + h * 64;
    const bf16*  wrow = ew + ((size_t)bi * 64 + j) * H_ + h * 64;
    float acc = 0.f;
    #pragma unroll 8
    for (int d = 0; d < 64; ++d)
        acc += qs[d] * (krow[d] + __bfloat162float(wrow[d]));
    float logit = acc * INV_SCALE;
    if (adj[(size_t)bi * 64 + j] <= 0) logit = -INFINITY;

    float m = logit;
    #pragma unroll
    for (int off = 32; off; off >>= 1) m = fmaxf(m, __shfl_xor(m, off));
    float p = expf(logit - m);
    float s = p;
    #pragma unroll
    for (int off = 32; off; off >>= 1) s += __shfl_xor(s, off);
    as[lane] = p / s;
    __syncthreads();

    const float* vbase = v + (size_t)(b * 64) * H_ + h * 64;
    float oacc = 0.f;
    int d = lane;
    #pragma unroll 8
    for (int jj = 0; jj < 64; ++jj)
        oacc += as[jj] * vbase[(size_t)jj * H_ + d];
    o[(size_t)bi * H_ + h * 64 + d] = __float2bfloat16(oacc);
}

// ---------------------------------------------------------------- edge update
__global__ void edge_kernel(const bf16* __restrict__ ew, const float* __restrict__ x,
                            bf16* __restrict__ bond) {
    int pair = blockIdx.x;         // (b*64+i)*64 + j
    int b = pair >> 12;
    int i = (pair >> 6) & 63;
    int j = pair & 63;
    const bf16*  e  = ew + (size_t)pair * H_;
    const float* xi = x + ((size_t)(b * 64 + i)) * H_;
    const float* xj = x + ((size_t)(b * 64 + j)) * H_;
    int lane = threadIdx.x;
    float s0 = 0.f, s1 = 0.f, s2 = 0.f;
    float ev[8], av[8], cv[8];
    #pragma unroll
    for (int t = 0; t < 8; ++t) {
        int h = lane + t * 64;
        float e_ = __bfloat162float(e[h]);
        float a_ = xi[h], c_ = xj[h];
        ev[t] = e_; av[t] = a_; cv[t] = c_;
        s0 += e_ * e_; s1 += e_ * a_; s2 += e_ * c_;
    }
    #pragma unroll
    for (int off = 32; off; off >>= 1) {
        s0 += __shfl_xor(s0, off);
        s1 += __shfl_xor(s1, off);
        s2 += __shfl_xor(s2, off);
    }
    float t0 = s0 * INV_SCALE, t1 = s1 * INV_SCALE, t2 = s2 * INV_SCALE;
    float m = fmaxf(t0, fmaxf(t1, t2));
    float e0 = expf(t0 - m), e1 = expf(t1 - m), e2 = expf(t2 - m);
    float inv = 1.0f / (e0 + e1 + e2);
    float w0 = e0 * inv, w1 = e1 * inv, w2 = e2 * inv;
    bf16* bo = bond + (size_t)pair * H_;
    #pragma unroll
    for (int t = 0; t < 8; ++t)
        bo[lane + t * 64] = __float2bfloat16(w0 * ev[t] + w1 * av[t] + w2 * cv[t]);
}

// ---------------------------------------------------------------- head
__global__ void cls_kernel(const float* __restrict__ x, const float* __restrict__ Wout,
                           float* __restrict__ cls) {
    int b = blockIdx.x, cc = blockIdx.y;
    int col = cc * 64 + threadIdx.x;
    const float* xr = x + (size_t)(b * 64) * H_;   // x[b,0,:]
    float acc = 0.f;
    for (int h = 0; h < H_; ++h)
        acc += xr[h] * Wout[(size_t)h * H_ + col];
    cls[b * H_ + col] = tanhf(acc);
}

__global__ void pred_kernel(const float* __restrict__ cls, const float* __restrict__ Wpred,
                            const float* __restrict__ bpred, float* __restrict__ out) {
    int b = blockIdx.x;
    int lane = threadIdx.x;
    const float* c = cls + (size_t)b * H_;
    float a0 = 0.f, a1 = 0.f;
    for (int h = lane; h < H_; h += 64) {
        float cvv = c[h];
        a0 += cvv * Wpred[h * 2 + 0];
        a1 += cvv * Wpred[h * 2 + 1];
    }
    #pragma unroll
    for (int off = 32; off; off >>= 1) {
        a0 += __shfl_xor(a0, off);
        a1 += __shfl_xor(a1, off);
    }
    if (lane == 0) {
        a0 += bpred[0];
        a1 += bpred[1];
        float m = fmaxf(a0, a1);
        float e0 = expf(a0 - m), e1 = expf(a1 - m);
        float inv = 1.0f / (e0 + e1);
        out[b * 2 + 0] = e0 * inv;
        out[b * 2 + 1] = e1 * inv;
    }
}

// ---------------------------------------------------------------- launch
extern "C" void kernel_launch(void* const* d_in, const int* in_sizes, int n_in,
                              void* d_out, int out_size, void* d_ws, size_t ws_size,
                              hipStream_t stream) {
    const int*   ids      = (const int*)d_in[0];
    const int*   adj      = (const int*)d_in[1];
    const float* atom_emb = (const float*)d_in[2];
    const float* bond_emb = (const float*)d_in[3];
    const float* Wq     = (const float*)d_in[4];
    const float* Wk     = (const float*)d_in[5];
    const float* Wv     = (const float*)d_in[6];
    const float* Wew    = (const float*)d_in[7];
    const float* Wstack = (const float*)d_in[8];
    const float* Wf1    = (const float*)d_in[9];
    const float* Wf2    = (const float*)d_in[10];
    const float* Wout   = (const float*)d_in[11];
    const float* Wpred  = (const float*)d_in[12];
    const float* bpred  = (const float*)d_in[13];

    char* ws = (char*)d_ws;
    size_t off = 0;
    auto alloc = [&](size_t bytes) {
        size_t o = off;
        off += (bytes + 255) & ~(size_t)255;
        return o;
    };
    const size_t ROWS  = (size_t)B_ * N_;           // 512
    const size_t PAIRS = (size_t)B_ * N_ * N_;      // 32768
    const size_t KN    = (size_t)H_ * H_;           // 262144

    float* x       = (float*)(ws + alloc(ROWS * H_ * 4));
    float* xn      = (float*)(ws + alloc(ROWS * H_ * 4));
    bf16*  xn_bf   = (bf16*) (ws + alloc(ROWS * H_ * 2));
    float* qkv     = (float*)(ws + alloc(3 * ROWS * H_ * 4));
    bf16*  o_bf    = (bf16*) (ws + alloc(ROWS * H_ * 2));
    float* resid   = (float*)(ws + alloc(ROWS * H_ * 4));
    bf16*  ffin_bf = (bf16*) (ws + alloc(ROWS * H_ * 2));
    bf16*  ffh_bf  = (bf16*) (ws + alloc(ROWS * 4 * H_ * 2));
    float* part    = (float*)(ws + alloc(4 * ROWS * H_ * 4));   // split-K partials (4 MB)
    float* cls     = (float*)(ws + alloc((size_t)B_ * H_ * 4));
    bf16*  bond    = (bf16*) (ws + alloc(PAIRS * H_ * 2));      // 32 MB
    bf16*  ew      = (bf16*) (ws + alloc(PAIRS * H_ * 2));      // 32 MB
    bf16*  qkvt    = (bf16*) (ws + alloc((size_t)L_ * 3 * KN * 2));   // 6 MB
    bf16*  ewt     = (bf16*) (ws + alloc((size_t)L_ * KN * 2));       // 2 MB
    bf16*  stackt  = (bf16*) (ws + alloc((size_t)L_ * KN * 2));       // 2 MB
    bf16*  f1t     = (bf16*) (ws + alloc((size_t)L_ * 4 * KN * 2));   // 8 MB
    bf16*  f2t     = (bf16*) (ws + alloc((size_t)L_ * 4 * KN * 2));   // 8 MB
    (void)ws_size;

    embed_x_kernel<<<1024, 256, 0, stream>>>(ids, atom_emb, x);
    embed_bond_kernel<<<65536, 256, 0, stream>>>(adj, bond_emb, bond);

    // one-time weight transpose + bf16 cast
    dim3 tb(32, 8);
    transpose_w<<<dim3(16, 16, 4), tb, 0, stream>>>(Wq, qkvt + 0 * KN, 512, 512, KN, 3 * KN);
    transpose_w<<<dim3(16, 16, 4), tb, 0, stream>>>(Wk, qkvt + 1 * KN, 512, 512, KN, 3 * KN);
    transpose_w<<<dim3(16, 16, 4), tb, 0, stream>>>(Wv, qkvt + 2 * KN, 512, 512, KN, 3 * KN);
    transpose_w<<<dim3(16, 16, 4), tb, 0, stream>>>(Wew, ewt, 512, 512, KN, KN);
    transpose_w<<<dim3(16, 16, 4), tb, 0, stream>>>(Wstack, stackt, 512, 512, KN, KN);
    transpose_w<<<dim3(16, 64, 4), tb, 0, stream>>>(Wf1, f1t, 512, 2048, 4 * KN, 4 * KN);
    transpose_w<<<dim3(64, 16, 4), tb, 0, stream>>>(Wf2, f2t, 2048, 512, 4 * KN, 4 * KN);

    for (int l = 0; l < L_; ++l) {
        ln_kernel<3><<<512, 256, 0, stream>>>(x, xn, xn_bf);
        // q,k,v fused small-tile: z selects weight slice and output slice (192 blocks)
        mfma_gemm_s<0, false><<<dim3(8, 8, 3), 256, 0, stream>>>(
            xn_bf, qkvt + (size_t)l * 3 * KN, qkv, nullptr, 512, 512, 512);
        // ew = bond @ Wew (1024 blocks, throughput-bound)
        mfma_gemm<3><<<dim3(256, 4), 256, 0, stream>>>(
            bond, ewt + (size_t)l * KN, ew, nullptr, 32768, 512, 512);
        attn_kernel<<<dim3(512, 8), 64, 0, stream>>>(qkv, ew, adj, o_bf);
        // resid = o @ Wstack + xn (64 blocks)
        mfma_gemm_s<1, false><<<dim3(8, 8), 256, 0, stream>>>(
            o_bf, stackt + (size_t)l * KN, resid, xn, 512, 512, 512);
        ln_kernel<2><<<512, 256, 0, stream>>>(resid, nullptr, ffin_bf);
        // ffh = relu(ffin @ Wf1) (256 blocks)
        mfma_gemm_s<2, false><<<dim3(8, 32), 256, 0, stream>>>(
            ffin_bf, f1t + (size_t)l * 4 * KN, ffh_bf, nullptr, 512, 2048, 512);
        // x = ffh @ Wf2 + resid : split-K x4 (256 blocks) + reduce
        mfma_gemm_s<0, true><<<dim3(8, 8, 4), 256, 0, stream>>>(
            ffh_bf, f2t + (size_t)l * 4 * KN, part, nullptr, 512, 512, 2048);
        reduce_add<<<1024, 256, 0, stream>>>(part, resid, x, 512 * 512, 4);
        edge_kernel<<<32768, 64, 0, stream>>>(ew, x, bond);
    }

    cls_kernel<<<dim3(8, 8), 64, 0, stream>>>(x, Wout, cls);
    pred_kernel<<<8, 64, 0, stream>>>(cls, Wpred, bpred, (float*)d_out);
}

// Round 5
// 613.126 us; speedup vs baseline: 4.4082x; 1.0642x over previous
//
#include <hip/hip_runtime.h>
#include <hip/hip_bf16.h>

typedef __hip_bfloat16 bf16;

// Problem constants
#define B_     8
#define N_     64
#define H_     512
#define HEADS_ 8
#define SP_    64
#define L_     4
static constexpr float INV_SCALE = 0.044194173824159216f; // 1/sqrt(512)

// MFMA fragment types (per guide §3: short8 = 8 bf16 = 4 VGPRs)
typedef __attribute__((ext_vector_type(8))) short short8;
typedef __attribute__((ext_vector_type(4))) float f32x4;

// async global->LDS, 16B per lane; LDS dest is wave-uniform base + lane*16
__device__ __forceinline__ void gload_lds16(const void* g, void* l) {
    __builtin_amdgcn_global_load_lds(
        (const __attribute__((address_space(1))) unsigned int*)g,
        (__attribute__((address_space(3))) unsigned int*)l, 16, 0, 0);
}

__device__ __forceinline__ void unpack8(uint4 u, float* f) {
    f[0] = __uint_as_float(u.x << 16); f[1] = __uint_as_float(u.x & 0xffff0000u);
    f[2] = __uint_as_float(u.y << 16); f[3] = __uint_as_float(u.y & 0xffff0000u);
    f[4] = __uint_as_float(u.z << 16); f[5] = __uint_as_float(u.z & 0xffff0000u);
    f[6] = __uint_as_float(u.w << 16); f[7] = __uint_as_float(u.w & 0xffff0000u);
}

// ---------------------------------------------------------------- embeddings
__global__ void embed_x_kernel(const int* __restrict__ ids,
                               const float* __restrict__ emb,
                               float* __restrict__ x) {
    int idx = blockIdx.x * 256 + threadIdx.x;      // 262144
    int row = idx >> 9;
    int h   = idx & 511;
    x[idx] = emb[ids[row] * H_ + h];
}

__global__ void embed_bond_kernel(const int* __restrict__ adj,
                                  const float* __restrict__ emb,
                                  bf16* __restrict__ bond) {
    size_t idx = (size_t)blockIdx.x * 256 + threadIdx.x;  // 16.7M
    int pair = (int)(idx >> 9);
    int h    = (int)(idx & 511);
    bond[idx] = __float2bfloat16(emb[adj[pair] * H_ + h]);
}

// ------------------------------------------------- weight transpose + cast
// W [Lz][K][N] fp32 -> Wt [Lz][N][K] bf16 (layer strides passed explicitly)
__global__ void transpose_w(const float* __restrict__ W, bf16* __restrict__ Wt,
                            int K, int N, long in_ls, long out_ls) {
    __shared__ float t[32][33];
    const float* Wl = W + (size_t)blockIdx.z * in_ls;
    bf16* Wtl = Wt + (size_t)blockIdx.z * out_ls;
    int k0 = blockIdx.x * 32, n0 = blockIdx.y * 32;
    int tx = threadIdx.x, ty = threadIdx.y;  // 32, 8
    #pragma unroll
    for (int r = ty; r < 32; r += 8)
        t[r][tx] = Wl[(size_t)(k0 + r) * N + n0 + tx];
    __syncthreads();
    #pragma unroll
    for (int r = ty; r < 32; r += 8)
        Wtl[(size_t)(n0 + r) * K + k0 + tx] = __float2bfloat16(t[tx][r]);
}

// ---------------------------------------------------------------- LayerNorm
// one block (256 threads) per row of 512. OUTMODE bit0: fp32 out, bit1: bf16 out
template <int OUTMODE>
__global__ void ln_kernel(const float* __restrict__ in, float* __restrict__ out32,
                          bf16* __restrict__ out16) {
    int row = blockIdx.x;
    int tid = threadIdx.x;
    const float* r = in + (size_t)row * H_;
    float x0 = r[tid], x1 = r[tid + 256];
    float s = x0 + x1, sq = x0 * x0 + x1 * x1;
    #pragma unroll
    for (int off = 32; off; off >>= 1) {
        s  += __shfl_xor(s,  off);
        sq += __shfl_xor(sq, off);
    }
    __shared__ float ls[4], lq[4];
    int w = tid >> 6;
    if ((tid & 63) == 0) { ls[w] = s; lq[w] = sq; }
    __syncthreads();
    float S = ls[0] + ls[1] + ls[2] + ls[3];
    float Q = lq[0] + lq[1] + lq[2] + lq[3];
    float mean = S * (1.0f / H_);
    float var  = Q * (1.0f / H_) - mean * mean;
    float inv  = rsqrtf(var + 1e-5f);
    float y0 = (x0 - mean) * inv, y1 = (x1 - mean) * inv;
    if (OUTMODE & 1) {
        out32[(size_t)row * H_ + tid]       = y0;
        out32[(size_t)row * H_ + tid + 256] = y1;
    }
    if (OUTMODE & 2) {
        out16[(size_t)row * H_ + tid]       = __float2bfloat16(y0);
        out16[(size_t)row * H_ + tid + 256] = __float2bfloat16(y1);
    }
}

// ---------------------------------------------------------------- MFMA GEMM (large, 128x128)
// C[M,N] = A[M,K] @ Bt[N,K]^T, bf16 in, fp32 accum. Async global_load_lds staging,
// unpadded 64B LDS rows (builtin requires contiguous base+lane*16 layout; m97-style).
// EPI: 0 = fp32 store, 1 = fp32 store + R, 2 = relu -> bf16, 3 = bf16 store
#define BM 128
#define BN 128
#define BK 32
#define RSTR 80   // (gemm_s only) LDS row stride: 64 B data + 16 pad

template <int EPI>
__launch_bounds__(256)
__global__ void mfma_gemm(const bf16* __restrict__ A, const bf16* __restrict__ Bt,
                          void* __restrict__ Cv, const float* __restrict__ R,
                          int M, int N, int K) {
    __shared__ __align__(16) char lds[2 * BM * 64];   // 16 KB, unpadded
    char* As = lds;
    char* Bs = lds + BM * 64;
    const int tid = threadIdx.x;
    const int bm = blockIdx.x * BM, bn = blockIdx.y * BN;
    Bt += (size_t)blockIdx.z * N * K;
    const int w = tid >> 6, lane = tid & 63;
    const int wr = (w >> 1) * 64, wc = (w & 1) * 64;
    const int m0 = lane & 15, q4 = lane >> 4;

    f32x4 acc[4][4] = {};

    // staging geometry: wave w, instr t (0,1): rows w*32+t*16 .. +15, 1024 B chunk
    const int srow = lane >> 2;           // 0..15
    const int scol = (lane & 3) * 8;      // element col (16B chunks)

    for (int k0 = 0; k0 < K; k0 += BK) {
        __syncthreads();   // all waves done reading previous tile
        #pragma unroll
        for (int t = 0; t < 2; ++t) {
            gload_lds16(A  + (size_t)(bm + w * 32 + t * 16 + srow) * K + k0 + scol,
                        As + (w * 2 + t) * 1024);
            gload_lds16(Bt + (size_t)(bn + w * 32 + t * 16 + srow) * K + k0 + scol,
                        Bs + (w * 2 + t) * 1024);
        }
        __syncthreads();   // compiler drains vmcnt(0) before barrier -> tile visible
        short8 af[4], bfr[4];
        #pragma unroll
        for (int t = 0; t < 4; ++t) {
            af[t]  = *(const short8*)(As + (wr + t * 16 + m0) * 64 + q4 * 16);
            bfr[t] = *(const short8*)(Bs + (wc + t * 16 + m0) * 64 + q4 * 16);
        }
        #pragma unroll
        for (int mt = 0; mt < 4; ++mt)
            #pragma unroll
            for (int nt = 0; nt < 4; ++nt)
                acc[mt][nt] = __builtin_amdgcn_mfma_f32_16x16x32_bf16(
                    af[mt], bfr[nt], acc[mt][nt], 0, 0, 0);
    }

    // epilogue: C/D layout col = lane&15, row = quad*4 + reg  [m89/m91 verified]
    if (EPI <= 1) {
        float* C = (float*)Cv + (size_t)blockIdx.z * M * N;
        #pragma unroll
        for (int mt = 0; mt < 4; ++mt)
            #pragma unroll
            for (int i = 0; i < 4; ++i) {
                int row = bm + wr + mt * 16 + q4 * 4 + i;
                #pragma unroll
                for (int nt = 0; nt < 4; ++nt) {
                    int col = bn + wc + nt * 16 + m0;
                    float v = acc[mt][nt][i];
                    if (EPI == 1) v += R[(size_t)row * N + col];
                    C[(size_t)row * N + col] = v;
                }
            }
    } else {
        bf16* C = (bf16*)Cv;
        #pragma unroll
        for (int mt = 0; mt < 4; ++mt)
            #pragma unroll
            for (int i = 0; i < 4; ++i) {
                int row = bm + wr + mt * 16 + q4 * 4 + i;
                #pragma unroll
                for (int nt = 0; nt < 4; ++nt) {
                    int col = bn + wc + nt * 16 + m0;
                    float v = acc[mt][nt][i];
                    if (EPI == 2) v = fmaxf(v, 0.0f);
                    C[(size_t)row * N + col] = __float2bfloat16(v);
                }
            }
    }
}

// ------------------------------------------- MFMA GEMM (small, 64x64, BK=64)
// 4 waves as 2x2; each wave 32x32 = 2x2 frags of 16x16x32. RSTR=80 padded LDS.
// SPLIT=false: blockIdx.z = weight/output slice (fused qkv).
// SPLIT=true:  blockIdx.z = K-split slice s; fp32 partial to Cv[s*M*N + ...].
template <int EPI, bool SPLIT>
__launch_bounds__(256)
__global__ void mfma_gemm_s(const bf16* __restrict__ A, const bf16* __restrict__ Bt,
                            void* __restrict__ Cv, const float* __restrict__ R,
                            int M, int N, int K) {
    __shared__ __align__(16) char lds[4 * 64 * RSTR];   // 20 KB
    char* As = lds;
    char* Bs = lds + 2 * 64 * RSTR;
    const int tid = threadIdx.x;
    const int bm = blockIdx.x * 64, bn = blockIdx.y * 64;
    int kbeg = 0, kend = K;
    if (SPLIT) {
        int ks = K / gridDim.z;
        kbeg = blockIdx.z * ks;
        kend = kbeg + ks;
    } else {
        Bt += (size_t)blockIdx.z * N * K;
    }
    const int w = tid >> 6, lane = tid & 63;
    const int wr = (w >> 1) * 32, wc = (w & 1) * 32;
    const int m0 = lane & 15, q4 = lane >> 4;

    f32x4 acc[2][2] = {};

    const int rA = tid >> 3;              // 0..31
    const int cA = tid & 7;
    const int ksP = cA >> 2;              // K-plane
    const int cB = (cA & 3) * 16;
    const int cE = cA * 8;

    for (int k0 = kbeg; k0 < kend; k0 += 64) {
        uint4 a0 = *(const uint4*)(A  + (size_t)(bm + rA) * K + k0 + cE);
        uint4 a1 = *(const uint4*)(A  + (size_t)(bm + rA + 32) * K + k0 + cE);
        uint4 b0 = *(const uint4*)(Bt + (size_t)(bn + rA) * K + k0 + cE);
        uint4 b1 = *(const uint4*)(Bt + (size_t)(bn + rA + 32) * K + k0 + cE);
        __syncthreads();
        *(uint4*)(As + ksP * (64 * RSTR) + rA * RSTR + cB) = a0;
        *(uint4*)(As + ksP * (64 * RSTR) + (rA + 32) * RSTR + cB) = a1;
        *(uint4*)(Bs + ksP * (64 * RSTR) + rA * RSTR + cB) = b0;
        *(uint4*)(Bs + ksP * (64 * RSTR) + (rA + 32) * RSTR + cB) = b1;
        __syncthreads();
        short8 af[2][2], bfr[2][2];
        #pragma unroll
        for (int ks = 0; ks < 2; ++ks)
            #pragma unroll
            for (int t = 0; t < 2; ++t) {
                af[ks][t]  = *(const short8*)(As + ks * (64 * RSTR) + (wr + t * 16 + m0) * RSTR + q4 * 16);
                bfr[ks][t] = *(const short8*)(Bs + ks * (64 * RSTR) + (wc + t * 16 + m0) * RSTR + q4 * 16);
            }
        #pragma unroll
        for (int ks = 0; ks < 2; ++ks)
            #pragma unroll
            for (int mt = 0; mt < 2; ++mt)
                #pragma unroll
                for (int nt = 0; nt < 2; ++nt)
                    acc[mt][nt] = __builtin_amdgcn_mfma_f32_16x16x32_bf16(
                        af[ks][mt], bfr[ks][nt], acc[mt][nt], 0, 0, 0);
    }

    if (SPLIT) {
        float* C = (float*)Cv + (size_t)blockIdx.z * M * N;
        #pragma unroll
        for (int mt = 0; mt < 2; ++mt)
            #pragma unroll
            for (int i = 0; i < 4; ++i) {
                int row = bm + wr + mt * 16 + q4 * 4 + i;
                #pragma unroll
                for (int nt = 0; nt < 2; ++nt)
                    C[(size_t)row * N + bn + wc + nt * 16 + m0] = acc[mt][nt][i];
            }
    } else if (EPI <= 1) {
        float* C = (float*)Cv + (size_t)blockIdx.z * M * N;
        #pragma unroll
        for (int mt = 0; mt < 2; ++mt)
            #pragma unroll
            for (int i = 0; i < 4; ++i) {
                int row = bm + wr + mt * 16 + q4 * 4 + i;
                #pragma unroll
                for (int nt = 0; nt < 2; ++nt) {
                    int col = bn + wc + nt * 16 + m0;
                    float v = acc[mt][nt][i];
                    if (EPI == 1) v += R[(size_t)row * N + col];
                    C[(size_t)row * N + col] = v;
                }
            }
    } else {
        bf16* C = (bf16*)Cv;
        #pragma unroll
        for (int mt = 0; mt < 2; ++mt)
            #pragma unroll
            for (int i = 0; i < 4; ++i) {
                int row = bm + wr + mt * 16 + q4 * 4 + i;
                #pragma unroll
                for (int nt = 0; nt < 2; ++nt) {
                    int col = bn + wc + nt * 16 + m0;
                    float v = acc[mt][nt][i];
                    if (EPI == 2) v = fmaxf(v, 0.0f);
                    C[(size_t)row * N + col] = __float2bfloat16(v);
                }
            }
    }
}

// out = sum_s part[s] (+ R), fp32
__global__ void reduce_add(const float* __restrict__ part, const float* __restrict__ R,
                           float* __restrict__ out, int MN, int S) {
    int i = blockIdx.x * 256 + threadIdx.x;
    if (i >= MN) return;
    float v = R ? R[i] : 0.0f;
    for (int s = 0; s < S; ++s) v += part[(size_t)s * MN + i];
    out[i] = v;
}

// ---------------------------------------------------------------- attention
// block = (b,i) x 4 heads (64x4 threads); wave ty owns head h = by*4+ty.
// lane j: vectorized q.(k_j + w_ij) dot; softmax via shuffles; PV coalesced.
__global__ void attn_kernel(const float* __restrict__ qkv, const bf16* __restrict__ ew,
                            const int* __restrict__ adj, bf16* __restrict__ o) {
    const float* q = qkv;
    const float* k = qkv + (size_t)512 * H_;
    const float* v = qkv + (size_t)1024 * H_;
    int bi = blockIdx.x;           // b*64 + i
    int b  = bi >> 6;
    int ty = threadIdx.y;
    int h  = blockIdx.y * 4 + ty;
    int lane = threadIdx.x;        // 64
    __shared__ float qs[4][64], as[4][64];
    qs[ty][lane] = q[(size_t)bi * H_ + h * 64 + lane];
    __syncthreads();

    int j = lane;
    const float4* k4 = (const float4*)(k + (size_t)(b * 64 + j) * H_ + h * 64);
    const uint4*  w4 = (const uint4*)(ew + ((size_t)bi * 64 + j) * H_ + h * 64);
    float acc = 0.f;
    #pragma unroll
    for (int t = 0; t < 8; ++t) {
        uint4 wu = w4[t];
        float4 ka = k4[2 * t], kb = k4[2 * t + 1];
        float wf[8];
        unpack8(wu, wf);
        const float* qq = &qs[ty][t * 8];
        acc += qq[0] * (ka.x + wf[0]) + qq[1] * (ka.y + wf[1])
             + qq[2] * (ka.z + wf[2]) + qq[3] * (ka.w + wf[3])
             + qq[4] * (kb.x + wf[4]) + qq[5] * (kb.y + wf[5])
             + qq[6] * (kb.z + wf[6]) + qq[7] * (kb.w + wf[7]);
    }
    float logit = acc * INV_SCALE;
    if (adj[(size_t)bi * 64 + j] <= 0) logit = -INFINITY;

    float m = logit;
    #pragma unroll
    for (int off = 32; off; off >>= 1) m = fmaxf(m, __shfl_xor(m, off));
    float p = expf(logit - m);
    float s = p;
    #pragma unroll
    for (int off = 32; off; off >>= 1) s += __shfl_xor(s, off);
    as[ty][lane] = p / s;
    __syncthreads();

    const float* vbase = v + (size_t)(b * 64) * H_ + h * 64;
    float oacc = 0.f;
    int d = lane;
    #pragma unroll 8
    for (int jj = 0; jj < 64; ++jj)
        oacc += as[ty][jj] * vbase[(size_t)jj * H_ + d];
    o[(size_t)bi * H_ + h * 64 + d] = __float2bfloat16(oacc);
}

// ---------------------------------------------------------------- edge update
// block (64,4): wave ty owns pair blockIdx.x*4+ty; lane owns elems [8*lane, 8*lane+8)
__global__ void edge_kernel(const bf16* __restrict__ ew, const float* __restrict__ x,
                            bf16* __restrict__ bond) {
    int pair = blockIdx.x * 4 + threadIdx.y;   // (b*64+i)*64 + j
    int b = pair >> 12;
    int i = (pair >> 6) & 63;
    int j = pair & 63;
    int lane = threadIdx.x;
    const uint4*  e4  = (const uint4*)(ew + (size_t)pair * H_);
    const float4* xi4 = (const float4*)(x + (size_t)(b * 64 + i) * H_);
    const float4* xj4 = (const float4*)(x + (size_t)(b * 64 + j) * H_);
    uint4  eu = e4[lane];
    float4 a0 = xi4[lane * 2], a1 = xi4[lane * 2 + 1];
    float4 c0 = xj4[lane * 2], c1 = xj4[lane * 2 + 1];
    float ef[8], af[8], cf[8];
    unpack8(eu, ef);
    af[0] = a0.x; af[1] = a0.y; af[2] = a0.z; af[3] = a0.w;
    af[4] = a1.x; af[5] = a1.y; af[6] = a1.z; af[7] = a1.w;
    cf[0] = c0.x; cf[1] = c0.y; cf[2] = c0.z; cf[3] = c0.w;
    cf[4] = c1.x; cf[5] = c1.y; cf[6] = c1.z; cf[7] = c1.w;
    float s0 = 0.f, s1 = 0.f, s2 = 0.f;
    #pragma unroll
    for (int t = 0; t < 8; ++t) {
        s0 += ef[t] * ef[t]; s1 += ef[t] * af[t]; s2 += ef[t] * cf[t];
    }
    #pragma unroll
    for (int off = 32; off; off >>= 1) {
        s0 += __shfl_xor(s0, off);
        s1 += __shfl_xor(s1, off);
        s2 += __shfl_xor(s2, off);
    }
    float t0 = s0 * INV_SCALE, t1 = s1 * INV_SCALE, t2 = s2 * INV_SCALE;
    float m = fmaxf(t0, fmaxf(t1, t2));
    float e0 = expf(t0 - m), e1 = expf(t1 - m), e2 = expf(t2 - m);
    float inv = 1.0f / (e0 + e1 + e2);
    float w0 = e0 * inv, w1 = e1 * inv, w2 = e2 * inv;
    __align__(16) bf16 ob[8];
    #pragma unroll
    for (int t = 0; t < 8; ++t)
        ob[t] = __float2bfloat16(w0 * ef[t] + w1 * af[t] + w2 * cf[t]);
    *(uint4*)(bond + (size_t)pair * H_ + lane * 8) = *(const uint4*)ob;
}

// ---------------------------------------------------------------- head
__global__ void cls_kernel(const float* __restrict__ x, const float* __restrict__ Wout,
                           float* __restrict__ cls) {
    int b = blockIdx.x, cc = blockIdx.y;
    int col = cc * 64 + threadIdx.x;
    const float* xr = x + (size_t)(b * 64) * H_;   // x[b,0,:]
    float acc = 0.f;
    for (int h = 0; h < H_; ++h)
        acc += xr[h] * Wout[(size_t)h * H_ + col];
    cls[b * H_ + col] = tanhf(acc);
}

__global__ void pred_kernel(const float* __restrict__ cls, const float* __restrict__ Wpred,
                            const float* __restrict__ bpred, float* __restrict__ out) {
    int b = blockIdx.x;
    int lane = threadIdx.x;
    const float* c = cls + (size_t)b * H_;
    float a0 = 0.f, a1 = 0.f;
    for (int h = lane; h < H_; h += 64) {
        float cvv = c[h];
        a0 += cvv * Wpred[h * 2 + 0];
        a1 += cvv * Wpred[h * 2 + 1];
    }
    #pragma unroll
    for (int off = 32; off; off >>= 1) {
        a0 += __shfl_xor(a0, off);
        a1 += __shfl_xor(a1, off);
    }
    if (lane == 0) {
        a0 += bpred[0];
        a1 += bpred[1];
        float m = fmaxf(a0, a1);
        float e0 = expf(a0 - m), e1 = expf(a1 - m);
        float inv = 1.0f / (e0 + e1);
        out[b * 2 + 0] = e0 * inv;
        out[b * 2 + 1] = e1 * inv;
    }
}

// ---------------------------------------------------------------- launch
extern "C" void kernel_launch(void* const* d_in, const int* in_sizes, int n_in,
                              void* d_out, int out_size, void* d_ws, size_t ws_size,
                              hipStream_t stream) {
    const int*   ids      = (const int*)d_in[0];
    const int*   adj      = (const int*)d_in[1];
    const float* atom_emb = (const float*)d_in[2];
    const float* bond_emb = (const float*)d_in[3];
    const float* Wq     = (const float*)d_in[4];
    const float* Wk     = (const float*)d_in[5];
    const float* Wv     = (const float*)d_in[6];
    const float* Wew    = (const float*)d_in[7];
    const float* Wstack = (const float*)d_in[8];
    const float* Wf1    = (const float*)d_in[9];
    const float* Wf2    = (const float*)d_in[10];
    const float* Wout   = (const float*)d_in[11];
    const float* Wpred  = (const float*)d_in[12];
    const float* bpred  = (const float*)d_in[13];

    char* ws = (char*)d_ws;
    size_t off = 0;
    auto alloc = [&](size_t bytes) {
        size_t o = off;
        off += (bytes + 255) & ~(size_t)255;
        return o;
    };
    const size_t ROWS  = (size_t)B_ * N_;           // 512
    const size_t PAIRS = (size_t)B_ * N_ * N_;      // 32768
    const size_t KN    = (size_t)H_ * H_;           // 262144

    float* x       = (float*)(ws + alloc(ROWS * H_ * 4));
    float* xn      = (float*)(ws + alloc(ROWS * H_ * 4));
    bf16*  xn_bf   = (bf16*) (ws + alloc(ROWS * H_ * 2));
    float* qkv     = (float*)(ws + alloc(3 * ROWS * H_ * 4));
    bf16*  o_bf    = (bf16*) (ws + alloc(ROWS * H_ * 2));
    float* resid   = (float*)(ws + alloc(ROWS * H_ * 4));
    bf16*  ffin_bf = (bf16*) (ws + alloc(ROWS * H_ * 2));
    bf16*  ffh_bf  = (bf16*) (ws + alloc(ROWS * 4 * H_ * 2));
    float* part    = (float*)(ws + alloc(4 * ROWS * H_ * 4));   // split-K partials
    float* cls     = (float*)(ws + alloc((size_t)B_ * H_ * 4));
    bf16*  bond    = (bf16*) (ws + alloc(PAIRS * H_ * 2));      // 32 MB
    bf16*  ew      = (bf16*) (ws + alloc(PAIRS * H_ * 2));      // 32 MB
    bf16*  qkvt    = (bf16*) (ws + alloc((size_t)L_ * 3 * KN * 2));
    bf16*  ewt     = (bf16*) (ws + alloc((size_t)L_ * KN * 2));
    bf16*  stackt  = (bf16*) (ws + alloc((size_t)L_ * KN * 2));
    bf16*  f1t     = (bf16*) (ws + alloc((size_t)L_ * 4 * KN * 2));
    bf16*  f2t     = (bf16*) (ws + alloc((size_t)L_ * 4 * KN * 2));
    (void)ws_size;

    embed_x_kernel<<<1024, 256, 0, stream>>>(ids, atom_emb, x);
    embed_bond_kernel<<<65536, 256, 0, stream>>>(adj, bond_emb, bond);

    // one-time weight transpose + bf16 cast
    dim3 tb(32, 8);
    transpose_w<<<dim3(16, 16, 4), tb, 0, stream>>>(Wq, qkvt + 0 * KN, 512, 512, KN, 3 * KN);
    transpose_w<<<dim3(16, 16, 4), tb, 0, stream>>>(Wk, qkvt + 1 * KN, 512, 512, KN, 3 * KN);
    transpose_w<<<dim3(16, 16, 4), tb, 0, stream>>>(Wv, qkvt + 2 * KN, 512, 512, KN, 3 * KN);
    transpose_w<<<dim3(16, 16, 4), tb, 0, stream>>>(Wew, ewt, 512, 512, KN, KN);
    transpose_w<<<dim3(16, 16, 4), tb, 0, stream>>>(Wstack, stackt, 512, 512, KN, KN);
    transpose_w<<<dim3(16, 64, 4), tb, 0, stream>>>(Wf1, f1t, 512, 2048, 4 * KN, 4 * KN);
    transpose_w<<<dim3(64, 16, 4), tb, 0, stream>>>(Wf2, f2t, 2048, 512, 4 * KN, 4 * KN);

    for (int l = 0; l < L_; ++l) {
        ln_kernel<3><<<512, 256, 0, stream>>>(x, xn, xn_bf);
        // q,k,v fused small-tile: z selects weight slice and output slice
        mfma_gemm_s<0, false><<<dim3(8, 8, 3), 256, 0, stream>>>(
            xn_bf, qkvt + (size_t)l * 3 * KN, qkv, nullptr, 512, 512, 512);
        // ew = bond @ Wew (1024 blocks, async staging)
        mfma_gemm<3><<<dim3(256, 4), 256, 0, stream>>>(
            bond, ewt + (size_t)l * KN, ew, nullptr, 32768, 512, 512);
        attn_kernel<<<dim3(512, 2), dim3(64, 4), 0, stream>>>(qkv, ew, adj, o_bf);
        // resid = o @ Wstack + xn
        mfma_gemm_s<1, false><<<dim3(8, 8), 256, 0, stream>>>(
            o_bf, stackt + (size_t)l * KN, resid, xn, 512, 512, 512);
        ln_kernel<2><<<512, 256, 0, stream>>>(resid, nullptr, ffin_bf);
        // ffh = relu(ffin @ Wf1)
        mfma_gemm_s<2, false><<<dim3(8, 32), 256, 0, stream>>>(
            ffin_bf, f1t + (size_t)l * 4 * KN, ffh_bf, nullptr, 512, 2048, 512);
        // x = ffh @ Wf2 + resid : split-K x4 + reduce
        mfma_gemm_s<0, true><<<dim3(8, 8, 4), 256, 0, stream>>>(
            ffh_bf, f2t + (size_t)l * 4 * KN, part, nullptr, 512, 512, 2048);
        reduce_add<<<1024, 256, 0, stream>>>(part, resid, x, 512 * 512, 4);
        edge_kernel<<<8192, dim3(64, 4), 0, stream>>>(ew, x, bond);
    }

    cls_kernel<<<dim3(8, 8), 64, 0, stream>>>(x, Wout, cls);
    pred_kernel<<<8, 64, 0, stream>>>(cls, Wpred, bpred, (float*)d_out);
}

// Round 6
// 600.383 us; speedup vs baseline: 4.5018x; 1.0212x over previous
//
#include <hip/hip_runtime.h>
#include <hip/hip_bf16.h>

typedef __hip_bfloat16 bf16;

// Problem constants
#define B_     8
#define N_     64
#define H_     512
#define HEADS_ 8
#define SP_    64
#define L_     4
static constexpr float INV_SCALE = 0.044194173824159216f; // 1/sqrt(512)

// MFMA fragment types (per guide §3: short8 = 8 bf16 = 4 VGPRs)
typedef __attribute__((ext_vector_type(8))) short short8;
typedef __attribute__((ext_vector_type(4))) float f32x4;

// async global->LDS, 16B per lane; LDS dest is wave-uniform base + lane*16
__device__ __forceinline__ void gload_lds16(const void* g, void* l) {
    __builtin_amdgcn_global_load_lds(
        (const __attribute__((address_space(1))) unsigned int*)g,
        (__attribute__((address_space(3))) unsigned int*)l, 16, 0, 0);
}

__device__ __forceinline__ void unpack8(uint4 u, float* f) {
    f[0] = __uint_as_float(u.x << 16); f[1] = __uint_as_float(u.x & 0xffff0000u);
    f[2] = __uint_as_float(u.y << 16); f[3] = __uint_as_float(u.y & 0xffff0000u);
    f[4] = __uint_as_float(u.z << 16); f[5] = __uint_as_float(u.z & 0xffff0000u);
    f[6] = __uint_as_float(u.w << 16); f[7] = __uint_as_float(u.w & 0xffff0000u);
}

__device__ __forceinline__ bf16 f2bf(float v) { return __float2bfloat16(v); }

// ---------------------------------------------------------------- embeddings
// bond gather: 8 elems/thread; 2x float4 read -> uint4 bf16 write
__global__ void embed_bond_kernel(const int* __restrict__ adj,
                                  const float* __restrict__ emb,
                                  bf16* __restrict__ bond) {
    int gid = blockIdx.x * 256 + threadIdx.x;      // 2,097,152 total
    int pair = gid >> 6;
    int c    = gid & 63;
    const float4* e4 = (const float4*)(emb + (size_t)adj[pair] * H_) + c * 2;
    float4 f0 = e4[0], f1 = e4[1];
    __align__(16) bf16 ob[8];
    ob[0] = f2bf(f0.x); ob[1] = f2bf(f0.y); ob[2] = f2bf(f0.z); ob[3] = f2bf(f0.w);
    ob[4] = f2bf(f1.x); ob[5] = f2bf(f1.y); ob[6] = f2bf(f1.z); ob[7] = f2bf(f1.w);
    *(uint4*)(bond + (size_t)pair * H_ + c * 8) = *(const uint4*)ob;
}

// fused: x = atom_emb[ids[row]]; LN -> xn (fp32), xn_bf (bf16). x never stored.
__global__ void embed_ln_kernel(const int* __restrict__ ids,
                                const float* __restrict__ emb,
                                float* __restrict__ xn, bf16* __restrict__ xn_bf) {
    int row = blockIdx.x;
    int tid = threadIdx.x;
    const float* r = emb + (size_t)ids[row] * H_;
    float x0 = r[tid], x1 = r[tid + 256];
    float s = x0 + x1, sq = x0 * x0 + x1 * x1;
    #pragma unroll
    for (int off = 32; off; off >>= 1) {
        s  += __shfl_xor(s,  off);
        sq += __shfl_xor(sq, off);
    }
    __shared__ float ls[4], lq[4];
    int w = tid >> 6;
    if ((tid & 63) == 0) { ls[w] = s; lq[w] = sq; }
    __syncthreads();
    float S = ls[0] + ls[1] + ls[2] + ls[3];
    float Q = lq[0] + lq[1] + lq[2] + lq[3];
    float mean = S * (1.0f / H_);
    float var  = Q * (1.0f / H_) - mean * mean;
    float inv  = rsqrtf(var + 1e-5f);
    float y0 = (x0 - mean) * inv, y1 = (x1 - mean) * inv;
    xn[(size_t)row * H_ + tid]       = y0;
    xn[(size_t)row * H_ + tid + 256] = y1;
    xn_bf[(size_t)row * H_ + tid]       = f2bf(y0);
    xn_bf[(size_t)row * H_ + tid + 256] = f2bf(y1);
}

// ------------------------------------------------- weight transpose + cast
// square 512x512 set: z<12: qkv (slot=z/4, layer=z%4); z in [12,16): Wew; [16,20): Wstack
__global__ void transpose_sq(const float* __restrict__ Wq, const float* __restrict__ Wk,
                             const float* __restrict__ Wv, const float* __restrict__ Wew,
                             const float* __restrict__ Wst,
                             bf16* __restrict__ qkvt, bf16* __restrict__ ewt,
                             bf16* __restrict__ stackt) {
    const size_t KN = (size_t)H_ * H_;
    int z = blockIdx.z;
    const float* W; bf16* Wt;
    if (z < 12) {
        int s = z >> 2, l = z & 3;
        W  = (s == 0 ? Wq : s == 1 ? Wk : Wv) + (size_t)l * KN;
        Wt = qkvt + (size_t)l * 3 * KN + (size_t)s * KN;
    } else if (z < 16) {
        int l = z - 12;
        W = Wew + (size_t)l * KN; Wt = ewt + (size_t)l * KN;
    } else {
        int l = z - 16;
        W = Wst + (size_t)l * KN; Wt = stackt + (size_t)l * KN;
    }
    __shared__ float t[32][33];
    int k0 = blockIdx.x * 32, n0 = blockIdx.y * 32;
    int tx = threadIdx.x, ty = threadIdx.y;  // 32, 8
    #pragma unroll
    for (int r = ty; r < 32; r += 8)
        t[r][tx] = W[(size_t)(k0 + r) * H_ + n0 + tx];
    __syncthreads();
    #pragma unroll
    for (int r = ty; r < 32; r += 8)
        Wt[(size_t)(n0 + r) * H_ + k0 + tx] = f2bf(t[tx][r]);
}

// rect set: z<4: Wf1 layer z (512x2048); z>=4: Wf2 layer z-4 (2048x512). grid (64,64,8)
__global__ void transpose_rect(const float* __restrict__ Wf1, const float* __restrict__ Wf2,
                               bf16* __restrict__ f1t, bf16* __restrict__ f2t) {
    const size_t KN4 = (size_t)4 * H_ * H_;
    int z = blockIdx.z;
    const float* W; bf16* Wt; int K, N;
    if (z < 4) {
        if (blockIdx.x >= 16) return;          // K=512 -> 16 tiles
        W = Wf1 + (size_t)z * KN4; Wt = f1t + (size_t)z * KN4; K = 512; N = 2048;
    } else {
        if (blockIdx.y >= 16) return;          // N=512 -> 16 tiles
        W = Wf2 + (size_t)(z - 4) * KN4; Wt = f2t + (size_t)(z - 4) * KN4; K = 2048; N = 512;
    }
    __shared__ float t[32][33];
    int k0 = blockIdx.x * 32, n0 = blockIdx.y * 32;
    int tx = threadIdx.x, ty = threadIdx.y;
    #pragma unroll
    for (int r = ty; r < 32; r += 8)
        t[r][tx] = W[(size_t)(k0 + r) * N + n0 + tx];
    __syncthreads();
    #pragma unroll
    for (int r = ty; r < 32; r += 8)
        Wt[(size_t)(n0 + r) * K + k0 + tx] = f2bf(t[tx][r]);
}

// ---------------------------------------------------------------- LayerNorm (mid-layer)
// one block per row of 512; bf16 out only
__global__ void ln_bf_kernel(const float* __restrict__ in, bf16* __restrict__ out16) {
    int row = blockIdx.x;
    int tid = threadIdx.x;
    const float* r = in + (size_t)row * H_;
    float x0 = r[tid], x1 = r[tid + 256];
    float s = x0 + x1, sq = x0 * x0 + x1 * x1;
    #pragma unroll
    for (int off = 32; off; off >>= 1) {
        s  += __shfl_xor(s,  off);
        sq += __shfl_xor(sq, off);
    }
    __shared__ float ls[4], lq[4];
    int w = tid >> 6;
    if ((tid & 63) == 0) { ls[w] = s; lq[w] = sq; }
    __syncthreads();
    float S = ls[0] + ls[1] + ls[2] + ls[3];
    float Q = lq[0] + lq[1] + lq[2] + lq[3];
    float mean = S * (1.0f / H_);
    float var  = Q * (1.0f / H_) - mean * mean;
    float inv  = rsqrtf(var + 1e-5f);
    out16[(size_t)row * H_ + tid]       = f2bf((x0 - mean) * inv);
    out16[(size_t)row * H_ + tid + 256] = f2bf((x1 - mean) * inv);
}

// ------------------------- split-K reduce (+resid) fused with next-layer LN
// one block per row. x = resid + sum_s part[s]; if DO_LN also xn, xn_bf = LN(x)
template <bool DO_LN>
__global__ void reduce_ln_kernel(const float* __restrict__ part, const float* __restrict__ resid,
                                 float* __restrict__ x, float* __restrict__ xn,
                                 bf16* __restrict__ xn_bf) {
    const int MN = 512 * H_;
    int row = blockIdx.x;
    int tid = threadIdx.x;
    size_t base = (size_t)row * H_;
    float v0 = resid[base + tid], v1 = resid[base + tid + 256];
    #pragma unroll
    for (int s = 0; s < 4; ++s) {
        v0 += part[(size_t)s * MN + base + tid];
        v1 += part[(size_t)s * MN + base + tid + 256];
    }
    x[base + tid] = v0;
    x[base + tid + 256] = v1;
    if (DO_LN) {
        float s = v0 + v1, sq = v0 * v0 + v1 * v1;
        #pragma unroll
        for (int off = 32; off; off >>= 1) {
            s  += __shfl_xor(s,  off);
            sq += __shfl_xor(sq, off);
        }
        __shared__ float ls[4], lq[4];
        int w = tid >> 6;
        if ((tid & 63) == 0) { ls[w] = s; lq[w] = sq; }
        __syncthreads();
        float S = ls[0] + ls[1] + ls[2] + ls[3];
        float Q = lq[0] + lq[1] + lq[2] + lq[3];
        float mean = S * (1.0f / H_);
        float var  = Q * (1.0f / H_) - mean * mean;
        float inv  = rsqrtf(var + 1e-5f);
        float y0 = (v0 - mean) * inv, y1 = (v1 - mean) * inv;
        xn[base + tid]       = y0;
        xn[base + tid + 256] = y1;
        xn_bf[base + tid]       = f2bf(y0);
        xn_bf[base + tid + 256] = f2bf(y1);
    }
}

// ---------------------------------------------------------------- MFMA GEMM (large, 128x128)
// C[M,N] = A[M,K] @ Bt[N,K]^T, bf16 in, fp32 accum. Async global_load_lds staging,
// unpadded 64B LDS rows (builtin requires contiguous base+lane*16 layout; m97-style).
// EPI: 0 = fp32 store, 1 = fp32 store + R, 2 = relu -> bf16, 3 = bf16 store
#define BM 128
#define BN 128
#define BK 32
#define RSTR 80   // (gemm_s only) LDS row stride: 64 B data + 16 pad

template <int EPI>
__launch_bounds__(256)
__global__ void mfma_gemm(const bf16* __restrict__ A, const bf16* __restrict__ Bt,
                          void* __restrict__ Cv, const float* __restrict__ R,
                          int M, int N, int K) {
    __shared__ __align__(16) char lds[2 * BM * 64];   // 16 KB, unpadded
    char* As = lds;
    char* Bs = lds + BM * 64;
    const int tid = threadIdx.x;
    const int bm = blockIdx.x * BM, bn = blockIdx.y * BN;
    Bt += (size_t)blockIdx.z * N * K;
    const int w = tid >> 6, lane = tid & 63;
    const int wr = (w >> 1) * 64, wc = (w & 1) * 64;
    const int m0 = lane & 15, q4 = lane >> 4;

    f32x4 acc[4][4] = {};

    const int srow = lane >> 2;           // 0..15
    const int scol = (lane & 3) * 8;      // element col (16B chunks)

    for (int k0 = 0; k0 < K; k0 += BK) {
        __syncthreads();   // all waves done reading previous tile
        #pragma unroll
        for (int t = 0; t < 2; ++t) {
            gload_lds16(A  + (size_t)(bm + w * 32 + t * 16 + srow) * K + k0 + scol,
                        As + (w * 2 + t) * 1024);
            gload_lds16(Bt + (size_t)(bn + w * 32 + t * 16 + srow) * K + k0 + scol,
                        Bs + (w * 2 + t) * 1024);
        }
        __syncthreads();   // compiler drains vmcnt(0) before barrier -> tile visible
        short8 af[4], bfr[4];
        #pragma unroll
        for (int t = 0; t < 4; ++t) {
            af[t]  = *(const short8*)(As + (wr + t * 16 + m0) * 64 + q4 * 16);
            bfr[t] = *(const short8*)(Bs + (wc + t * 16 + m0) * 64 + q4 * 16);
        }
        #pragma unroll
        for (int mt = 0; mt < 4; ++mt)
            #pragma unroll
            for (int nt = 0; nt < 4; ++nt)
                acc[mt][nt] = __builtin_amdgcn_mfma_f32_16x16x32_bf16(
                    af[mt], bfr[nt], acc[mt][nt], 0, 0, 0);
    }

    // epilogue: C/D layout col = lane&15, row = quad*4 + reg  [m89/m91 verified]
    if (EPI <= 1) {
        float* C = (float*)Cv + (size_t)blockIdx.z * M * N;
        #pragma unroll
        for (int mt = 0; mt < 4; ++mt)
            #pragma unroll
            for (int i = 0; i < 4; ++i) {
                int row = bm + wr + mt * 16 + q4 * 4 + i;
                #pragma unroll
                for (int nt = 0; nt < 4; ++nt) {
                    int col = bn + wc + nt * 16 + m0;
                    float v = acc[mt][nt][i];
                    if (EPI == 1) v += R[(size_t)row * N + col];
                    C[(size_t)row * N + col] = v;
                }
            }
    } else {
        bf16* C = (bf16*)Cv;
        #pragma unroll
        for (int mt = 0; mt < 4; ++mt)
            #pragma unroll
            for (int i = 0; i < 4; ++i) {
                int row = bm + wr + mt * 16 + q4 * 4 + i;
                #pragma unroll
                for (int nt = 0; nt < 4; ++nt) {
                    int col = bn + wc + nt * 16 + m0;
                    float v = acc[mt][nt][i];
                    if (EPI == 2) v = fmaxf(v, 0.0f);
                    C[(size_t)row * N + col] = __float2bfloat16(v);
                }
            }
    }
}

// ------------------------------------------- MFMA GEMM (small, 64x64, BK=64)
// 4 waves as 2x2; each wave 32x32 = 2x2 frags of 16x16x32. RSTR=80 padded LDS.
// SPLIT=false: blockIdx.z = weight/output slice (fused qkv).
// SPLIT=true:  blockIdx.z = K-split slice s; fp32 partial to Cv[s*M*N + ...].
template <int EPI, bool SPLIT>
__launch_bounds__(256)
__global__ void mfma_gemm_s(const bf16* __restrict__ A, const bf16* __restrict__ Bt,
                            void* __restrict__ Cv, const float* __restrict__ R,
                            int M, int N, int K) {
    __shared__ __align__(16) char lds[4 * 64 * RSTR];   // 20 KB
    char* As = lds;
    char* Bs = lds + 2 * 64 * RSTR;
    const int tid = threadIdx.x;
    const int bm = blockIdx.x * 64, bn = blockIdx.y * 64;
    int kbeg = 0, kend = K;
    if (SPLIT) {
        int ks = K / gridDim.z;
        kbeg = blockIdx.z * ks;
        kend = kbeg + ks;
    } else {
        Bt += (size_t)blockIdx.z * N * K;
    }
    const int w = tid >> 6, lane = tid & 63;
    const int wr = (w >> 1) * 32, wc = (w & 1) * 32;
    const int m0 = lane & 15, q4 = lane >> 4;

    f32x4 acc[2][2] = {};

    const int rA = tid >> 3;              // 0..31
    const int cA = tid & 7;
    const int ksP = cA >> 2;              // K-plane
    const int cB = (cA & 3) * 16;
    const int cE = cA * 8;

    for (int k0 = kbeg; k0 < kend; k0 += 64) {
        uint4 a0 = *(const uint4*)(A  + (size_t)(bm + rA) * K + k0 + cE);
        uint4 a1 = *(const uint4*)(A  + (size_t)(bm + rA + 32) * K + k0 + cE);
        uint4 b0 = *(const uint4*)(Bt + (size_t)(bn + rA) * K + k0 + cE);
        uint4 b1 = *(const uint4*)(Bt + (size_t)(bn + rA + 32) * K + k0 + cE);
        __syncthreads();
        *(uint4*)(As + ksP * (64 * RSTR) + rA * RSTR + cB) = a0;
        *(uint4*)(As + ksP * (64 * RSTR) + (rA + 32) * RSTR + cB) = a1;
        *(uint4*)(Bs + ksP * (64 * RSTR) + rA * RSTR + cB) = b0;
        *(uint4*)(Bs + ksP * (64 * RSTR) + (rA + 32) * RSTR + cB) = b1;
        __syncthreads();
        short8 af[2][2], bfr[2][2];
        #pragma unroll
        for (int ks = 0; ks < 2; ++ks)
            #pragma unroll
            for (int t = 0; t < 2; ++t) {
                af[ks][t]  = *(const short8*)(As + ks * (64 * RSTR) + (wr + t * 16 + m0) * RSTR + q4 * 16);
                bfr[ks][t] = *(const short8*)(Bs + ks * (64 * RSTR) + (wc + t * 16 + m0) * RSTR + q4 * 16);
            }
        #pragma unroll
        for (int ks = 0; ks < 2; ++ks)
            #pragma unroll
            for (int mt = 0; mt < 2; ++mt)
                #pragma unroll
                for (int nt = 0; nt < 2; ++nt)
                    acc[mt][nt] = __builtin_amdgcn_mfma_f32_16x16x32_bf16(
                        af[ks][mt], bfr[ks][nt], acc[mt][nt], 0, 0, 0);
    }

    if (SPLIT) {
        float* C = (float*)Cv + (size_t)blockIdx.z * M * N;
        #pragma unroll
        for (int mt = 0; mt < 2; ++mt)
            #pragma unroll
            for (int i = 0; i < 4; ++i) {
                int row = bm + wr + mt * 16 + q4 * 4 + i;
                #pragma unroll
                for (int nt = 0; nt < 2; ++nt)
                    C[(size_t)row * N + bn + wc + nt * 16 + m0] = acc[mt][nt][i];
            }
    } else if (EPI <= 1) {
        float* C = (float*)Cv + (size_t)blockIdx.z * M * N;
        #pragma unroll
        for (int mt = 0; mt < 2; ++mt)
            #pragma unroll
            for (int i = 0; i < 4; ++i) {
                int row = bm + wr + mt * 16 + q4 * 4 + i;
                #pragma unroll
                for (int nt = 0; nt < 2; ++nt) {
                    int col = bn + wc + nt * 16 + m0;
                    float v = acc[mt][nt][i];
                    if (EPI == 1) v += R[(size_t)row * N + col];
                    C[(size_t)row * N + col] = v;
                }
            }
    } else {
        bf16* C = (bf16*)Cv;
        #pragma unroll
        for (int mt = 0; mt < 2; ++mt)
            #pragma unroll
            for (int i = 0; i < 4; ++i) {
                int row = bm + wr + mt * 16 + q4 * 4 + i;
                #pragma unroll
                for (int nt = 0; nt < 2; ++nt) {
                    int col = bn + wc + nt * 16 + m0;
                    float v = acc[mt][nt][i];
                    if (EPI == 2) v = fmaxf(v, 0.0f);
                    C[(size_t)row * N + col] = __float2bfloat16(v);
                }
            }
    }
}

// ---------------------------------------------------------------- attention
// block = (b,i) x 4 heads (64x4 threads); wave ty owns head h = by*4+ty.
__global__ void attn_kernel(const float* __restrict__ qkv, const bf16* __restrict__ ew,
                            const int* __restrict__ adj, bf16* __restrict__ o) {
    const float* q = qkv;
    const float* k = qkv + (size_t)512 * H_;
    const float* v = qkv + (size_t)1024 * H_;
    int bi = blockIdx.x;           // b*64 + i
    int b  = bi >> 6;
    int ty = threadIdx.y;
    int h  = blockIdx.y * 4 + ty;
    int lane = threadIdx.x;        // 64
    __shared__ float qs[4][64], as[4][64];
    qs[ty][lane] = q[(size_t)bi * H_ + h * 64 + lane];
    __syncthreads();

    int j = lane;
    const float4* k4 = (const float4*)(k + (size_t)(b * 64 + j) * H_ + h * 64);
    const uint4*  w4 = (const uint4*)(ew + ((size_t)bi * 64 + j) * H_ + h * 64);
    float acc = 0.f;
    #pragma unroll
    for (int t = 0; t < 8; ++t) {
        uint4 wu = w4[t];
        float4 ka = k4[2 * t], kb = k4[2 * t + 1];
        float wf[8];
        unpack8(wu, wf);
        const float* qq = &qs[ty][t * 8];
        acc += qq[0] * (ka.x + wf[0]) + qq[1] * (ka.y + wf[1])
             + qq[2] * (ka.z + wf[2]) + qq[3] * (ka.w + wf[3])
             + qq[4] * (kb.x + wf[4]) + qq[5] * (kb.y + wf[5])
             + qq[6] * (kb.z + wf[6]) + qq[7] * (kb.w + wf[7]);
    }
    float logit = acc * INV_SCALE;
    if (adj[(size_t)bi * 64 + j] <= 0) logit = -INFINITY;

    float m = logit;
    #pragma unroll
    for (int off = 32; off; off >>= 1) m = fmaxf(m, __shfl_xor(m, off));
    float p = expf(logit - m);
    float s = p;
    #pragma unroll
    for (int off = 32; off; off >>= 1) s += __shfl_xor(s, off);
    as[ty][lane] = p / s;
    __syncthreads();

    const float* vbase = v + (size_t)(b * 64) * H_ + h * 64;
    float oacc = 0.f;
    int d = lane;
    #pragma unroll 8
    for (int jj = 0; jj < 64; ++jj)
        oacc += as[ty][jj] * vbase[(size_t)jj * H_ + d];
    o[(size_t)bi * H_ + h * 64 + d] = __float2bfloat16(oacc);
}

// ---------------------------------------------------------------- edge update
// block (64,4): wave ty owns pair blockIdx.x*4+ty; lane owns elems [8*lane, 8*lane+8)
__global__ void edge_kernel(const bf16* __restrict__ ew, const float* __restrict__ x,
                            bf16* __restrict__ bond) {
    int pair = blockIdx.x * 4 + threadIdx.y;   // (b*64+i)*64 + j
    int b = pair >> 12;
    int i = (pair >> 6) & 63;
    int j = pair & 63;
    int lane = threadIdx.x;
    const uint4*  e4  = (const uint4*)(ew + (size_t)pair * H_);
    const float4* xi4 = (const float4*)(x + (size_t)(b * 64 + i) * H_);
    const float4* xj4 = (const float4*)(x + (size_t)(b * 64 + j) * H_);
    uint4  eu = e4[lane];
    float4 a0 = xi4[lane * 2], a1 = xi4[lane * 2 + 1];
    float4 c0 = xj4[lane * 2], c1 = xj4[lane * 2 + 1];
    float ef[8], af[8], cf[8];
    unpack8(eu, ef);
    af[0] = a0.x; af[1] = a0.y; af[2] = a0.z; af[3] = a0.w;
    af[4] = a1.x; af[5] = a1.y; af[6] = a1.z; af[7] = a1.w;
    cf[0] = c0.x; cf[1] = c0.y; cf[2] = c0.z; cf[3] = c0.w;
    cf[4] = c1.x; cf[5] = c1.y; cf[6] = c1.z; cf[7] = c1.w;
    float s0 = 0.f, s1 = 0.f, s2 = 0.f;
    #pragma unroll
    for (int t = 0; t < 8; ++t) {
        s0 += ef[t] * ef[t]; s1 += ef[t] * af[t]; s2 += ef[t] * cf[t];
    }
    #pragma unroll
    for (int off = 32; off; off >>= 1) {
        s0 += __shfl_xor(s0, off);
        s1 += __shfl_xor(s1, off);
        s2 += __shfl_xor(s2, off);
    }
    float t0 = s0 * INV_SCALE, t1 = s1 * INV_SCALE, t2 = s2 * INV_SCALE;
    float m = fmaxf(t0, fmaxf(t1, t2));
    float e0 = expf(t0 - m), e1 = expf(t1 - m), e2 = expf(t2 - m);
    float inv = 1.0f / (e0 + e1 + e2);
    float w0 = e0 * inv, w1 = e1 * inv, w2 = e2 * inv;
    __align__(16) bf16 ob[8];
    #pragma unroll
    for (int t = 0; t < 8; ++t)
        ob[t] = __float2bfloat16(w0 * ef[t] + w1 * af[t] + w2 * cf[t]);
    *(uint4*)(bond + (size_t)pair * H_ + lane * 8) = *(const uint4*)ob;
}

// ---------------------------------------------------------------- head (fused cls+pred)
// one block per b (256 threads). cls = tanh(x[b,0,:] @ Wout); out = softmax(cls@Wpred + bpred)
__global__ void cls_pred_kernel(const float* __restrict__ x, const float* __restrict__ Wout,
                                const float* __restrict__ Wpred, const float* __restrict__ bpred,
                                float* __restrict__ out) {
    int b = blockIdx.x;
    int tid = threadIdx.x;
    __shared__ float xr[512];
    __shared__ float red0[4], red1[4];
    const float* row = x + (size_t)(b * 64) * H_;   // x[b,0,:]
    xr[tid] = row[tid];
    xr[tid + 256] = row[tid + 256];
    __syncthreads();
    float a0 = 0.f, a1 = 0.f;
    #pragma unroll
    for (int t = 0; t < 2; ++t) {
        int c = tid + t * 256;
        float acc = 0.f;
        for (int h = 0; h < 512; ++h)
            acc += xr[h] * Wout[(size_t)h * H_ + c];
        float tv = tanhf(acc);
        a0 += tv * Wpred[c * 2 + 0];
        a1 += tv * Wpred[c * 2 + 1];
    }
    #pragma unroll
    for (int off = 32; off; off >>= 1) {
        a0 += __shfl_xor(a0, off);
        a1 += __shfl_xor(a1, off);
    }
    int w = tid >> 6;
    if ((tid & 63) == 0) { red0[w] = a0; red1[w] = a1; }
    __syncthreads();
    if (tid == 0) {
        float s0 = red0[0] + red0[1] + red0[2] + red0[3] + bpred[0];
        float s1 = red1[0] + red1[1] + red1[2] + red1[3] + bpred[1];
        float m = fmaxf(s0, s1);
        float e0 = expf(s0 - m), e1 = expf(s1 - m);
        float inv = 1.0f / (e0 + e1);
        out[b * 2 + 0] = e0 * inv;
        out[b * 2 + 1] = e1 * inv;
    }
}

// ---------------------------------------------------------------- launch
extern "C" void kernel_launch(void* const* d_in, const int* in_sizes, int n_in,
                              void* d_out, int out_size, void* d_ws, size_t ws_size,
                              hipStream_t stream) {
    const int*   ids      = (const int*)d_in[0];
    const int*   adj      = (const int*)d_in[1];
    const float* atom_emb = (const float*)d_in[2];
    const float* bond_emb = (const float*)d_in[3];
    const float* Wq     = (const float*)d_in[4];
    const float* Wk     = (const float*)d_in[5];
    const float* Wv     = (const float*)d_in[6];
    const float* Wew    = (const float*)d_in[7];
    const float* Wstack = (const float*)d_in[8];
    const float* Wf1    = (const float*)d_in[9];
    const float* Wf2    = (const float*)d_in[10];
    const float* Wout   = (const float*)d_in[11];
    const float* Wpred  = (const float*)d_in[12];
    const float* bpred  = (const float*)d_in[13];

    char* ws = (char*)d_ws;
    size_t off = 0;
    auto alloc = [&](size_t bytes) {
        size_t o = off;
        off += (bytes + 255) & ~(size_t)255;
        return o;
    };
    const size_t ROWS  = (size_t)B_ * N_;           // 512
    const size_t PAIRS = (size_t)B_ * N_ * N_;      // 32768
    const size_t KN    = (size_t)H_ * H_;           // 262144

    float* x       = (float*)(ws + alloc(ROWS * H_ * 4));
    float* xn      = (float*)(ws + alloc(ROWS * H_ * 4));
    bf16*  xn_bf   = (bf16*) (ws + alloc(ROWS * H_ * 2));
    float* qkv     = (float*)(ws + alloc(3 * ROWS * H_ * 4));
    bf16*  o_bf    = (bf16*) (ws + alloc(ROWS * H_ * 2));
    float* resid   = (float*)(ws + alloc(ROWS * H_ * 4));
    bf16*  ffin_bf = (bf16*) (ws + alloc(ROWS * H_ * 2));
    bf16*  ffh_bf  = (bf16*) (ws + alloc(ROWS * 4 * H_ * 2));
    float* part    = (float*)(ws + alloc(4 * ROWS * H_ * 4));   // split-K partials
    bf16*  bond    = (bf16*) (ws + alloc(PAIRS * H_ * 2));      // 32 MB
    bf16*  ew      = (bf16*) (ws + alloc(PAIRS * H_ * 2));      // 32 MB
    bf16*  qkvt    = (bf16*) (ws + alloc((size_t)L_ * 3 * KN * 2));
    bf16*  ewt     = (bf16*) (ws + alloc((size_t)L_ * KN * 2));
    bf16*  stackt  = (bf16*) (ws + alloc((size_t)L_ * KN * 2));
    bf16*  f1t     = (bf16*) (ws + alloc((size_t)L_ * 4 * KN * 2));
    bf16*  f2t     = (bf16*) (ws + alloc((size_t)L_ * 4 * KN * 2));
    (void)ws_size;

    embed_bond_kernel<<<8192, 256, 0, stream>>>(adj, bond_emb, bond);
    embed_ln_kernel<<<512, 256, 0, stream>>>(ids, atom_emb, xn, xn_bf);

    // one-time weight transpose + bf16 cast (2 launches)
    dim3 tb(32, 8);
    transpose_sq<<<dim3(16, 16, 20), tb, 0, stream>>>(Wq, Wk, Wv, Wew, Wstack,
                                                      qkvt, ewt, stackt);
    transpose_rect<<<dim3(64, 64, 8), tb, 0, stream>>>(Wf1, Wf2, f1t, f2t);

    for (int l = 0; l < L_; ++l) {
        // q,k,v fused small-tile: z selects weight slice and output slice
        mfma_gemm_s<0, false><<<dim3(8, 8, 3), 256, 0, stream>>>(
            xn_bf, qkvt + (size_t)l * 3 * KN, qkv, nullptr, 512, 512, 512);
        // ew = bond @ Wew (1024 blocks, async staging)
        mfma_gemm<3><<<dim3(256, 4), 256, 0, stream>>>(
            bond, ewt + (size_t)l * KN, ew, nullptr, 32768, 512, 512);
        attn_kernel<<<dim3(512, 2), dim3(64, 4), 0, stream>>>(qkv, ew, adj, o_bf);
        // resid = o @ Wstack + xn
        mfma_gemm_s<1, false><<<dim3(8, 8), 256, 0, stream>>>(
            o_bf, stackt + (size_t)l * KN, resid, xn, 512, 512, 512);
        ln_bf_kernel<<<512, 256, 0, stream>>>(resid, ffin_bf);
        // ffh = relu(ffin @ Wf1)
        mfma_gemm_s<2, false><<<dim3(8, 32), 256, 0, stream>>>(
            ffin_bf, f1t + (size_t)l * 4 * KN, ffh_bf, nullptr, 512, 2048, 512);
        // x = ffh @ Wf2 + resid : split-K x4
        mfma_gemm_s<0, true><<<dim3(8, 8, 4), 256, 0, stream>>>(
            ffh_bf, f2t + (size_t)l * 4 * KN, part, nullptr, 512, 512, 2048);
        // reduce (+ next-layer LN for l<3)
        if (l < L_ - 1)
            reduce_ln_kernel<true><<<512, 256, 0, stream>>>(part, resid, x, xn, xn_bf);
        else
            reduce_ln_kernel<false><<<512, 256, 0, stream>>>(part, resid, x, xn, xn_bf);
        edge_kernel<<<8192, dim3(64, 4), 0, stream>>>(ew, x, bond);
    }

    cls_pred_kernel<<<8, 256, 0, stream>>>(x, Wout, Wpred, bpred, (float*)d_out);
}

// Round 7
// 589.103 us; speedup vs baseline: 4.5880x; 1.0191x over previous
//
#include <hip/hip_runtime.h>
#include <hip/hip_bf16.h>

typedef __hip_bfloat16 bf16;

// Problem constants
#define B_     8
#define N_     64
#define H_     512
#define HEADS_ 8
#define SP_    64
#define L_     4
static constexpr float INV_SCALE = 0.044194173824159216f; // 1/sqrt(512)

// MFMA fragment types (per guide §3: short8 = 8 bf16 = 4 VGPRs)
typedef __attribute__((ext_vector_type(8))) short short8;
typedef __attribute__((ext_vector_type(4))) float f32x4;

// async global->LDS, 16B per lane; LDS dest is wave-uniform base + lane*16
__device__ __forceinline__ void gload_lds16(const void* g, void* l) {
    __builtin_amdgcn_global_load_lds(
        (const __attribute__((address_space(1))) unsigned int*)g,
        (__attribute__((address_space(3))) unsigned int*)l, 16, 0, 0);
}

__device__ __forceinline__ void unpack8(uint4 u, float* f) {
    f[0] = __uint_as_float(u.x << 16); f[1] = __uint_as_float(u.x & 0xffff0000u);
    f[2] = __uint_as_float(u.y << 16); f[3] = __uint_as_float(u.y & 0xffff0000u);
    f[4] = __uint_as_float(u.z << 16); f[5] = __uint_as_float(u.z & 0xffff0000u);
    f[6] = __uint_as_float(u.w << 16); f[7] = __uint_as_float(u.w & 0xffff0000u);
}

__device__ __forceinline__ bf16 f2bf(float v) { return __float2bfloat16(v); }

// ---------------------------------------------------------------- embeddings
// fused: x = atom_emb[ids[row]]; LN -> xn (fp32), xn_bf (bf16). x never stored.
__global__ void embed_ln_kernel(const int* __restrict__ ids,
                                const float* __restrict__ emb,
                                float* __restrict__ xn, bf16* __restrict__ xn_bf) {
    int row = blockIdx.x;
    int tid = threadIdx.x;
    const float* r = emb + (size_t)ids[row] * H_;
    float x0 = r[tid], x1 = r[tid + 256];
    float s = x0 + x1, sq = x0 * x0 + x1 * x1;
    #pragma unroll
    for (int off = 32; off; off >>= 1) {
        s  += __shfl_xor(s,  off);
        sq += __shfl_xor(sq, off);
    }
    __shared__ float ls[4], lq[4];
    int w = tid >> 6;
    if ((tid & 63) == 0) { ls[w] = s; lq[w] = sq; }
    __syncthreads();
    float S = ls[0] + ls[1] + ls[2] + ls[3];
    float Q = lq[0] + lq[1] + lq[2] + lq[3];
    float mean = S * (1.0f / H_);
    float var  = Q * (1.0f / H_) - mean * mean;
    float inv  = rsqrtf(var + 1e-5f);
    float y0 = (x0 - mean) * inv, y1 = (x1 - mean) * inv;
    xn[(size_t)row * H_ + tid]       = y0;
    xn[(size_t)row * H_ + tid + 256] = y1;
    xn_bf[(size_t)row * H_ + tid]       = f2bf(y0);
    xn_bf[(size_t)row * H_ + tid + 256] = f2bf(y1);
}

// -------- layer-0 ew factorization: E0[t] = bond_emb[t] @ Wew[0]  (8x512)
// grid (8 t, 8 cb) x 64 lanes; ewt0 is transposed bf16 [c][h]
__global__ void ew0_precompute(const float* __restrict__ bond_emb,
                               const bf16* __restrict__ ewt0, bf16* __restrict__ E0) {
    int t = blockIdx.x, cb = blockIdx.y, lane = threadIdx.x;
    int c = cb * 64 + lane;
    __shared__ float be[512];
    for (int h = lane; h < 512; h += 64) be[h] = bond_emb[t * 512 + h];
    __syncthreads();
    const bf16* wr = ewt0 + (size_t)c * 512;
    float acc = 0.f;
    for (int h8 = 0; h8 < 64; ++h8) {
        uint4 u = *(const uint4*)(wr + h8 * 8);
        float wf[8];
        unpack8(u, wf);
        const float* b = &be[h8 * 8];
        acc += b[0]*wf[0] + b[1]*wf[1] + b[2]*wf[2] + b[3]*wf[3]
             + b[4]*wf[4] + b[5]*wf[5] + b[6]*wf[6] + b[7]*wf[7];
    }
    E0[t * 512 + c] = f2bf(acc);
}

// ew0 = E0[adj]  (pure gather, 32 MB write)
__global__ void ew0_gather(const int* __restrict__ adj, const bf16* __restrict__ E0,
                           bf16* __restrict__ ew) {
    int gid = blockIdx.x * 256 + threadIdx.x;   // 2,097,152
    int pair = gid >> 6;
    int c    = gid & 63;
    uint4 v = *(const uint4*)(E0 + (size_t)adj[pair] * H_ + c * 8);
    *(uint4*)(ew + (size_t)pair * H_ + c * 8) = v;
}

// ------------------------------------------------- weight transpose + cast
// square 512x512 set: z<12: qkv (slot=z/4, layer=z%4); z in [12,16): Wew; [16,20): Wstack
__global__ void transpose_sq(const float* __restrict__ Wq, const float* __restrict__ Wk,
                             const float* __restrict__ Wv, const float* __restrict__ Wew,
                             const float* __restrict__ Wst,
                             bf16* __restrict__ qkvt, bf16* __restrict__ ewt,
                             bf16* __restrict__ stackt) {
    const size_t KN = (size_t)H_ * H_;
    int z = blockIdx.z;
    const float* W; bf16* Wt;
    if (z < 12) {
        int s = z >> 2, l = z & 3;
        W  = (s == 0 ? Wq : s == 1 ? Wk : Wv) + (size_t)l * KN;
        Wt = qkvt + (size_t)l * 3 * KN + (size_t)s * KN;
    } else if (z < 16) {
        int l = z - 12;
        W = Wew + (size_t)l * KN; Wt = ewt + (size_t)l * KN;
    } else {
        int l = z - 16;
        W = Wst + (size_t)l * KN; Wt = stackt + (size_t)l * KN;
    }
    __shared__ float t[32][33];
    int k0 = blockIdx.x * 32, n0 = blockIdx.y * 32;
    int tx = threadIdx.x, ty = threadIdx.y;  // 32, 8
    #pragma unroll
    for (int r = ty; r < 32; r += 8)
        t[r][tx] = W[(size_t)(k0 + r) * H_ + n0 + tx];
    __syncthreads();
    #pragma unroll
    for (int r = ty; r < 32; r += 8)
        Wt[(size_t)(n0 + r) * H_ + k0 + tx] = f2bf(t[tx][r]);
}

// rect set: z<4: Wf1 layer z (512x2048); z>=4: Wf2 layer z-4 (2048x512). grid (64,64,8)
__global__ void transpose_rect(const float* __restrict__ Wf1, const float* __restrict__ Wf2,
                               bf16* __restrict__ f1t, bf16* __restrict__ f2t) {
    const size_t KN4 = (size_t)4 * H_ * H_;
    int z = blockIdx.z;
    const float* W; bf16* Wt; int K, N;
    if (z < 4) {
        if (blockIdx.x >= 16) return;          // K=512 -> 16 tiles
        W = Wf1 + (size_t)z * KN4; Wt = f1t + (size_t)z * KN4; K = 512; N = 2048;
    } else {
        if (blockIdx.y >= 16) return;          // N=512 -> 16 tiles
        W = Wf2 + (size_t)(z - 4) * KN4; Wt = f2t + (size_t)(z - 4) * KN4; K = 2048; N = 512;
    }
    __shared__ float t[32][33];
    int k0 = blockIdx.x * 32, n0 = blockIdx.y * 32;
    int tx = threadIdx.x, ty = threadIdx.y;
    #pragma unroll
    for (int r = ty; r < 32; r += 8)
        t[r][tx] = W[(size_t)(k0 + r) * N + n0 + tx];
    __syncthreads();
    #pragma unroll
    for (int r = ty; r < 32; r += 8)
        Wt[(size_t)(n0 + r) * K + k0 + tx] = f2bf(t[tx][r]);
}

// ---------------------------------------------------------------- LayerNorm (mid-layer)
__global__ void ln_bf_kernel(const float* __restrict__ in, bf16* __restrict__ out16) {
    int row = blockIdx.x;
    int tid = threadIdx.x;
    const float* r = in + (size_t)row * H_;
    float x0 = r[tid], x1 = r[tid + 256];
    float s = x0 + x1, sq = x0 * x0 + x1 * x1;
    #pragma unroll
    for (int off = 32; off; off >>= 1) {
        s  += __shfl_xor(s,  off);
        sq += __shfl_xor(sq, off);
    }
    __shared__ float ls[4], lq[4];
    int w = tid >> 6;
    if ((tid & 63) == 0) { ls[w] = s; lq[w] = sq; }
    __syncthreads();
    float S = ls[0] + ls[1] + ls[2] + ls[3];
    float Q = lq[0] + lq[1] + lq[2] + lq[3];
    float mean = S * (1.0f / H_);
    float var  = Q * (1.0f / H_) - mean * mean;
    float inv  = rsqrtf(var + 1e-5f);
    out16[(size_t)row * H_ + tid]       = f2bf((x0 - mean) * inv);
    out16[(size_t)row * H_ + tid + 256] = f2bf((x1 - mean) * inv);
}

// ------------------------- split-K reduce (+resid) fused with next-layer LN
template <bool DO_LN>
__global__ void reduce_ln_kernel(const float* __restrict__ part, const float* __restrict__ resid,
                                 float* __restrict__ x, float* __restrict__ xn,
                                 bf16* __restrict__ xn_bf) {
    const int MN = 512 * H_;
    int row = blockIdx.x;
    int tid = threadIdx.x;
    size_t base = (size_t)row * H_;
    float v0 = resid[base + tid], v1 = resid[base + tid + 256];
    #pragma unroll
    for (int s = 0; s < 4; ++s) {
        v0 += part[(size_t)s * MN + base + tid];
        v1 += part[(size_t)s * MN + base + tid + 256];
    }
    x[base + tid] = v0;
    x[base + tid + 256] = v1;
    if (DO_LN) {
        float s = v0 + v1, sq = v0 * v0 + v1 * v1;
        #pragma unroll
        for (int off = 32; off; off >>= 1) {
            s  += __shfl_xor(s,  off);
            sq += __shfl_xor(sq, off);
        }
        __shared__ float ls[4], lq[4];
        int w = tid >> 6;
        if ((tid & 63) == 0) { ls[w] = s; lq[w] = sq; }
        __syncthreads();
        float S = ls[0] + ls[1] + ls[2] + ls[3];
        float Q = lq[0] + lq[1] + lq[2] + lq[3];
        float mean = S * (1.0f / H_);
        float var  = Q * (1.0f / H_) - mean * mean;
        float inv  = rsqrtf(var + 1e-5f);
        float y0 = (v0 - mean) * inv, y1 = (v1 - mean) * inv;
        xn[base + tid]       = y0;
        xn[base + tid + 256] = y1;
        xn_bf[base + tid]       = f2bf(y0);
        xn_bf[base + tid + 256] = f2bf(y1);
    }
}

// ---------------------------------------------------------------- MFMA GEMM (large, 128x128)
// C = A @ Bt^T, bf16, fp32 accum. Async global_load_lds staging with K-major lane map:
// stage lane (sr=lane&15, sc=lane>>4) fetches row sr, k-chunk sc -> LDS elem at
// sr*16 + sc*256 within the 1024B wave-instr region. Fragment read lane (m0,q4):
// addr = region(row)*1024 + m0*16 + q4*256 -> bank 4*m0%32 = 2-way (free, m136).
// EPI: 0 = fp32 store, 1 = fp32 store + R, 2 = relu -> bf16, 3 = bf16 store
#define BM 128
#define BN 128
#define BK 32
#define RSTR 80   // (gemm_s only) LDS row stride: 64 B data + 16 pad

template <int EPI>
__launch_bounds__(256)
__global__ void mfma_gemm(const bf16* __restrict__ A, const bf16* __restrict__ Bt,
                          void* __restrict__ Cv, const float* __restrict__ R,
                          int M, int N, int K) {
    __shared__ __align__(16) char lds[2 * BM * 64];   // 16 KB
    char* As = lds;
    char* Bs = lds + BM * 64;
    const int tid = threadIdx.x;
    const int bm = blockIdx.x * BM, bn = blockIdx.y * BN;
    Bt += (size_t)blockIdx.z * N * K;
    const int w = tid >> 6, lane = tid & 63;
    const int wr = (w >> 1) * 64, wc = (w & 1) * 64;
    const int m0 = lane & 15, q4 = lane >> 4;

    f32x4 acc[4][4] = {};

    const int sr = lane & 15;             // staged row within 16-row group
    const int sc = (lane >> 4) * 8;       // staged k element offset (16B chunk)

    for (int k0 = 0; k0 < K; k0 += BK) {
        __syncthreads();   // all waves done reading previous tile
        #pragma unroll
        for (int t = 0; t < 2; ++t) {
            gload_lds16(A  + (size_t)(bm + w * 32 + t * 16 + sr) * K + k0 + sc,
                        As + (w * 2 + t) * 1024);
            gload_lds16(Bt + (size_t)(bn + w * 32 + t * 16 + sr) * K + k0 + sc,
                        Bs + (w * 2 + t) * 1024);
        }
        __syncthreads();   // compiler drains vmcnt(0) before barrier -> tile visible
        short8 af[4], bfr[4];
        #pragma unroll
        for (int t = 0; t < 4; ++t) {
            af[t]  = *(const short8*)(As + (wr / 16 + t) * 1024 + m0 * 16 + q4 * 256);
            bfr[t] = *(const short8*)(Bs + (wc / 16 + t) * 1024 + m0 * 16 + q4 * 256);
        }
        #pragma unroll
        for (int mt = 0; mt < 4; ++mt)
            #pragma unroll
            for (int nt = 0; nt < 4; ++nt)
                acc[mt][nt] = __builtin_amdgcn_mfma_f32_16x16x32_bf16(
                    af[mt], bfr[nt], acc[mt][nt], 0, 0, 0);
    }

    // epilogue: C/D layout col = lane&15, row = quad*4 + reg  [m89/m91 verified]
    if (EPI <= 1) {
        float* C = (float*)Cv + (size_t)blockIdx.z * M * N;
        #pragma unroll
        for (int mt = 0; mt < 4; ++mt)
            #pragma unroll
            for (int i = 0; i < 4; ++i) {
                int row = bm + wr + mt * 16 + q4 * 4 + i;
                #pragma unroll
                for (int nt = 0; nt < 4; ++nt) {
                    int col = bn + wc + nt * 16 + m0;
                    float v = acc[mt][nt][i];
                    if (EPI == 1) v += R[(size_t)row * N + col];
                    C[(size_t)row * N + col] = v;
                }
            }
    } else {
        bf16* C = (bf16*)Cv;
        #pragma unroll
        for (int mt = 0; mt < 4; ++mt)
            #pragma unroll
            for (int i = 0; i < 4; ++i) {
                int row = bm + wr + mt * 16 + q4 * 4 + i;
                #pragma unroll
                for (int nt = 0; nt < 4; ++nt) {
                    int col = bn + wc + nt * 16 + m0;
                    float v = acc[mt][nt][i];
                    if (EPI == 2) v = fmaxf(v, 0.0f);
                    C[(size_t)row * N + col] = __float2bfloat16(v);
                }
            }
    }
}

// ------------------------------------------- MFMA GEMM (small, 64x64, BK=64)
// 4 waves as 2x2; each wave 32x32 = 2x2 frags of 16x16x32. RSTR=80 padded LDS.
template <int EPI, bool SPLIT>
__launch_bounds__(256)
__global__ void mfma_gemm_s(const bf16* __restrict__ A, const bf16* __restrict__ Bt,
                            void* __restrict__ Cv, const float* __restrict__ R,
                            int M, int N, int K) {
    __shared__ __align__(16) char lds[4 * 64 * RSTR];   // 20 KB
    char* As = lds;
    char* Bs = lds + 2 * 64 * RSTR;
    const int tid = threadIdx.x;
    const int bm = blockIdx.x * 64, bn = blockIdx.y * 64;
    int kbeg = 0, kend = K;
    if (SPLIT) {
        int ks = K / gridDim.z;
        kbeg = blockIdx.z * ks;
        kend = kbeg + ks;
    } else {
        Bt += (size_t)blockIdx.z * N * K;
    }
    const int w = tid >> 6, lane = tid & 63;
    const int wr = (w >> 1) * 32, wc = (w & 1) * 32;
    const int m0 = lane & 15, q4 = lane >> 4;

    f32x4 acc[2][2] = {};

    const int rA = tid >> 3;              // 0..31
    const int cA = tid & 7;
    const int ksP = cA >> 2;              // K-plane
    const int cB = (cA & 3) * 16;
    const int cE = cA * 8;

    for (int k0 = kbeg; k0 < kend; k0 += 64) {
        uint4 a0 = *(const uint4*)(A  + (size_t)(bm + rA) * K + k0 + cE);
        uint4 a1 = *(const uint4*)(A  + (size_t)(bm + rA + 32) * K + k0 + cE);
        uint4 b0 = *(const uint4*)(Bt + (size_t)(bn + rA) * K + k0 + cE);
        uint4 b1 = *(const uint4*)(Bt + (size_t)(bn + rA + 32) * K + k0 + cE);
        __syncthreads();
        *(uint4*)(As + ksP * (64 * RSTR) + rA * RSTR + cB) = a0;
        *(uint4*)(As + ksP * (64 * RSTR) + (rA + 32) * RSTR + cB) = a1;
        *(uint4*)(Bs + ksP * (64 * RSTR) + rA * RSTR + cB) = b0;
        *(uint4*)(Bs + ksP * (64 * RSTR) + (rA + 32) * RSTR + cB) = b1;
        __syncthreads();
        short8 af[2][2], bfr[2][2];
        #pragma unroll
        for (int ks = 0; ks < 2; ++ks)
            #pragma unroll
            for (int t = 0; t < 2; ++t) {
                af[ks][t]  = *(const short8*)(As + ks * (64 * RSTR) + (wr + t * 16 + m0) * RSTR + q4 * 16);
                bfr[ks][t] = *(const short8*)(Bs + ks * (64 * RSTR) + (wc + t * 16 + m0) * RSTR + q4 * 16);
            }
        #pragma unroll
        for (int ks = 0; ks < 2; ++ks)
            #pragma unroll
            for (int mt = 0; mt < 2; ++mt)
                #pragma unroll
                for (int nt = 0; nt < 2; ++nt)
                    acc[mt][nt] = __builtin_amdgcn_mfma_f32_16x16x32_bf16(
                        af[ks][mt], bfr[ks][nt], acc[mt][nt], 0, 0, 0);
    }

    if (SPLIT) {
        float* C = (float*)Cv + (size_t)blockIdx.z * M * N;
        #pragma unroll
        for (int mt = 0; mt < 2; ++mt)
            #pragma unroll
            for (int i = 0; i < 4; ++i) {
                int row = bm + wr + mt * 16 + q4 * 4 + i;
                #pragma unroll
                for (int nt = 0; nt < 2; ++nt)
                    C[(size_t)row * N + bn + wc + nt * 16 + m0] = acc[mt][nt][i];
            }
    } else if (EPI <= 1) {
        float* C = (float*)Cv + (size_t)blockIdx.z * M * N;
        #pragma unroll
        for (int mt = 0; mt < 2; ++mt)
            #pragma unroll
            for (int i = 0; i < 4; ++i) {
                int row = bm + wr + mt * 16 + q4 * 4 + i;
                #pragma unroll
                for (int nt = 0; nt < 2; ++nt) {
                    int col = bn + wc + nt * 16 + m0;
                    float v = acc[mt][nt][i];
                    if (EPI == 1) v += R[(size_t)row * N + col];
                    C[(size_t)row * N + col] = v;
                }
            }
    } else {
        bf16* C = (bf16*)Cv;
        #pragma unroll
        for (int mt = 0; mt < 2; ++mt)
            #pragma unroll
            for (int i = 0; i < 4; ++i) {
                int row = bm + wr + mt * 16 + q4 * 4 + i;
                #pragma unroll
                for (int nt = 0; nt < 2; ++nt) {
                    int col = bn + wc + nt * 16 + m0;
                    float v = acc[mt][nt][i];
                    if (EPI == 2) v = fmaxf(v, 0.0f);
                    C[(size_t)row * N + col] = __float2bfloat16(v);
                }
            }
    }
}

// ---------------------------------------------------------------- attention
// block = (b,i) x 4 heads (64x4 threads); wave ty owns head h = by*4+ty.
__global__ void attn_kernel(const float* __restrict__ qkv, const bf16* __restrict__ ew,
                            const int* __restrict__ adj, bf16* __restrict__ o) {
    const float* q = qkv;
    const float* k = qkv + (size_t)512 * H_;
    const float* v = qkv + (size_t)1024 * H_;
    int bi = blockIdx.x;           // b*64 + i
    int b  = bi >> 6;
    int ty = threadIdx.y;
    int h  = blockIdx.y * 4 + ty;
    int lane = threadIdx.x;        // 64
    __shared__ float qs[4][64], as[4][64];
    qs[ty][lane] = q[(size_t)bi * H_ + h * 64 + lane];
    __syncthreads();

    int j = lane;
    const float4* k4 = (const float4*)(k + (size_t)(b * 64 + j) * H_ + h * 64);
    const uint4*  w4 = (const uint4*)(ew + ((size_t)bi * 64 + j) * H_ + h * 64);
    float acc = 0.f;
    #pragma unroll
    for (int t = 0; t < 8; ++t) {
        uint4 wu = w4[t];
        float4 ka = k4[2 * t], kb = k4[2 * t + 1];
        float wf[8];
        unpack8(wu, wf);
        const float* qq = &qs[ty][t * 8];
        acc += qq[0] * (ka.x + wf[0]) + qq[1] * (ka.y + wf[1])
             + qq[2] * (ka.z + wf[2]) + qq[3] * (ka.w + wf[3])
             + qq[4] * (kb.x + wf[4]) + qq[5] * (kb.y + wf[5])
             + qq[6] * (kb.z + wf[6]) + qq[7] * (kb.w + wf[7]);
    }
    float logit = acc * INV_SCALE;
    if (adj[(size_t)bi * 64 + j] <= 0) logit = -INFINITY;

    float m = logit;
    #pragma unroll
    for (int off = 32; off; off >>= 1) m = fmaxf(m, __shfl_xor(m, off));
    float p = expf(logit - m);
    float s = p;
    #pragma unroll
    for (int off = 32; off; off >>= 1) s += __shfl_xor(s, off);
    as[ty][lane] = p / s;
    __syncthreads();

    const float* vbase = v + (size_t)(b * 64) * H_ + h * 64;
    float oacc = 0.f;
    int d = lane;
    #pragma unroll 8
    for (int jj = 0; jj < 64; ++jj)
        oacc += as[ty][jj] * vbase[(size_t)jj * H_ + d];
    o[(size_t)bi * H_ + h * 64 + d] = __float2bfloat16(oacc);
}

// ---------------------------------------------------------------- edge update
// block (64,4): wave ty owns pair blockIdx.x*4+ty; lane owns elems [8*lane, 8*lane+8)
__global__ void edge_kernel(const bf16* __restrict__ ew, const float* __restrict__ x,
                            bf16* __restrict__ bond) {
    int pair = blockIdx.x * 4 + threadIdx.y;   // (b*64+i)*64 + j
    int b = pair >> 12;
    int i = (pair >> 6) & 63;
    int j = pair & 63;
    int lane = threadIdx.x;
    const uint4*  e4  = (const uint4*)(ew + (size_t)pair * H_);
    const float4* xi4 = (const float4*)(x + (size_t)(b * 64 + i) * H_);
    const float4* xj4 = (const float4*)(x + (size_t)(b * 64 + j) * H_);
    uint4  eu = e4[lane];
    float4 a0 = xi4[lane * 2], a1 = xi4[lane * 2 + 1];
    float4 c0 = xj4[lane * 2], c1 = xj4[lane * 2 + 1];
    float ef[8], af[8], cf[8];
    unpack8(eu, ef);
    af[0] = a0.x; af[1] = a0.y; af[2] = a0.z; af[3] = a0.w;
    af[4] = a1.x; af[5] = a1.y; af[6] = a1.z; af[7] = a1.w;
    cf[0] = c0.x; cf[1] = c0.y; cf[2] = c0.z; cf[3] = c0.w;
    cf[4] = c1.x; cf[5] = c1.y; cf[6] = c1.z; cf[7] = c1.w;
    float s0 = 0.f, s1 = 0.f, s2 = 0.f;
    #pragma unroll
    for (int t = 0; t < 8; ++t) {
        s0 += ef[t] * ef[t]; s1 += ef[t] * af[t]; s2 += ef[t] * cf[t];
    }
    #pragma unroll
    for (int off = 32; off; off >>= 1) {
        s0 += __shfl_xor(s0, off);
        s1 += __shfl_xor(s1, off);
        s2 += __shfl_xor(s2, off);
    }
    float t0 = s0 * INV_SCALE, t1 = s1 * INV_SCALE, t2 = s2 * INV_SCALE;
    float m = fmaxf(t0, fmaxf(t1, t2));
    float e0 = expf(t0 - m), e1 = expf(t1 - m), e2 = expf(t2 - m);
    float inv = 1.0f / (e0 + e1 + e2);
    float w0 = e0 * inv, w1 = e1 * inv, w2 = e2 * inv;
    __align__(16) bf16 ob[8];
    #pragma unroll
    for (int t = 0; t < 8; ++t)
        ob[t] = __float2bfloat16(w0 * ef[t] + w1 * af[t] + w2 * cf[t]);
    *(uint4*)(bond + (size_t)pair * H_ + lane * 8) = *(const uint4*)ob;
}

// ---------------------------------------------------------------- head (fused cls+pred)
__global__ void cls_pred_kernel(const float* __restrict__ x, const float* __restrict__ Wout,
                                const float* __restrict__ Wpred, const float* __restrict__ bpred,
                                float* __restrict__ out) {
    int b = blockIdx.x;
    int tid = threadIdx.x;
    __shared__ float xr[512];
    __shared__ float red0[4], red1[4];
    const float* row = x + (size_t)(b * 64) * H_;   // x[b,0,:]
    xr[tid] = row[tid];
    xr[tid + 256] = row[tid + 256];
    __syncthreads();
    float a0 = 0.f, a1 = 0.f;
    #pragma unroll
    for (int t = 0; t < 2; ++t) {
        int c = tid + t * 256;
        float acc = 0.f;
        for (int h = 0; h < 512; ++h)
            acc += xr[h] * Wout[(size_t)h * H_ + c];
        float tv = tanhf(acc);
        a0 += tv * Wpred[c * 2 + 0];
        a1 += tv * Wpred[c * 2 + 1];
    }
    #pragma unroll
    for (int off = 32; off; off >>= 1) {
        a0 += __shfl_xor(a0, off);
        a1 += __shfl_xor(a1, off);
    }
    int w = tid >> 6;
    if ((tid & 63) == 0) { red0[w] = a0; red1[w] = a1; }
    __syncthreads();
    if (tid == 0) {
        float s0 = red0[0] + red0[1] + red0[2] + red0[3] + bpred[0];
        float s1 = red1[0] + red1[1] + red1[2] + red1[3] + bpred[1];
        float m = fmaxf(s0, s1);
        float e0 = expf(s0 - m), e1 = expf(s1 - m);
        float inv = 1.0f / (e0 + e1);
        out[b * 2 + 0] = e0 * inv;
        out[b * 2 + 1] = e1 * inv;
    }
}

// ---------------------------------------------------------------- launch
extern "C" void kernel_launch(void* const* d_in, const int* in_sizes, int n_in,
                              void* d_out, int out_size, void* d_ws, size_t ws_size,
                              hipStream_t stream) {
    const int*   ids      = (const int*)d_in[0];
    const int*   adj      = (const int*)d_in[1];
    const float* atom_emb = (const float*)d_in[2];
    const float* bond_emb = (const float*)d_in[3];
    const float* Wq     = (const float*)d_in[4];
    const float* Wk     = (const float*)d_in[5];
    const float* Wv     = (const float*)d_in[6];
    const float* Wew    = (const float*)d_in[7];
    const float* Wstack = (const float*)d_in[8];
    const float* Wf1    = (const float*)d_in[9];
    const float* Wf2    = (const float*)d_in[10];
    const float* Wout   = (const float*)d_in[11];
    const float* Wpred  = (const float*)d_in[12];
    const float* bpred  = (const float*)d_in[13];

    char* ws = (char*)d_ws;
    size_t off = 0;
    auto alloc = [&](size_t bytes) {
        size_t o = off;
        off += (bytes + 255) & ~(size_t)255;
        return o;
    };
    const size_t ROWS  = (size_t)B_ * N_;           // 512
    const size_t PAIRS = (size_t)B_ * N_ * N_;      // 32768
    const size_t KN    = (size_t)H_ * H_;           // 262144

    float* x       = (float*)(ws + alloc(ROWS * H_ * 4));
    float* xn      = (float*)(ws + alloc(ROWS * H_ * 4));
    bf16*  xn_bf   = (bf16*) (ws + alloc(ROWS * H_ * 2));
    float* qkv     = (float*)(ws + alloc(3 * ROWS * H_ * 4));
    bf16*  o_bf    = (bf16*) (ws + alloc(ROWS * H_ * 2));
    float* resid   = (float*)(ws + alloc(ROWS * H_ * 4));
    bf16*  ffin_bf = (bf16*) (ws + alloc(ROWS * H_ * 2));
    bf16*  ffh_bf  = (bf16*) (ws + alloc(ROWS * 4 * H_ * 2));
    float* part    = (float*)(ws + alloc(4 * ROWS * H_ * 4));   // split-K partials
    bf16*  E0      = (bf16*) (ws + alloc(8 * H_ * 2));          // 8 KB
    bf16*  bond    = (bf16*) (ws + alloc(PAIRS * H_ * 2));      // 32 MB
    bf16*  ew      = (bf16*) (ws + alloc(PAIRS * H_ * 2));      // 32 MB
    bf16*  qkvt    = (bf16*) (ws + alloc((size_t)L_ * 3 * KN * 2));
    bf16*  ewt     = (bf16*) (ws + alloc((size_t)L_ * KN * 2));
    bf16*  stackt  = (bf16*) (ws + alloc((size_t)L_ * KN * 2));
    bf16*  f1t     = (bf16*) (ws + alloc((size_t)L_ * 4 * KN * 2));
    bf16*  f2t     = (bf16*) (ws + alloc((size_t)L_ * 4 * KN * 2));
    (void)ws_size;

    embed_ln_kernel<<<512, 256, 0, stream>>>(ids, atom_emb, xn, xn_bf);

    // one-time weight transpose + bf16 cast (2 launches)
    dim3 tb(32, 8);
    transpose_sq<<<dim3(16, 16, 20), tb, 0, stream>>>(Wq, Wk, Wv, Wew, Wstack,
                                                      qkvt, ewt, stackt);
    transpose_rect<<<dim3(64, 64, 8), tb, 0, stream>>>(Wf1, Wf2, f1t, f2t);

    // layer-0 ew factorization: 8 distinct bond rows -> precompute + gather
    ew0_precompute<<<dim3(8, 8), 64, 0, stream>>>(bond_emb, ewt, E0);
    ew0_gather<<<8192, 256, 0, stream>>>(adj, E0, ew);

    for (int l = 0; l < L_; ++l) {
        // q,k,v fused small-tile: z selects weight slice and output slice
        mfma_gemm_s<0, false><<<dim3(8, 8, 3), 256, 0, stream>>>(
            xn_bf, qkvt + (size_t)l * 3 * KN, qkv, nullptr, 512, 512, 512);
        // ew = bond @ Wew (layers >=1; layer 0 comes from the gather)
        if (l > 0)
            mfma_gemm<3><<<dim3(256, 4), 256, 0, stream>>>(
                bond, ewt + (size_t)l * KN, ew, nullptr, 32768, 512, 512);
        attn_kernel<<<dim3(512, 2), dim3(64, 4), 0, stream>>>(qkv, ew, adj, o_bf);
        // resid = o @ Wstack + xn
        mfma_gemm_s<1, false><<<dim3(8, 8), 256, 0, stream>>>(
            o_bf, stackt + (size_t)l * KN, resid, xn, 512, 512, 512);
        ln_bf_kernel<<<512, 256, 0, stream>>>(resid, ffin_bf);
        // ffh = relu(ffin @ Wf1)
        mfma_gemm_s<2, false><<<dim3(8, 32), 256, 0, stream>>>(
            ffin_bf, f1t + (size_t)l * 4 * KN, ffh_bf, nullptr, 512, 2048, 512);
        // x = ffh @ Wf2 + resid : split-K x4
        mfma_gemm_s<0, true><<<dim3(8, 8, 4), 256, 0, stream>>>(
            ffh_bf, f2t + (size_t)l * 4 * KN, part, nullptr, 512, 512, 2048);
        if (l < L_ - 1)
            reduce_ln_kernel<true><<<512, 256, 0, stream>>>(part, resid, x, xn, xn_bf);
        else
            reduce_ln_kernel<false><<<512, 256, 0, stream>>>(part, resid, x, xn, xn_bf);
        // bond for next layer (last layer's edge output is never read -> skip)
        if (l < L_ - 1)
            edge_kernel<<<8192, dim3(64, 4), 0, stream>>>(ew, x, bond);
    }

    cls_pred_kernel<<<8, 256, 0, stream>>>(x, Wout, Wpred, bpred, (float*)d_out);
}

// Round 8
// 565.591 us; speedup vs baseline: 4.7787x; 1.0416x over previous
//
#include <hip/hip_runtime.h>
#include <hip/hip_bf16.h>

typedef __hip_bfloat16 bf16;

// Problem constants
#define B_     8
#define N_     64
#define H_     512
#define HEADS_ 8
#define SP_    64
#define L_     4
static constexpr float INV_SCALE = 0.044194173824159216f; // 1/sqrt(512)

// MFMA fragment types (per guide §3: short8 = 8 bf16 = 4 VGPRs)
typedef __attribute__((ext_vector_type(8))) short short8;
typedef __attribute__((ext_vector_type(4))) float f32x4;

// async global->LDS, 16B per lane; LDS dest is wave-uniform base + lane*16
__device__ __forceinline__ void gload_lds16(const void* g, void* l) {
    __builtin_amdgcn_global_load_lds(
        (const __attribute__((address_space(1))) unsigned int*)g,
        (__attribute__((address_space(3))) unsigned int*)l, 16, 0, 0);
}

__device__ __forceinline__ void unpack8(uint4 u, float* f) {
    f[0] = __uint_as_float(u.x << 16); f[1] = __uint_as_float(u.x & 0xffff0000u);
    f[2] = __uint_as_float(u.y << 16); f[3] = __uint_as_float(u.y & 0xffff0000u);
    f[4] = __uint_as_float(u.z << 16); f[5] = __uint_as_float(u.z & 0xffff0000u);
    f[6] = __uint_as_float(u.w << 16); f[7] = __uint_as_float(u.w & 0xffff0000u);
}

__device__ __forceinline__ bf16 f2bf(float v) { return __float2bfloat16(v); }

// ---------------------------------------------------------------- embeddings
// fused: x = atom_emb[ids[row]]; LN -> xn (fp32), xn_bf (bf16). x never stored.
__global__ void embed_ln_kernel(const int* __restrict__ ids,
                                const float* __restrict__ emb,
                                float* __restrict__ xn, bf16* __restrict__ xn_bf) {
    int row = blockIdx.x;
    int tid = threadIdx.x;
    const float* r = emb + (size_t)ids[row] * H_;
    float x0 = r[tid], x1 = r[tid + 256];
    float s = x0 + x1, sq = x0 * x0 + x1 * x1;
    #pragma unroll
    for (int off = 32; off; off >>= 1) {
        s  += __shfl_xor(s,  off);
        sq += __shfl_xor(sq, off);
    }
    __shared__ float ls[4], lq[4];
    int w = tid >> 6;
    if ((tid & 63) == 0) { ls[w] = s; lq[w] = sq; }
    __syncthreads();
    float S = ls[0] + ls[1] + ls[2] + ls[3];
    float Q = lq[0] + lq[1] + lq[2] + lq[3];
    float mean = S * (1.0f / H_);
    float var  = Q * (1.0f / H_) - mean * mean;
    float inv  = rsqrtf(var + 1e-5f);
    float y0 = (x0 - mean) * inv, y1 = (x1 - mean) * inv;
    xn[(size_t)row * H_ + tid]       = y0;
    xn[(size_t)row * H_ + tid + 256] = y1;
    xn_bf[(size_t)row * H_ + tid]       = f2bf(y0);
    xn_bf[(size_t)row * H_ + tid + 256] = f2bf(y1);
}

// -------- layer-0 ew factorization: E0[t] = bond_emb[t] @ Wew[0]  (8x512)
__global__ void ew0_precompute(const float* __restrict__ bond_emb,
                               const bf16* __restrict__ ewt0, bf16* __restrict__ E0) {
    int t = blockIdx.x, cb = blockIdx.y, lane = threadIdx.x;
    int c = cb * 64 + lane;
    __shared__ float be[512];
    for (int h = lane; h < 512; h += 64) be[h] = bond_emb[t * 512 + h];
    __syncthreads();
    const bf16* wr = ewt0 + (size_t)c * 512;
    float acc = 0.f;
    for (int h8 = 0; h8 < 64; ++h8) {
        uint4 u = *(const uint4*)(wr + h8 * 8);
        float wf[8];
        unpack8(u, wf);
        const float* b = &be[h8 * 8];
        acc += b[0]*wf[0] + b[1]*wf[1] + b[2]*wf[2] + b[3]*wf[3]
             + b[4]*wf[4] + b[5]*wf[5] + b[6]*wf[6] + b[7]*wf[7];
    }
    E0[t * 512 + c] = f2bf(acc);
}

// ew0 = E0[adj]  (pure gather, 32 MB write)
__global__ void ew0_gather(const int* __restrict__ adj, const bf16* __restrict__ E0,
                           bf16* __restrict__ ew) {
    int gid = blockIdx.x * 256 + threadIdx.x;   // 2,097,152
    int pair = gid >> 6;
    int c    = gid & 63;
    uint4 v = *(const uint4*)(E0 + (size_t)adj[pair] * H_ + c * 8);
    *(uint4*)(ew + (size_t)pair * H_ + c * 8) = v;
}

// ------------------------------------------------- weight transpose + cast
__global__ void transpose_sq(const float* __restrict__ Wq, const float* __restrict__ Wk,
                             const float* __restrict__ Wv, const float* __restrict__ Wew,
                             const float* __restrict__ Wst,
                             bf16* __restrict__ qkvt, bf16* __restrict__ ewt,
                             bf16* __restrict__ stackt) {
    const size_t KN = (size_t)H_ * H_;
    int z = blockIdx.z;
    const float* W; bf16* Wt;
    if (z < 12) {
        int s = z >> 2, l = z & 3;
        W  = (s == 0 ? Wq : s == 1 ? Wk : Wv) + (size_t)l * KN;
        Wt = qkvt + (size_t)l * 3 * KN + (size_t)s * KN;
    } else if (z < 16) {
        int l = z - 12;
        W = Wew + (size_t)l * KN; Wt = ewt + (size_t)l * KN;
    } else {
        int l = z - 16;
        W = Wst + (size_t)l * KN; Wt = stackt + (size_t)l * KN;
    }
    __shared__ float t[32][33];
    int k0 = blockIdx.x * 32, n0 = blockIdx.y * 32;
    int tx = threadIdx.x, ty = threadIdx.y;  // 32, 8
    #pragma unroll
    for (int r = ty; r < 32; r += 8)
        t[r][tx] = W[(size_t)(k0 + r) * H_ + n0 + tx];
    __syncthreads();
    #pragma unroll
    for (int r = ty; r < 32; r += 8)
        Wt[(size_t)(n0 + r) * H_ + k0 + tx] = f2bf(t[tx][r]);
}

// rect set: z<4: Wf1 layer z (512x2048); z>=4: Wf2 layer z-4 (2048x512). grid (64,64,8)
__global__ void transpose_rect(const float* __restrict__ Wf1, const float* __restrict__ Wf2,
                               bf16* __restrict__ f1t, bf16* __restrict__ f2t) {
    const size_t KN4 = (size_t)4 * H_ * H_;
    int z = blockIdx.z;
    const float* W; bf16* Wt; int K, N;
    if (z < 4) {
        if (blockIdx.x >= 16) return;          // K=512 -> 16 tiles
        W = Wf1 + (size_t)z * KN4; Wt = f1t + (size_t)z * KN4; K = 512; N = 2048;
    } else {
        if (blockIdx.y >= 16) return;          // N=512 -> 16 tiles
        W = Wf2 + (size_t)(z - 4) * KN4; Wt = f2t + (size_t)(z - 4) * KN4; K = 2048; N = 512;
    }
    __shared__ float t[32][33];
    int k0 = blockIdx.x * 32, n0 = blockIdx.y * 32;
    int tx = threadIdx.x, ty = threadIdx.y;
    #pragma unroll
    for (int r = ty; r < 32; r += 8)
        t[r][tx] = W[(size_t)(k0 + r) * N + n0 + tx];
    __syncthreads();
    #pragma unroll
    for (int r = ty; r < 32; r += 8)
        Wt[(size_t)(n0 + r) * K + k0 + tx] = f2bf(t[tx][r]);
}

// ---------------------------------------------------------------- LayerNorm (mid-layer)
__global__ void ln_bf_kernel(const float* __restrict__ in, bf16* __restrict__ out16) {
    int row = blockIdx.x;
    int tid = threadIdx.x;
    const float* r = in + (size_t)row * H_;
    float x0 = r[tid], x1 = r[tid + 256];
    float s = x0 + x1, sq = x0 * x0 + x1 * x1;
    #pragma unroll
    for (int off = 32; off; off >>= 1) {
        s  += __shfl_xor(s,  off);
        sq += __shfl_xor(sq, off);
    }
    __shared__ float ls[4], lq[4];
    int w = tid >> 6;
    if ((tid & 63) == 0) { ls[w] = s; lq[w] = sq; }
    __syncthreads();
    float S = ls[0] + ls[1] + ls[2] + ls[3];
    float Q = lq[0] + lq[1] + lq[2] + lq[3];
    float mean = S * (1.0f / H_);
    float var  = Q * (1.0f / H_) - mean * mean;
    float inv  = rsqrtf(var + 1e-5f);
    out16[(size_t)row * H_ + tid]       = f2bf((x0 - mean) * inv);
    out16[(size_t)row * H_ + tid + 256] = f2bf((x1 - mean) * inv);
}

// ------------------------- split-K reduce (+resid) fused with next-layer LN
template <bool DO_LN>
__global__ void reduce_ln_kernel(const float* __restrict__ part, const float* __restrict__ resid,
                                 float* __restrict__ x, float* __restrict__ xn,
                                 bf16* __restrict__ xn_bf) {
    const int MN = 512 * H_;
    int row = blockIdx.x;
    int tid = threadIdx.x;
    size_t base = (size_t)row * H_;
    float v0 = resid[base + tid], v1 = resid[base + tid + 256];
    #pragma unroll
    for (int s = 0; s < 4; ++s) {
        v0 += part[(size_t)s * MN + base + tid];
        v1 += part[(size_t)s * MN + base + tid + 256];
    }
    x[base + tid] = v0;
    x[base + tid + 256] = v1;
    if (DO_LN) {
        float s = v0 + v1, sq = v0 * v0 + v1 * v1;
        #pragma unroll
        for (int off = 32; off; off >>= 1) {
            s  += __shfl_xor(s,  off);
            sq += __shfl_xor(sq, off);
        }
        __shared__ float ls[4], lq[4];
        int w = tid >> 6;
        if ((tid & 63) == 0) { ls[w] = s; lq[w] = sq; }
        __syncthreads();
        float S = ls[0] + ls[1] + ls[2] + ls[3];
        float Q = lq[0] + lq[1] + lq[2] + lq[3];
        float mean = S * (1.0f / H_);
        float var  = Q * (1.0f / H_) - mean * mean;
        float inv  = rsqrtf(var + 1e-5f);
        float y0 = (v0 - mean) * inv, y1 = (v1 - mean) * inv;
        xn[base + tid]       = y0;
        xn[base + tid + 256] = y1;
        xn_bf[base + tid]       = f2bf(y0);
        xn_bf[base + tid + 256] = f2bf(y1);
    }
}

// ---------------------------------------------------------------- MFMA GEMM (large, 128x128)
// C = A @ Bt^T, bf16, fp32 accum. Async global_load_lds staging with XOR-swizzled
// lane map: lane (r=lane>>2, c=(lane&3)^(r&3)) fetches row r, 16B chunk c.
//  - Global: each 4-lane run covers one contiguous 64B line (permuted order) ->
//    same line set as linear map (coalescer-friendly; R7's K-major map was 4x lines).
//  - LDS: datum (row m, chunk q) at 64*m + 16*(q^(m&3)); frag read by lane (m0,q4)
//    gives per-8-lane bank residues {4 distinct}x2 -> 2-way aliasing = free (m136).
// EPI: 0 = fp32 store, 1 = fp32 store + R, 2 = relu -> bf16, 3 = bf16 store
#define BM 128
#define BN 128
#define BK 32
#define RSTR 80   // (gemm_s only) LDS row stride: 64 B data + 16 pad

template <int EPI>
__launch_bounds__(256)
__global__ void mfma_gemm(const bf16* __restrict__ A, const bf16* __restrict__ Bt,
                          void* __restrict__ Cv, const float* __restrict__ R,
                          int M, int N, int K) {
    __shared__ __align__(16) char lds[2 * BM * 64];   // 16 KB
    char* As = lds;
    char* Bs = lds + BM * 64;
    const int tid = threadIdx.x;
    const int bm = blockIdx.x * BM, bn = blockIdx.y * BN;
    Bt += (size_t)blockIdx.z * N * K;
    const int w = tid >> 6, lane = tid & 63;
    const int wr = (w >> 1) * 64, wc = (w & 1) * 64;
    const int m0 = lane & 15, q4 = lane >> 4;

    f32x4 acc[4][4] = {};

    const int sr = lane >> 2;                        // row within 16-row group
    const int scE = (((lane & 3) ^ (sr & 3)) * 8);   // swizzled 16B chunk (elements)
    const int fr = m0 * 64 + ((q4 ^ (m0 & 3)) * 16); // frag read byte offset in region

    for (int k0 = 0; k0 < K; k0 += BK) {
        __syncthreads();   // all waves done reading previous tile
        #pragma unroll
        for (int t = 0; t < 2; ++t) {
            gload_lds16(A  + (size_t)(bm + w * 32 + t * 16 + sr) * K + k0 + scE,
                        As + (w * 2 + t) * 1024);
            gload_lds16(Bt + (size_t)(bn + w * 32 + t * 16 + sr) * K + k0 + scE,
                        Bs + (w * 2 + t) * 1024);
        }
        __syncthreads();   // compiler drains vmcnt(0) before barrier -> tile visible
        short8 af[4], bfr[4];
        #pragma unroll
        for (int t = 0; t < 4; ++t) {
            af[t]  = *(const short8*)(As + (wr / 16 + t) * 1024 + fr);
            bfr[t] = *(const short8*)(Bs + (wc / 16 + t) * 1024 + fr);
        }
        #pragma unroll
        for (int mt = 0; mt < 4; ++mt)
            #pragma unroll
            for (int nt = 0; nt < 4; ++nt)
                acc[mt][nt] = __builtin_amdgcn_mfma_f32_16x16x32_bf16(
                    af[mt], bfr[nt], acc[mt][nt], 0, 0, 0);
    }

    // epilogue: C/D layout col = lane&15, row = quad*4 + reg  [m89/m91 verified]
    if (EPI <= 1) {
        float* C = (float*)Cv + (size_t)blockIdx.z * M * N;
        #pragma unroll
        for (int mt = 0; mt < 4; ++mt)
            #pragma unroll
            for (int i = 0; i < 4; ++i) {
                int row = bm + wr + mt * 16 + q4 * 4 + i;
                #pragma unroll
                for (int nt = 0; nt < 4; ++nt) {
                    int col = bn + wc + nt * 16 + m0;
                    float v = acc[mt][nt][i];
                    if (EPI == 1) v += R[(size_t)row * N + col];
                    C[(size_t)row * N + col] = v;
                }
            }
    } else {
        bf16* C = (bf16*)Cv;
        #pragma unroll
        for (int mt = 0; mt < 4; ++mt)
            #pragma unroll
            for (int i = 0; i < 4; ++i) {
                int row = bm + wr + mt * 16 + q4 * 4 + i;
                #pragma unroll
                for (int nt = 0; nt < 4; ++nt) {
                    int col = bn + wc + nt * 16 + m0;
                    float v = acc[mt][nt][i];
                    if (EPI == 2) v = fmaxf(v, 0.0f);
                    C[(size_t)row * N + col] = __float2bfloat16(v);
                }
            }
    }
}

// ------------------------------------------- MFMA GEMM (small, 64x64, BK=64)
template <int EPI, bool SPLIT>
__launch_bounds__(256)
__global__ void mfma_gemm_s(const bf16* __restrict__ A, const bf16* __restrict__ Bt,
                            void* __restrict__ Cv, const float* __restrict__ R,
                            int M, int N, int K) {
    __shared__ __align__(16) char lds[4 * 64 * RSTR];   // 20 KB
    char* As = lds;
    char* Bs = lds + 2 * 64 * RSTR;
    const int tid = threadIdx.x;
    const int bm = blockIdx.x * 64, bn = blockIdx.y * 64;
    int kbeg = 0, kend = K;
    if (SPLIT) {
        int ks = K / gridDim.z;
        kbeg = blockIdx.z * ks;
        kend = kbeg + ks;
    } else {
        Bt += (size_t)blockIdx.z * N * K;
    }
    const int w = tid >> 6, lane = tid & 63;
    const int wr = (w >> 1) * 32, wc = (w & 1) * 32;
    const int m0 = lane & 15, q4 = lane >> 4;

    f32x4 acc[2][2] = {};

    const int rA = tid >> 3;              // 0..31
    const int cA = tid & 7;
    const int ksP = cA >> 2;              // K-plane
    const int cB = (cA & 3) * 16;
    const int cE = cA * 8;

    for (int k0 = kbeg; k0 < kend; k0 += 64) {
        uint4 a0 = *(const uint4*)(A  + (size_t)(bm + rA) * K + k0 + cE);
        uint4 a1 = *(const uint4*)(A  + (size_t)(bm + rA + 32) * K + k0 + cE);
        uint4 b0 = *(const uint4*)(Bt + (size_t)(bn + rA) * K + k0 + cE);
        uint4 b1 = *(const uint4*)(Bt + (size_t)(bn + rA + 32) * K + k0 + cE);
        __syncthreads();
        *(uint4*)(As + ksP * (64 * RSTR) + rA * RSTR + cB) = a0;
        *(uint4*)(As + ksP * (64 * RSTR) + (rA + 32) * RSTR + cB) = a1;
        *(uint4*)(Bs + ksP * (64 * RSTR) + rA * RSTR + cB) = b0;
        *(uint4*)(Bs + ksP * (64 * RSTR) + (rA + 32) * RSTR + cB) = b1;
        __syncthreads();
        short8 af[2][2], bfr[2][2];
        #pragma unroll
        for (int ks = 0; ks < 2; ++ks)
            #pragma unroll
            for (int t = 0; t < 2; ++t) {
                af[ks][t]  = *(const short8*)(As + ks * (64 * RSTR) + (wr + t * 16 + m0) * RSTR + q4 * 16);
                bfr[ks][t] = *(const short8*)(Bs + ks * (64 * RSTR) + (wc + t * 16 + m0) * RSTR + q4 * 16);
            }
        #pragma unroll
        for (int ks = 0; ks < 2; ++ks)
            #pragma unroll
            for (int mt = 0; mt < 2; ++mt)
                #pragma unroll
                for (int nt = 0; nt < 2; ++nt)
                    acc[mt][nt] = __builtin_amdgcn_mfma_f32_16x16x32_bf16(
                        af[ks][mt], bfr[ks][nt], acc[mt][nt], 0, 0, 0);
    }

    if (SPLIT) {
        float* C = (float*)Cv + (size_t)blockIdx.z * M * N;
        #pragma unroll
        for (int mt = 0; mt < 2; ++mt)
            #pragma unroll
            for (int i = 0; i < 4; ++i) {
                int row = bm + wr + mt * 16 + q4 * 4 + i;
                #pragma unroll
                for (int nt = 0; nt < 2; ++nt)
                    C[(size_t)row * N + bn + wc + nt * 16 + m0] = acc[mt][nt][i];
            }
    } else if (EPI <= 1) {
        float* C = (float*)Cv + (size_t)blockIdx.z * M * N;
        #pragma unroll
        for (int mt = 0; mt < 2; ++mt)
            #pragma unroll
            for (int i = 0; i < 4; ++i) {
                int row = bm + wr + mt * 16 + q4 * 4 + i;
                #pragma unroll
                for (int nt = 0; nt < 2; ++nt) {
                    int col = bn + wc + nt * 16 + m0;
                    float v = acc[mt][nt][i];
                    if (EPI == 1) v += R[(size_t)row * N + col];
                    C[(size_t)row * N + col] = v;
                }
            }
    } else {
        bf16* C = (bf16*)Cv;
        #pragma unroll
        for (int mt = 0; mt < 2; ++mt)
            #pragma unroll
            for (int i = 0; i < 4; ++i) {
                int row = bm + wr + mt * 16 + q4 * 4 + i;
                #pragma unroll
                for (int nt = 0; nt < 2; ++nt) {
                    int col = bn + wc + nt * 16 + m0;
                    float v = acc[mt][nt][i];
                    if (EPI == 2) v = fmaxf(v, 0.0f);
                    C[(size_t)row * N + col] = __float2bfloat16(v);
                }
            }
    }
}

// ---------------------------------------------------------------- attention
__global__ void attn_kernel(const float* __restrict__ qkv, const bf16* __restrict__ ew,
                            const int* __restrict__ adj, bf16* __restrict__ o) {
    const float* q = qkv;
    const float* k = qkv + (size_t)512 * H_;
    const float* v = qkv + (size_t)1024 * H_;
    int bi = blockIdx.x;           // b*64 + i
    int b  = bi >> 6;
    int ty = threadIdx.y;
    int h  = blockIdx.y * 4 + ty;
    int lane = threadIdx.x;        // 64
    __shared__ float qs[4][64], as[4][64];
    qs[ty][lane] = q[(size_t)bi * H_ + h * 64 + lane];
    __syncthreads();

    int j = lane;
    const float4* k4 = (const float4*)(k + (size_t)(b * 64 + j) * H_ + h * 64);
    const uint4*  w4 = (const uint4*)(ew + ((size_t)bi * 64 + j) * H_ + h * 64);
    float acc = 0.f;
    #pragma unroll
    for (int t = 0; t < 8; ++t) {
        uint4 wu = w4[t];
        float4 ka = k4[2 * t], kb = k4[2 * t + 1];
        float wf[8];
        unpack8(wu, wf);
        const float* qq = &qs[ty][t * 8];
        acc += qq[0] * (ka.x + wf[0]) + qq[1] * (ka.y + wf[1])
             + qq[2] * (ka.z + wf[2]) + qq[3] * (ka.w + wf[3])
             + qq[4] * (kb.x + wf[4]) + qq[5] * (kb.y + wf[5])
             + qq[6] * (kb.z + wf[6]) + qq[7] * (kb.w + wf[7]);
    }
    float logit = acc * INV_SCALE;
    if (adj[(size_t)bi * 64 + j] <= 0) logit = -INFINITY;

    float m = logit;
    #pragma unroll
    for (int off = 32; off; off >>= 1) m = fmaxf(m, __shfl_xor(m, off));
    float p = expf(logit - m);
    float s = p;
    #pragma unroll
    for (int off = 32; off; off >>= 1) s += __shfl_xor(s, off);
    as[ty][lane] = p / s;
    __syncthreads();

    const float* vbase = v + (size_t)(b * 64) * H_ + h * 64;
    float oacc = 0.f;
    int d = lane;
    #pragma unroll 8
    for (int jj = 0; jj < 64; ++jj)
        oacc += as[ty][jj] * vbase[(size_t)jj * H_ + d];
    o[(size_t)bi * H_ + h * 64 + d] = __float2bfloat16(oacc);
}

// ---------------------------------------------------------------- edge update
__global__ void edge_kernel(const bf16* __restrict__ ew, const float* __restrict__ x,
                            bf16* __restrict__ bond) {
    int pair = blockIdx.x * 4 + threadIdx.y;   // (b*64+i)*64 + j
    int b = pair >> 12;
    int i = (pair >> 6) & 63;
    int j = pair & 63;
    int lane = threadIdx.x;
    const uint4*  e4  = (const uint4*)(ew + (size_t)pair * H_);
    const float4* xi4 = (const float4*)(x + (size_t)(b * 64 + i) * H_);
    const float4* xj4 = (const float4*)(x + (size_t)(b * 64 + j) * H_);
    uint4  eu = e4[lane];
    float4 a0 = xi4[lane * 2], a1 = xi4[lane * 2 + 1];
    float4 c0 = xj4[lane * 2], c1 = xj4[lane * 2 + 1];
    float ef[8], af[8], cf[8];
    unpack8(eu, ef);
    af[0] = a0.x; af[1] = a0.y; af[2] = a0.z; af[3] = a0.w;
    af[4] = a1.x; af[5] = a1.y; af[6] = a1.z; af[7] = a1.w;
    cf[0] = c0.x; cf[1] = c0.y; cf[2] = c0.z; cf[3] = c0.w;
    cf[4] = c1.x; cf[5] = c1.y; cf[6] = c1.z; cf[7] = c1.w;
    float s0 = 0.f, s1 = 0.f, s2 = 0.f;
    #pragma unroll
    for (int t = 0; t < 8; ++t) {
        s0 += ef[t] * ef[t]; s1 += ef[t] * af[t]; s2 += ef[t] * cf[t];
    }
    #pragma unroll
    for (int off = 32; off; off >>= 1) {
        s0 += __shfl_xor(s0, off);
        s1 += __shfl_xor(s1, off);
        s2 += __shfl_xor(s2, off);
    }
    float t0 = s0 * INV_SCALE, t1 = s1 * INV_SCALE, t2 = s2 * INV_SCALE;
    float m = fmaxf(t0, fmaxf(t1, t2));
    float e0 = expf(t0 - m), e1 = expf(t1 - m), e2 = expf(t2 - m);
    float inv = 1.0f / (e0 + e1 + e2);
    float w0 = e0 * inv, w1 = e1 * inv, w2 = e2 * inv;
    __align__(16) bf16 ob[8];
    #pragma unroll
    for (int t = 0; t < 8; ++t)
        ob[t] = __float2bfloat16(w0 * ef[t] + w1 * af[t] + w2 * cf[t]);
    *(uint4*)(bond + (size_t)pair * H_ + lane * 8) = *(const uint4*)ob;
}

// ---------------------------------------------------------------- head (fused cls+pred)
__global__ void cls_pred_kernel(const float* __restrict__ x, const float* __restrict__ Wout,
                                const float* __restrict__ Wpred, const float* __restrict__ bpred,
                                float* __restrict__ out) {
    int b = blockIdx.x;
    int tid = threadIdx.x;
    __shared__ float xr[512];
    __shared__ float red0[4], red1[4];
    const float* row = x + (size_t)(b * 64) * H_;   // x[b,0,:]
    xr[tid] = row[tid];
    xr[tid + 256] = row[tid + 256];
    __syncthreads();
    float a0 = 0.f, a1 = 0.f;
    #pragma unroll
    for (int t = 0; t < 2; ++t) {
        int c = tid + t * 256;
        float acc = 0.f;
        for (int h = 0; h < 512; ++h)
            acc += xr[h] * Wout[(size_t)h * H_ + c];
        float tv = tanhf(acc);
        a0 += tv * Wpred[c * 2 + 0];
        a1 += tv * Wpred[c * 2 + 1];
    }
    #pragma unroll
    for (int off = 32; off; off >>= 1) {
        a0 += __shfl_xor(a0, off);
        a1 += __shfl_xor(a1, off);
    }
    int w = tid >> 6;
    if ((tid & 63) == 0) { red0[w] = a0; red1[w] = a1; }
    __syncthreads();
    if (tid == 0) {
        float s0 = red0[0] + red0[1] + red0[2] + red0[3] + bpred[0];
        float s1 = red1[0] + red1[1] + red1[2] + red1[3] + bpred[1];
        float m = fmaxf(s0, s1);
        float e0 = expf(s0 - m), e1 = expf(s1 - m);
        float inv = 1.0f / (e0 + e1);
        out[b * 2 + 0] = e0 * inv;
        out[b * 2 + 1] = e1 * inv;
    }
}

// ---------------------------------------------------------------- launch
extern "C" void kernel_launch(void* const* d_in, const int* in_sizes, int n_in,
                              void* d_out, int out_size, void* d_ws, size_t ws_size,
                              hipStream_t stream) {
    const int*   ids      = (const int*)d_in[0];
    const int*   adj      = (const int*)d_in[1];
    const float* atom_emb = (const float*)d_in[2];
    const float* bond_emb = (const float*)d_in[3];
    const float* Wq     = (const float*)d_in[4];
    const float* Wk     = (const float*)d_in[5];
    const float* Wv     = (const float*)d_in[6];
    const float* Wew    = (const float*)d_in[7];
    const float* Wstack = (const float*)d_in[8];
    const float* Wf1    = (const float*)d_in[9];
    const float* Wf2    = (const float*)d_in[10];
    const float* Wout   = (const float*)d_in[11];
    const float* Wpred  = (const float*)d_in[12];
    const float* bpred  = (const float*)d_in[13];

    char* ws = (char*)d_ws;
    size_t off = 0;
    auto alloc = [&](size_t bytes) {
        size_t o = off;
        off += (bytes + 255) & ~(size_t)255;
        return o;
    };
    const size_t ROWS  = (size_t)B_ * N_;           // 512
    const size_t PAIRS = (size_t)B_ * N_ * N_;      // 32768
    const size_t KN    = (size_t)H_ * H_;           // 262144

    float* x       = (float*)(ws + alloc(ROWS * H_ * 4));
    float* xn      = (float*)(ws + alloc(ROWS * H_ * 4));
    bf16*  xn_bf   = (bf16*) (ws + alloc(ROWS * H_ * 2));
    float* qkv     = (float*)(ws + alloc(3 * ROWS * H_ * 4));
    bf16*  o_bf    = (bf16*) (ws + alloc(ROWS * H_ * 2));
    float* resid   = (float*)(ws + alloc(ROWS * H_ * 4));
    bf16*  ffin_bf = (bf16*) (ws + alloc(ROWS * H_ * 2));
    bf16*  ffh_bf  = (bf16*) (ws + alloc(ROWS * 4 * H_ * 2));
    float* part    = (float*)(ws + alloc(4 * ROWS * H_ * 4));   // split-K partials
    bf16*  E0      = (bf16*) (ws + alloc(8 * H_ * 2));          // 8 KB
    bf16*  bond    = (bf16*) (ws + alloc(PAIRS * H_ * 2));      // 32 MB
    bf16*  ew      = (bf16*) (ws + alloc(PAIRS * H_ * 2));      // 32 MB
    bf16*  qkvt    = (bf16*) (ws + alloc((size_t)L_ * 3 * KN * 2));
    bf16*  ewt     = (bf16*) (ws + alloc((size_t)L_ * KN * 2));
    bf16*  stackt  = (bf16*) (ws + alloc((size_t)L_ * KN * 2));
    bf16*  f1t     = (bf16*) (ws + alloc((size_t)L_ * 4 * KN * 2));
    bf16*  f2t     = (bf16*) (ws + alloc((size_t)L_ * 4 * KN * 2));
    (void)ws_size;

    embed_ln_kernel<<<512, 256, 0, stream>>>(ids, atom_emb, xn, xn_bf);

    // one-time weight transpose + bf16 cast (2 launches)
    dim3 tb(32, 8);
    transpose_sq<<<dim3(16, 16, 20), tb, 0, stream>>>(Wq, Wk, Wv, Wew, Wstack,
                                                      qkvt, ewt, stackt);
    transpose_rect<<<dim3(64, 64, 8), tb, 0, stream>>>(Wf1, Wf2, f1t, f2t);

    // layer-0 ew factorization: 8 distinct bond rows -> precompute + gather
    ew0_precompute<<<dim3(8, 8), 64, 0, stream>>>(bond_emb, ewt, E0);
    ew0_gather<<<8192, 256, 0, stream>>>(adj, E0, ew);

    for (int l = 0; l < L_; ++l) {
        // q,k,v fused small-tile: z selects weight slice and output slice
        mfma_gemm_s<0, false><<<dim3(8, 8, 3), 256, 0, stream>>>(
            xn_bf, qkvt + (size_t)l * 3 * KN, qkv, nullptr, 512, 512, 512);
        // ew = bond @ Wew (layers >=1; layer 0 comes from the gather)
        if (l > 0)
            mfma_gemm<3><<<dim3(256, 4), 256, 0, stream>>>(
                bond, ewt + (size_t)l * KN, ew, nullptr, 32768, 512, 512);
        attn_kernel<<<dim3(512, 2), dim3(64, 4), 0, stream>>>(qkv, ew, adj, o_bf);
        // resid = o @ Wstack + xn
        mfma_gemm_s<1, false><<<dim3(8, 8), 256, 0, stream>>>(
            o_bf, stackt + (size_t)l * KN, resid, xn, 512, 512, 512);
        ln_bf_kernel<<<512, 256, 0, stream>>>(resid, ffin_bf);
        // ffh = relu(ffin @ Wf1)
        mfma_gemm_s<2, false><<<dim3(8, 32), 256, 0, stream>>>(
            ffin_bf, f1t + (size_t)l * 4 * KN, ffh_bf, nullptr, 512, 2048, 512);
        // x = ffh @ Wf2 + resid : split-K x4
        mfma_gemm_s<0, true><<<dim3(8, 8, 4), 256, 0, stream>>>(
            ffh_bf, f2t + (size_t)l * 4 * KN, part, nullptr, 512, 512, 2048);
        if (l < L_ - 1)
            reduce_ln_kernel<true><<<512, 256, 0, stream>>>(part, resid, x, xn, xn_bf);
        else
            reduce_ln_kernel<false><<<512, 256, 0, stream>>>(part, resid, x, xn, xn_bf);
        // bond for next layer (last layer's edge output is never read -> skip)
        if (l < L_ - 1)
            edge_kernel<<<8192, dim3(64, 4), 0, stream>>>(ew, x, bond);
    }

    cls_pred_kernel<<<8, 256, 0, stream>>>(x, Wout, Wpred, bpred, (float*)d_out);
}

// Round 9
// 528.293 us; speedup vs baseline: 5.1161x; 1.0706x over previous
//
#include <hip/hip_runtime.h>
#include <hip/hip_bf16.h>

typedef __hip_bfloat16 bf16;

// Problem constants
#define B_     8
#define N_     64
#define H_     512
#define HEADS_ 8
#define SP_    64
#define L_     4
static constexpr float INV_SCALE = 0.044194173824159216f; // 1/sqrt(512)

// MFMA fragment types (per guide §3: short8 = 8 bf16 = 4 VGPRs)
typedef __attribute__((ext_vector_type(8))) short short8;
typedef __attribute__((ext_vector_type(4))) float f32x4;

// async global->LDS, 16B per lane; LDS dest is wave-uniform base + lane*16
__device__ __forceinline__ void gload_lds16(const void* g, void* l) {
    __builtin_amdgcn_global_load_lds(
        (const __attribute__((address_space(1))) unsigned int*)g,
        (__attribute__((address_space(3))) unsigned int*)l, 16, 0, 0);
}

__device__ __forceinline__ void unpack8(uint4 u, float* f) {
    f[0] = __uint_as_float(u.x << 16); f[1] = __uint_as_float(u.x & 0xffff0000u);
    f[2] = __uint_as_float(u.y << 16); f[3] = __uint_as_float(u.y & 0xffff0000u);
    f[4] = __uint_as_float(u.z << 16); f[5] = __uint_as_float(u.z & 0xffff0000u);
    f[6] = __uint_as_float(u.w << 16); f[7] = __uint_as_float(u.w & 0xffff0000u);
}

__device__ __forceinline__ bf16 f2bf(float v) { return __float2bfloat16(v); }

// ---------------------------------------------------------------- embeddings
// fused: x = atom_emb[ids[row]]; LN -> xn (fp32), xn_bf (bf16). x never stored.
__global__ void embed_ln_kernel(const int* __restrict__ ids,
                                const float* __restrict__ emb,
                                float* __restrict__ xn, bf16* __restrict__ xn_bf) {
    int row = blockIdx.x;
    int tid = threadIdx.x;
    const float* r = emb + (size_t)ids[row] * H_;
    float x0 = r[tid], x1 = r[tid + 256];
    float s = x0 + x1, sq = x0 * x0 + x1 * x1;
    #pragma unroll
    for (int off = 32; off; off >>= 1) {
        s  += __shfl_xor(s,  off);
        sq += __shfl_xor(sq, off);
    }
    __shared__ float ls[4], lq[4];
    int w = tid >> 6;
    if ((tid & 63) == 0) { ls[w] = s; lq[w] = sq; }
    __syncthreads();
    float S = ls[0] + ls[1] + ls[2] + ls[3];
    float Q = lq[0] + lq[1] + lq[2] + lq[3];
    float mean = S * (1.0f / H_);
    float var  = Q * (1.0f / H_) - mean * mean;
    float inv  = rsqrtf(var + 1e-5f);
    float y0 = (x0 - mean) * inv, y1 = (x1 - mean) * inv;
    xn[(size_t)row * H_ + tid]       = y0;
    xn[(size_t)row * H_ + tid + 256] = y1;
    xn_bf[(size_t)row * H_ + tid]       = f2bf(y0);
    xn_bf[(size_t)row * H_ + tid + 256] = f2bf(y1);
}

// -------- layer-0 ew factorization: E0[t] = bond_emb[t] @ Wew[0]  (8x512)
__global__ void ew0_precompute(const float* __restrict__ bond_emb,
                               const bf16* __restrict__ ewt0, bf16* __restrict__ E0) {
    int t = blockIdx.x, cb = blockIdx.y, lane = threadIdx.x;
    int c = cb * 64 + lane;
    __shared__ float be[512];
    for (int h = lane; h < 512; h += 64) be[h] = bond_emb[t * 512 + h];
    __syncthreads();
    const bf16* wr = ewt0 + (size_t)c * 512;
    float acc = 0.f;
    for (int h8 = 0; h8 < 64; ++h8) {
        uint4 u = *(const uint4*)(wr + h8 * 8);
        float wf[8];
        unpack8(u, wf);
        const float* b = &be[h8 * 8];
        acc += b[0]*wf[0] + b[1]*wf[1] + b[2]*wf[2] + b[3]*wf[3]
             + b[4]*wf[4] + b[5]*wf[5] + b[6]*wf[6] + b[7]*wf[7];
    }
    E0[t * 512 + c] = f2bf(acc);
}

// ew0 = E0[adj]  (pure gather, 32 MB write)
__global__ void ew0_gather(const int* __restrict__ adj, const bf16* __restrict__ E0,
                           bf16* __restrict__ ew) {
    int gid = blockIdx.x * 256 + threadIdx.x;   // 2,097,152
    int pair = gid >> 6;
    int c    = gid & 63;
    uint4 v = *(const uint4*)(E0 + (size_t)adj[pair] * H_ + c * 8);
    *(uint4*)(ew + (size_t)pair * H_ + c * 8) = v;
}

// ------------------------------------------------- weight transpose + cast
__global__ void transpose_sq(const float* __restrict__ Wq, const float* __restrict__ Wk,
                             const float* __restrict__ Wv, const float* __restrict__ Wew,
                             const float* __restrict__ Wst,
                             bf16* __restrict__ qkvt, bf16* __restrict__ ewt,
                             bf16* __restrict__ stackt) {
    const size_t KN = (size_t)H_ * H_;
    int z = blockIdx.z;
    const float* W; bf16* Wt;
    if (z < 12) {
        int s = z >> 2, l = z & 3;
        W  = (s == 0 ? Wq : s == 1 ? Wk : Wv) + (size_t)l * KN;
        Wt = qkvt + (size_t)l * 3 * KN + (size_t)s * KN;
    } else if (z < 16) {
        int l = z - 12;
        W = Wew + (size_t)l * KN; Wt = ewt + (size_t)l * KN;
    } else {
        int l = z - 16;
        W = Wst + (size_t)l * KN; Wt = stackt + (size_t)l * KN;
    }
    __shared__ float t[32][33];
    int k0 = blockIdx.x * 32, n0 = blockIdx.y * 32;
    int tx = threadIdx.x, ty = threadIdx.y;  // 32, 8
    #pragma unroll
    for (int r = ty; r < 32; r += 8)
        t[r][tx] = W[(size_t)(k0 + r) * H_ + n0 + tx];
    __syncthreads();
    #pragma unroll
    for (int r = ty; r < 32; r += 8)
        Wt[(size_t)(n0 + r) * H_ + k0 + tx] = f2bf(t[tx][r]);
}

// rect set: z<4: Wf1 layer z (512x2048); z>=4: Wf2 layer z-4 (2048x512). grid (64,64,8)
__global__ void transpose_rect(const float* __restrict__ Wf1, const float* __restrict__ Wf2,
                               bf16* __restrict__ f1t, bf16* __restrict__ f2t) {
    const size_t KN4 = (size_t)4 * H_ * H_;
    int z = blockIdx.z;
    const float* W; bf16* Wt; int K, N;
    if (z < 4) {
        if (blockIdx.x >= 16) return;          // K=512 -> 16 tiles
        W = Wf1 + (size_t)z * KN4; Wt = f1t + (size_t)z * KN4; K = 512; N = 2048;
    } else {
        if (blockIdx.y >= 16) return;          // N=512 -> 16 tiles
        W = Wf2 + (size_t)(z - 4) * KN4; Wt = f2t + (size_t)(z - 4) * KN4; K = 2048; N = 512;
    }
    __shared__ float t[32][33];
    int k0 = blockIdx.x * 32, n0 = blockIdx.y * 32;
    int tx = threadIdx.x, ty = threadIdx.y;
    #pragma unroll
    for (int r = ty; r < 32; r += 8)
        t[r][tx] = W[(size_t)(k0 + r) * N + n0 + tx];
    __syncthreads();
    #pragma unroll
    for (int r = ty; r < 32; r += 8)
        Wt[(size_t)(n0 + r) * K + k0 + tx] = f2bf(t[tx][r]);
}

// ---------------------------------------------------------------- LayerNorm (mid-layer)
__global__ void ln_bf_kernel(const float* __restrict__ in, bf16* __restrict__ out16) {
    int row = blockIdx.x;
    int tid = threadIdx.x;
    const float* r = in + (size_t)row * H_;
    float x0 = r[tid], x1 = r[tid + 256];
    float s = x0 + x1, sq = x0 * x0 + x1 * x1;
    #pragma unroll
    for (int off = 32; off; off >>= 1) {
        s  += __shfl_xor(s,  off);
        sq += __shfl_xor(sq, off);
    }
    __shared__ float ls[4], lq[4];
    int w = tid >> 6;
    if ((tid & 63) == 0) { ls[w] = s; lq[w] = sq; }
    __syncthreads();
    float S = ls[0] + ls[1] + ls[2] + ls[3];
    float Q = lq[0] + lq[1] + lq[2] + lq[3];
    float mean = S * (1.0f / H_);
    float var  = Q * (1.0f / H_) - mean * mean;
    float inv  = rsqrtf(var + 1e-5f);
    out16[(size_t)row * H_ + tid]       = f2bf((x0 - mean) * inv);
    out16[(size_t)row * H_ + tid + 256] = f2bf((x1 - mean) * inv);
}

// ------------------------- split-K reduce (+resid) fused with next-layer LN
template <bool DO_LN>
__global__ void reduce_ln_kernel(const float* __restrict__ part, const float* __restrict__ resid,
                                 float* __restrict__ x, float* __restrict__ xn,
                                 bf16* __restrict__ xn_bf) {
    const int MN = 512 * H_;
    int row = blockIdx.x;
    int tid = threadIdx.x;
    size_t base = (size_t)row * H_;
    float v0 = resid[base + tid], v1 = resid[base + tid + 256];
    #pragma unroll
    for (int s = 0; s < 4; ++s) {
        v0 += part[(size_t)s * MN + base + tid];
        v1 += part[(size_t)s * MN + base + tid + 256];
    }
    x[base + tid] = v0;
    x[base + tid + 256] = v1;
    if (DO_LN) {
        float s = v0 + v1, sq = v0 * v0 + v1 * v1;
        #pragma unroll
        for (int off = 32; off; off >>= 1) {
            s  += __shfl_xor(s,  off);
            sq += __shfl_xor(sq, off);
        }
        __shared__ float ls[4], lq[4];
        int w = tid >> 6;
        if ((tid & 63) == 0) { ls[w] = s; lq[w] = sq; }
        __syncthreads();
        float S = ls[0] + ls[1] + ls[2] + ls[3];
        float Q = lq[0] + lq[1] + lq[2] + lq[3];
        float mean = S * (1.0f / H_);
        float var  = Q * (1.0f / H_) - mean * mean;
        float inv  = rsqrtf(var + 1e-5f);
        float y0 = (v0 - mean) * inv, y1 = (v1 - mean) * inv;
        xn[base + tid]       = y0;
        xn[base + tid + 256] = y1;
        xn_bf[base + tid]       = f2bf(y0);
        xn_bf[base + tid + 256] = f2bf(y1);
    }
}

// ---------------------------------------------------------------- MFMA GEMM (large, 128x128)
// C = A @ Bt^T, bf16, fp32 accum. Async global_load_lds staging with XOR-swizzled
// lane map (R8-verified: global 64B-contiguous per 4-lane run, LDS 2-way only).
// EPI: 0 = fp32 store, 1 = fp32 store + R, 2 = relu -> bf16, 3 = bf16 store
#define BM 128
#define BN 128
#define BK 32
#define RSTR 80   // (gemm_s only) LDS row stride: 64 B data + 16 pad

template <int EPI>
__launch_bounds__(256)
__global__ void mfma_gemm(const bf16* __restrict__ A, const bf16* __restrict__ Bt,
                          void* __restrict__ Cv, const float* __restrict__ R,
                          int M, int N, int K) {
    __shared__ __align__(16) char lds[2 * BM * 64];   // 16 KB
    char* As = lds;
    char* Bs = lds + BM * 64;
    const int tid = threadIdx.x;
    const int bm = blockIdx.x * BM, bn = blockIdx.y * BN;
    Bt += (size_t)blockIdx.z * N * K;
    const int w = tid >> 6, lane = tid & 63;
    const int wr = (w >> 1) * 64, wc = (w & 1) * 64;
    const int m0 = lane & 15, q4 = lane >> 4;

    f32x4 acc[4][4] = {};

    const int sr = lane >> 2;                        // row within 16-row group
    const int scE = (((lane & 3) ^ (sr & 3)) * 8);   // swizzled 16B chunk (elements)
    const int fr = m0 * 64 + ((q4 ^ (m0 & 3)) * 16); // frag read byte offset in region

    for (int k0 = 0; k0 < K; k0 += BK) {
        __syncthreads();   // all waves done reading previous tile
        #pragma unroll
        for (int t = 0; t < 2; ++t) {
            gload_lds16(A  + (size_t)(bm + w * 32 + t * 16 + sr) * K + k0 + scE,
                        As + (w * 2 + t) * 1024);
            gload_lds16(Bt + (size_t)(bn + w * 32 + t * 16 + sr) * K + k0 + scE,
                        Bs + (w * 2 + t) * 1024);
        }
        __syncthreads();   // compiler drains vmcnt(0) before barrier -> tile visible
        short8 af[4], bfr[4];
        #pragma unroll
        for (int t = 0; t < 4; ++t) {
            af[t]  = *(const short8*)(As + (wr / 16 + t) * 1024 + fr);
            bfr[t] = *(const short8*)(Bs + (wc / 16 + t) * 1024 + fr);
        }
        #pragma unroll
        for (int mt = 0; mt < 4; ++mt)
            #pragma unroll
            for (int nt = 0; nt < 4; ++nt)
                acc[mt][nt] = __builtin_amdgcn_mfma_f32_16x16x32_bf16(
                    af[mt], bfr[nt], acc[mt][nt], 0, 0, 0);
    }

    // epilogue: C/D layout col = lane&15, row = quad*4 + reg  [m89/m91 verified]
    if (EPI <= 1) {
        float* C = (float*)Cv + (size_t)blockIdx.z * M * N;
        #pragma unroll
        for (int mt = 0; mt < 4; ++mt)
            #pragma unroll
            for (int i = 0; i < 4; ++i) {
                int row = bm + wr + mt * 16 + q4 * 4 + i;
                #pragma unroll
                for (int nt = 0; nt < 4; ++nt) {
                    int col = bn + wc + nt * 16 + m0;
                    float v = acc[mt][nt][i];
                    if (EPI == 1) v += R[(size_t)row * N + col];
                    C[(size_t)row * N + col] = v;
                }
            }
    } else {
        bf16* C = (bf16*)Cv;
        #pragma unroll
        for (int mt = 0; mt < 4; ++mt)
            #pragma unroll
            for (int i = 0; i < 4; ++i) {
                int row = bm + wr + mt * 16 + q4 * 4 + i;
                #pragma unroll
                for (int nt = 0; nt < 4; ++nt) {
                    int col = bn + wc + nt * 16 + m0;
                    float v = acc[mt][nt][i];
                    if (EPI == 2) v = fmaxf(v, 0.0f);
                    C[(size_t)row * N + col] = __float2bfloat16(v);
                }
            }
    }
}

// ------------------------------------------- MFMA GEMM (small, 64x64, BK=64)
template <int EPI, bool SPLIT>
__launch_bounds__(256)
__global__ void mfma_gemm_s(const bf16* __restrict__ A, const bf16* __restrict__ Bt,
                            void* __restrict__ Cv, const float* __restrict__ R,
                            int M, int N, int K) {
    __shared__ __align__(16) char lds[4 * 64 * RSTR];   // 20 KB
    char* As = lds;
    char* Bs = lds + 2 * 64 * RSTR;
    const int tid = threadIdx.x;
    const int bm = blockIdx.x * 64, bn = blockIdx.y * 64;
    int kbeg = 0, kend = K;
    if (SPLIT) {
        int ks = K / gridDim.z;
        kbeg = blockIdx.z * ks;
        kend = kbeg + ks;
    } else {
        Bt += (size_t)blockIdx.z * N * K;
    }
    const int w = tid >> 6, lane = tid & 63;
    const int wr = (w >> 1) * 32, wc = (w & 1) * 32;
    const int m0 = lane & 15, q4 = lane >> 4;

    f32x4 acc[2][2] = {};

    const int rA = tid >> 3;              // 0..31
    const int cA = tid & 7;
    const int ksP = cA >> 2;              // K-plane
    const int cB = (cA & 3) * 16;
    const int cE = cA * 8;

    for (int k0 = kbeg; k0 < kend; k0 += 64) {
        uint4 a0 = *(const uint4*)(A  + (size_t)(bm + rA) * K + k0 + cE);
        uint4 a1 = *(const uint4*)(A  + (size_t)(bm + rA + 32) * K + k0 + cE);
        uint4 b0 = *(const uint4*)(Bt + (size_t)(bn + rA) * K + k0 + cE);
        uint4 b1 = *(const uint4*)(Bt + (size_t)(bn + rA + 32) * K + k0 + cE);
        __syncthreads();
        *(uint4*)(As + ksP * (64 * RSTR) + rA * RSTR + cB) = a0;
        *(uint4*)(As + ksP * (64 * RSTR) + (rA + 32) * RSTR + cB) = a1;
        *(uint4*)(Bs + ksP * (64 * RSTR) + rA * RSTR + cB) = b0;
        *(uint4*)(Bs + ksP * (64 * RSTR) + (rA + 32) * RSTR + cB) = b1;
        __syncthreads();
        short8 af[2][2], bfr[2][2];
        #pragma unroll
        for (int ks = 0; ks < 2; ++ks)
            #pragma unroll
            for (int t = 0; t < 2; ++t) {
                af[ks][t]  = *(const short8*)(As + ks * (64 * RSTR) + (wr + t * 16 + m0) * RSTR + q4 * 16);
                bfr[ks][t] = *(const short8*)(Bs + ks * (64 * RSTR) + (wc + t * 16 + m0) * RSTR + q4 * 16);
            }
        #pragma unroll
        for (int ks = 0; ks < 2; ++ks)
            #pragma unroll
            for (int mt = 0; mt < 2; ++mt)
                #pragma unroll
                for (int nt = 0; nt < 2; ++nt)
                    acc[mt][nt] = __builtin_amdgcn_mfma_f32_16x16x32_bf16(
                        af[ks][mt], bfr[ks][nt], acc[mt][nt], 0, 0, 0);
    }

    if (SPLIT) {
        float* C = (float*)Cv + (size_t)blockIdx.z * M * N;
        #pragma unroll
        for (int mt = 0; mt < 2; ++mt)
            #pragma unroll
            for (int i = 0; i < 4; ++i) {
                int row = bm + wr + mt * 16 + q4 * 4 + i;
                #pragma unroll
                for (int nt = 0; nt < 2; ++nt)
                    C[(size_t)row * N + bn + wc + nt * 16 + m0] = acc[mt][nt][i];
            }
    } else if (EPI <= 1) {
        float* C = (float*)Cv + (size_t)blockIdx.z * M * N;
        #pragma unroll
        for (int mt = 0; mt < 2; ++mt)
            #pragma unroll
            for (int i = 0; i < 4; ++i) {
                int row = bm + wr + mt * 16 + q4 * 4 + i;
                #pragma unroll
                for (int nt = 0; nt < 2; ++nt) {
                    int col = bn + wc + nt * 16 + m0;
                    float v = acc[mt][nt][i];
                    if (EPI == 1) v += R[(size_t)row * N + col];
                    C[(size_t)row * N + col] = v;
                }
            }
    } else {
        bf16* C = (bf16*)Cv;
        #pragma unroll
        for (int mt = 0; mt < 2; ++mt)
            #pragma unroll
            for (int i = 0; i < 4; ++i) {
                int row = bm + wr + mt * 16 + q4 * 4 + i;
                #pragma unroll
                for (int nt = 0; nt < 2; ++nt) {
                    int col = bn + wc + nt * 16 + m0;
                    float v = acc[mt][nt][i];
                    if (EPI == 2) v = fmaxf(v, 0.0f);
                    C[(size_t)row * N + col] = __float2bfloat16(v);
                }
            }
    }
}

// ---------------------------------------------------------------- attention
__global__ void attn_kernel(const float* __restrict__ qkv, const bf16* __restrict__ ew,
                            const int* __restrict__ adj, bf16* __restrict__ o) {
    const float* q = qkv;
    const float* k = qkv + (size_t)512 * H_;
    const float* v = qkv + (size_t)1024 * H_;
    int bi = blockIdx.x;           // b*64 + i
    int b  = bi >> 6;
    int ty = threadIdx.y;
    int h  = blockIdx.y * 4 + ty;
    int lane = threadIdx.x;        // 64
    __shared__ float qs[4][64], as[4][64];
    qs[ty][lane] = q[(size_t)bi * H_ + h * 64 + lane];
    __syncthreads();

    int j = lane;
    const float4* k4 = (const float4*)(k + (size_t)(b * 64 + j) * H_ + h * 64);
    const uint4*  w4 = (const uint4*)(ew + ((size_t)bi * 64 + j) * H_ + h * 64);
    float acc = 0.f;
    #pragma unroll
    for (int t = 0; t < 8; ++t) {
        uint4 wu = w4[t];
        float4 ka = k4[2 * t], kb = k4[2 * t + 1];
        float wf[8];
        unpack8(wu, wf);
        const float* qq = &qs[ty][t * 8];
        acc += qq[0] * (ka.x + wf[0]) + qq[1] * (ka.y + wf[1])
             + qq[2] * (ka.z + wf[2]) + qq[3] * (ka.w + wf[3])
             + qq[4] * (kb.x + wf[4]) + qq[5] * (kb.y + wf[5])
             + qq[6] * (kb.z + wf[6]) + qq[7] * (kb.w + wf[7]);
    }
    float logit = acc * INV_SCALE;
    if (adj[(size_t)bi * 64 + j] <= 0) logit = -INFINITY;

    float m = logit;
    #pragma unroll
    for (int off = 32; off; off >>= 1) m = fmaxf(m, __shfl_xor(m, off));
    float p = expf(logit - m);
    float s = p;
    #pragma unroll
    for (int off = 32; off; off >>= 1) s += __shfl_xor(s, off);
    as[ty][lane] = p / s;
    __syncthreads();

    const float* vbase = v + (size_t)(b * 64) * H_ + h * 64;
    float oacc = 0.f;
    int d = lane;
    #pragma unroll 8
    for (int jj = 0; jj < 64; ++jj)
        oacc += as[ty][jj] * vbase[(size_t)jj * H_ + d];
    o[(size_t)bi * H_ + h * 64 + d] = __float2bfloat16(oacc);
}

// ---------------------------------------------------------------- edge update
__global__ void edge_kernel(const bf16* __restrict__ ew, const float* __restrict__ x,
                            bf16* __restrict__ bond) {
    int pair = blockIdx.x * 4 + threadIdx.y;   // (b*64+i)*64 + j
    int b = pair >> 12;
    int i = (pair >> 6) & 63;
    int j = pair & 63;
    int lane = threadIdx.x;
    const uint4*  e4  = (const uint4*)(ew + (size_t)pair * H_);
    const float4* xi4 = (const float4*)(x + (size_t)(b * 64 + i) * H_);
    const float4* xj4 = (const float4*)(x + (size_t)(b * 64 + j) * H_);
    uint4  eu = e4[lane];
    float4 a0 = xi4[lane * 2], a1 = xi4[lane * 2 + 1];
    float4 c0 = xj4[lane * 2], c1 = xj4[lane * 2 + 1];
    float ef[8], af[8], cf[8];
    unpack8(eu, ef);
    af[0] = a0.x; af[1] = a0.y; af[2] = a0.z; af[3] = a0.w;
    af[4] = a1.x; af[5] = a1.y; af[6] = a1.z; af[7] = a1.w;
    cf[0] = c0.x; cf[1] = c0.y; cf[2] = c0.z; cf[3] = c0.w;
    cf[4] = c1.x; cf[5] = c1.y; cf[6] = c1.z; cf[7] = c1.w;
    float s0 = 0.f, s1 = 0.f, s2 = 0.f;
    #pragma unroll
    for (int t = 0; t < 8; ++t) {
        s0 += ef[t] * ef[t]; s1 += ef[t] * af[t]; s2 += ef[t] * cf[t];
    }
    #pragma unroll
    for (int off = 32; off; off >>= 1) {
        s0 += __shfl_xor(s0, off);
        s1 += __shfl_xor(s1, off);
        s2 += __shfl_xor(s2, off);
    }
    float t0 = s0 * INV_SCALE, t1 = s1 * INV_SCALE, t2 = s2 * INV_SCALE;
    float m = fmaxf(t0, fmaxf(t1, t2));
    float e0 = expf(t0 - m), e1 = expf(t1 - m), e2 = expf(t2 - m);
    float inv = 1.0f / (e0 + e1 + e2);
    float w0 = e0 * inv, w1 = e1 * inv, w2 = e2 * inv;
    __align__(16) bf16 ob[8];
    #pragma unroll
    for (int t = 0; t < 8; ++t)
        ob[t] = __float2bfloat16(w0 * ef[t] + w1 * af[t] + w2 * cf[t]);
    *(uint4*)(bond + (size_t)pair * H_ + lane * 8) = *(const uint4*)ob;
}

// ---------------------------------------------------------------- head
// stage 1: clspart[ks][b][c] = sum_{h in kslice} x[b,0,h] * Wout[h][c]
// grid (8 b, 8 cb, 4 ks) x 256 thr: 256 blocks (vs old 8 -> latency hidden)
__global__ void cls_part_kernel(const float* __restrict__ x, const float* __restrict__ Wout,
                                float* __restrict__ clspart) {
    int b  = blockIdx.x;
    int cb = blockIdx.y;
    int ks = blockIdx.z;
    int tid = threadIdx.x;
    int c  = cb * 64 + (tid & 63);
    int kk = tid >> 6;                    // 4 sub-chunks of 32 rows
    const float* xr = x + (size_t)(b * 64) * H_;   // x[b,0,:]
    int h0 = ks * 128 + kk * 32;
    float acc = 0.f;
    #pragma unroll
    for (int h = 0; h < 32; ++h)
        acc += xr[h0 + h] * Wout[(size_t)(h0 + h) * H_ + c];
    __shared__ float red[4][64];
    red[kk][tid & 63] = acc;
    __syncthreads();
    if (tid < 64) {
        float v = red[0][tid] + red[1][tid] + red[2][tid] + red[3][tid];
        clspart[((size_t)ks * 8 + b) * H_ + cb * 64 + tid] = v;
    }
}

// stage 2: cls = tanh(sum_ks clspart); out = softmax(cls @ Wpred + bpred)
__global__ void cls_pred2_kernel(const float* __restrict__ clspart,
                                 const float* __restrict__ Wpred,
                                 const float* __restrict__ bpred,
                                 float* __restrict__ out) {
    int b = blockIdx.x;
    int tid = threadIdx.x;
    __shared__ float red0[4], red1[4];
    float a0 = 0.f, a1 = 0.f;
    #pragma unroll
    for (int t = 0; t < 2; ++t) {
        int c = tid + t * 256;
        float v = clspart[((size_t)0 * 8 + b) * H_ + c]
                + clspart[((size_t)1 * 8 + b) * H_ + c]
                + clspart[((size_t)2 * 8 + b) * H_ + c]
                + clspart[((size_t)3 * 8 + b) * H_ + c];
        float tv = tanhf(v);
        a0 += tv * Wpred[c * 2 + 0];
        a1 += tv * Wpred[c * 2 + 1];
    }
    #pragma unroll
    for (int off = 32; off; off >>= 1) {
        a0 += __shfl_xor(a0, off);
        a1 += __shfl_xor(a1, off);
    }
    int w = tid >> 6;
    if ((tid & 63) == 0) { red0[w] = a0; red1[w] = a1; }
    __syncthreads();
    if (tid == 0) {
        float s0 = red0[0] + red0[1] + red0[2] + red0[3] + bpred[0];
        float s1 = red1[0] + red1[1] + red1[2] + red1[3] + bpred[1];
        float m = fmaxf(s0, s1);
        float e0 = expf(s0 - m), e1 = expf(s1 - m);
        float inv = 1.0f / (e0 + e1);
        out[b * 2 + 0] = e0 * inv;
        out[b * 2 + 1] = e1 * inv;
    }
}

// ---------------------------------------------------------------- launch
extern "C" void kernel_launch(void* const* d_in, const int* in_sizes, int n_in,
                              void* d_out, int out_size, void* d_ws, size_t ws_size,
                              hipStream_t stream) {
    const int*   ids      = (const int*)d_in[0];
    const int*   adj      = (const int*)d_in[1];
    const float* atom_emb = (const float*)d_in[2];
    const float* bond_emb = (const float*)d_in[3];
    const float* Wq     = (const float*)d_in[4];
    const float* Wk     = (const float*)d_in[5];
    const float* Wv     = (const float*)d_in[6];
    const float* Wew    = (const float*)d_in[7];
    const float* Wstack = (const float*)d_in[8];
    const float* Wf1    = (const float*)d_in[9];
    const float* Wf2    = (const float*)d_in[10];
    const float* Wout   = (const float*)d_in[11];
    const float* Wpred  = (const float*)d_in[12];
    const float* bpred  = (const float*)d_in[13];

    char* ws = (char*)d_ws;
    size_t off = 0;
    auto alloc = [&](size_t bytes) {
        size_t o = off;
        off += (bytes + 255) & ~(size_t)255;
        return o;
    };
    const size_t ROWS  = (size_t)B_ * N_;           // 512
    const size_t PAIRS = (size_t)B_ * N_ * N_;      // 32768
    const size_t KN    = (size_t)H_ * H_;           // 262144

    float* x       = (float*)(ws + alloc(ROWS * H_ * 4));
    float* xn      = (float*)(ws + alloc(ROWS * H_ * 4));
    bf16*  xn_bf   = (bf16*) (ws + alloc(ROWS * H_ * 2));
    float* qkv     = (float*)(ws + alloc(3 * ROWS * H_ * 4));
    bf16*  o_bf    = (bf16*) (ws + alloc(ROWS * H_ * 2));
    float* resid   = (float*)(ws + alloc(ROWS * H_ * 4));
    bf16*  ffin_bf = (bf16*) (ws + alloc(ROWS * H_ * 2));
    bf16*  ffh_bf  = (bf16*) (ws + alloc(ROWS * 4 * H_ * 2));
    float* part    = (float*)(ws + alloc(4 * ROWS * H_ * 4));   // split-K partials
    float* clspart = (float*)(ws + alloc(4 * 8 * H_ * 4));      // 64 KB head partials
    bf16*  E0      = (bf16*) (ws + alloc(8 * H_ * 2));          // 8 KB
    bf16*  bond    = (bf16*) (ws + alloc(PAIRS * H_ * 2));      // 32 MB
    bf16*  ew      = (bf16*) (ws + alloc(PAIRS * H_ * 2));      // 32 MB
    bf16*  qkvt    = (bf16*) (ws + alloc((size_t)L_ * 3 * KN * 2));
    bf16*  ewt     = (bf16*) (ws + alloc((size_t)L_ * KN * 2));
    bf16*  stackt  = (bf16*) (ws + alloc((size_t)L_ * KN * 2));
    bf16*  f1t     = (bf16*) (ws + alloc((size_t)L_ * 4 * KN * 2));
    bf16*  f2t     = (bf16*) (ws + alloc((size_t)L_ * 4 * KN * 2));
    (void)ws_size;

    embed_ln_kernel<<<512, 256, 0, stream>>>(ids, atom_emb, xn, xn_bf);

    // one-time weight transpose + bf16 cast (2 launches)
    dim3 tb(32, 8);
    transpose_sq<<<dim3(16, 16, 20), tb, 0, stream>>>(Wq, Wk, Wv, Wew, Wstack,
                                                      qkvt, ewt, stackt);
    transpose_rect<<<dim3(64, 64, 8), tb, 0, stream>>>(Wf1, Wf2, f1t, f2t);

    // layer-0 ew factorization: 8 distinct bond rows -> precompute + gather
    ew0_precompute<<<dim3(8, 8), 64, 0, stream>>>(bond_emb, ewt, E0);
    ew0_gather<<<8192, 256, 0, stream>>>(adj, E0, ew);

    for (int l = 0; l < L_; ++l) {
        // q,k,v fused small-tile: z selects weight slice and output slice
        mfma_gemm_s<0, false><<<dim3(8, 8, 3), 256, 0, stream>>>(
            xn_bf, qkvt + (size_t)l * 3 * KN, qkv, nullptr, 512, 512, 512);
        // ew = bond @ Wew (layers >=1; layer 0 comes from the gather)
        if (l > 0)
            mfma_gemm<3><<<dim3(256, 4), 256, 0, stream>>>(
                bond, ewt + (size_t)l * KN, ew, nullptr, 32768, 512, 512);
        attn_kernel<<<dim3(512, 2), dim3(64, 4), 0, stream>>>(qkv, ew, adj, o_bf);
        // resid = o @ Wstack + xn
        mfma_gemm_s<1, false><<<dim3(8, 8), 256, 0, stream>>>(
            o_bf, stackt + (size_t)l * KN, resid, xn, 512, 512, 512);
        ln_bf_kernel<<<512, 256, 0, stream>>>(resid, ffin_bf);
        // ffh = relu(ffin @ Wf1)
        mfma_gemm_s<2, false><<<dim3(8, 32), 256, 0, stream>>>(
            ffin_bf, f1t + (size_t)l * 4 * KN, ffh_bf, nullptr, 512, 2048, 512);
        // x = ffh @ Wf2 + resid : split-K x4
        mfma_gemm_s<0, true><<<dim3(8, 8, 4), 256, 0, stream>>>(
            ffh_bf, f2t + (size_t)l * 4 * KN, part, nullptr, 512, 512, 2048);
        if (l < L_ - 1)
            reduce_ln_kernel<true><<<512, 256, 0, stream>>>(part, resid, x, xn, xn_bf);
        else
            reduce_ln_kernel<false><<<512, 256, 0, stream>>>(part, resid, x, xn, xn_bf);
        // bond for next layer (last layer's edge output is never read -> skip)
        if (l < L_ - 1)
            edge_kernel<<<8192, dim3(64, 4), 0, stream>>>(ew, x, bond);
    }

    // head: parallel partial GEMV (256 blocks) then tiny reduce+pred
    cls_part_kernel<<<dim3(8, 8, 4), 256, 0, stream>>>(x, Wout, clspart);
    cls_pred2_kernel<<<8, 256, 0, stream>>>(clspart, Wpred, bpred, (float*)d_out);
}

// Round 10
// 500.965 us; speedup vs baseline: 5.3952x; 1.0546x over previous
//
#include <hip/hip_runtime.h>
#include <hip/hip_bf16.h>

typedef __hip_bfloat16 bf16;

// Problem constants
#define B_     8
#define N_     64
#define H_     512
#define HEADS_ 8
#define SP_    64
#define L_     4
static constexpr float INV_SCALE = 0.044194173824159216f; // 1/sqrt(512)

typedef __attribute__((ext_vector_type(8))) short short8;
typedef __attribute__((ext_vector_type(4))) float f32x4;

// async global->LDS, 16B per lane; LDS dest is wave-uniform base + lane*16
__device__ __forceinline__ void gload_lds16(const void* g, void* l) {
    __builtin_amdgcn_global_load_lds(
        (const __attribute__((address_space(1))) unsigned int*)g,
        (__attribute__((address_space(3))) unsigned int*)l, 16, 0, 0);
}

__device__ __forceinline__ void unpack8(uint4 u, float* f) {
    f[0] = __uint_as_float(u.x << 16); f[1] = __uint_as_float(u.x & 0xffff0000u);
    f[2] = __uint_as_float(u.y << 16); f[3] = __uint_as_float(u.y & 0xffff0000u);
    f[4] = __uint_as_float(u.z << 16); f[5] = __uint_as_float(u.z & 0xffff0000u);
    f[6] = __uint_as_float(u.w << 16); f[7] = __uint_as_float(u.w & 0xffff0000u);
}

__device__ __forceinline__ bf16 f2bf(float v) { return __float2bfloat16(v); }

#define BM 128
#define BN 128
#define BK 32
#define RSTR 80   // 64x64-path LDS row stride: 64 B data + 16 pad

// ------------------------------------------------------------ GEMM bodies
// 128x128 tile, async global_load_lds, XOR-swizzled lane map (R8-verified:
// global 64B-contiguous per 4-lane run, LDS 2-way aliasing only).
// EPI: 0 fp32, 1 fp32+R, 2 relu->bf16, 3 bf16
template <int EPI>
__device__ __forceinline__ void gemm128_body(char* lds,
        const bf16* __restrict__ A, const bf16* __restrict__ Bt,
        void* __restrict__ Cv, const float* __restrict__ R,
        int M, int N, int K, int bx, int by) {
    char* As = lds;
    char* Bs = lds + BM * 64;
    const int tid = threadIdx.x;
    const int bm = bx * BM, bn = by * BN;
    const int w = tid >> 6, lane = tid & 63;
    const int wr = (w >> 1) * 64, wc = (w & 1) * 64;
    const int m0 = lane & 15, q4 = lane >> 4;

    f32x4 acc[4][4] = {};

    const int sr = lane >> 2;
    const int scE = (((lane & 3) ^ (sr & 3)) * 8);
    const int fr = m0 * 64 + ((q4 ^ (m0 & 3)) * 16);

    for (int k0 = 0; k0 < K; k0 += BK) {
        __syncthreads();
        #pragma unroll
        for (int t = 0; t < 2; ++t) {
            gload_lds16(A  + (size_t)(bm + w * 32 + t * 16 + sr) * K + k0 + scE,
                        As + (w * 2 + t) * 1024);
            gload_lds16(Bt + (size_t)(bn + w * 32 + t * 16 + sr) * K + k0 + scE,
                        Bs + (w * 2 + t) * 1024);
        }
        __syncthreads();
        short8 af[4], bfr[4];
        #pragma unroll
        for (int t = 0; t < 4; ++t) {
            af[t]  = *(const short8*)(As + (wr / 16 + t) * 1024 + fr);
            bfr[t] = *(const short8*)(Bs + (wc / 16 + t) * 1024 + fr);
        }
        #pragma unroll
        for (int mt = 0; mt < 4; ++mt)
            #pragma unroll
            for (int nt = 0; nt < 4; ++nt)
                acc[mt][nt] = __builtin_amdgcn_mfma_f32_16x16x32_bf16(
                    af[mt], bfr[nt], acc[mt][nt], 0, 0, 0);
    }

    if (EPI <= 1) {
        float* C = (float*)Cv;
        #pragma unroll
        for (int mt = 0; mt < 4; ++mt)
            #pragma unroll
            for (int i = 0; i < 4; ++i) {
                int row = bm + wr + mt * 16 + q4 * 4 + i;
                #pragma unroll
                for (int nt = 0; nt < 4; ++nt) {
                    int col = bn + wc + nt * 16 + m0;
                    float v = acc[mt][nt][i];
                    if (EPI == 1) v += R[(size_t)row * N + col];
                    C[(size_t)row * N + col] = v;
                }
            }
    } else {
        bf16* C = (bf16*)Cv;
        #pragma unroll
        for (int mt = 0; mt < 4; ++mt)
            #pragma unroll
            for (int i = 0; i < 4; ++i) {
                int row = bm + wr + mt * 16 + q4 * 4 + i;
                #pragma unroll
                for (int nt = 0; nt < 4; ++nt) {
                    int col = bn + wc + nt * 16 + m0;
                    float v = acc[mt][nt][i];
                    if (EPI == 2) v = fmaxf(v, 0.0f);
                    C[(size_t)row * N + col] = __float2bfloat16(v);
                }
            }
    }
}

// 64x64 tile, BK=64, RSTR=80 padded LDS (vector-load staging).
template <int EPI>
__device__ __forceinline__ void gemm64_body(char* lds,
        const bf16* __restrict__ A, const bf16* __restrict__ Bt,
        void* __restrict__ Cv, const float* __restrict__ R,
        int M, int N, int K, int bx, int by, int kbeg, int kend) {
    char* As = lds;
    char* Bs = lds + 2 * 64 * RSTR;
    const int tid = threadIdx.x;
    const int bm = bx * 64, bn = by * 64;
    const int w = tid >> 6, lane = tid & 63;
    const int wr = (w >> 1) * 32, wc = (w & 1) * 32;
    const int m0 = lane & 15, q4 = lane >> 4;

    f32x4 acc[2][2] = {};

    const int rA = tid >> 3;
    const int cA = tid & 7;
    const int ksP = cA >> 2;
    const int cB = (cA & 3) * 16;
    const int cE = cA * 8;

    for (int k0 = kbeg; k0 < kend; k0 += 64) {
        uint4 a0 = *(const uint4*)(A  + (size_t)(bm + rA) * K + k0 + cE);
        uint4 a1 = *(const uint4*)(A  + (size_t)(bm + rA + 32) * K + k0 + cE);
        uint4 b0 = *(const uint4*)(Bt + (size_t)(bn + rA) * K + k0 + cE);
        uint4 b1 = *(const uint4*)(Bt + (size_t)(bn + rA + 32) * K + k0 + cE);
        __syncthreads();
        *(uint4*)(As + ksP * (64 * RSTR) + rA * RSTR + cB) = a0;
        *(uint4*)(As + ksP * (64 * RSTR) + (rA + 32) * RSTR + cB) = a1;
        *(uint4*)(Bs + ksP * (64 * RSTR) + rA * RSTR + cB) = b0;
        *(uint4*)(Bs + ksP * (64 * RSTR) + (rA + 32) * RSTR + cB) = b1;
        __syncthreads();
        short8 af[2][2], bfr[2][2];
        #pragma unroll
        for (int ks = 0; ks < 2; ++ks)
            #pragma unroll
            for (int t = 0; t < 2; ++t) {
                af[ks][t]  = *(const short8*)(As + ks * (64 * RSTR) + (wr + t * 16 + m0) * RSTR + q4 * 16);
                bfr[ks][t] = *(const short8*)(Bs + ks * (64 * RSTR) + (wc + t * 16 + m0) * RSTR + q4 * 16);
            }
        #pragma unroll
        for (int ks = 0; ks < 2; ++ks)
            #pragma unroll
            for (int mt = 0; mt < 2; ++mt)
                #pragma unroll
                for (int nt = 0; nt < 2; ++nt)
                    acc[mt][nt] = __builtin_amdgcn_mfma_f32_16x16x32_bf16(
                        af[ks][mt], bfr[ks][nt], acc[mt][nt], 0, 0, 0);
    }

    if (EPI <= 1) {
        float* C = (float*)Cv;
        #pragma unroll
        for (int mt = 0; mt < 2; ++mt)
            #pragma unroll
            for (int i = 0; i < 4; ++i) {
                int row = bm + wr + mt * 16 + q4 * 4 + i;
                #pragma unroll
                for (int nt = 0; nt < 2; ++nt) {
                    int col = bn + wc + nt * 16 + m0;
                    float v = acc[mt][nt][i];
                    if (EPI == 1) v += R[(size_t)row * N + col];
                    C[(size_t)row * N + col] = v;
                }
            }
    } else {
        bf16* C = (bf16*)Cv;
        #pragma unroll
        for (int mt = 0; mt < 2; ++mt)
            #pragma unroll
            for (int i = 0; i < 4; ++i) {
                int row = bm + wr + mt * 16 + q4 * 4 + i;
                #pragma unroll
                for (int nt = 0; nt < 2; ++nt) {
                    int col = bn + wc + nt * 16 + m0;
                    float v = acc[mt][nt][i];
                    if (EPI == 2) v = fmaxf(v, 0.0f);
                    C[(size_t)row * N + col] = __float2bfloat16(v);
                }
            }
    }
}

// ------------------------------------------------------------ GEMM kernels
// combined: blocks [0,1024) = ew 128-tile GEMM; [1024,1216) = fused qkv 64-tile
__launch_bounds__(256)
__global__ void qkv_ew_kernel(const bf16* __restrict__ bond, const bf16* __restrict__ ewt_l,
                              bf16* __restrict__ ew,
                              const bf16* __restrict__ xn_bf, const bf16* __restrict__ qkvt_l,
                              float* __restrict__ qkv) {
    __shared__ __align__(16) char lds[4 * 64 * RSTR];   // 20 KB (max of both paths)
    int blk = blockIdx.x;
    if (blk < 1024) {
        gemm128_body<3>(lds, bond, ewt_l, ew, nullptr, 32768, 512, 512,
                        blk >> 2, blk & 3);
    } else {
        int t = blk - 1024;          // 0..191
        int z = t >> 6;              // qkv slot
        int rem = t & 63;
        gemm64_body<0>(lds, xn_bf, qkvt_l + (size_t)z * 262144,
                       qkv + (size_t)z * 512 * 512, nullptr,
                       512, 512, 512, rem >> 3, rem & 7, 0, 512);
    }
}

// standalone small GEMM. SPLIT: blockIdx.z = K-slice, fp32 partials; else z = B/C slice.
template <int EPI, bool SPLIT>
__launch_bounds__(256)
__global__ void mfma_gemm_s(const bf16* __restrict__ A, const bf16* __restrict__ Bt,
                            void* __restrict__ Cv, const float* __restrict__ R,
                            int M, int N, int K) {
    __shared__ __align__(16) char lds[4 * 64 * RSTR];
    int kbeg = 0, kend = K;
    const bf16* B2 = Bt;
    void* C2 = Cv;
    if (SPLIT) {
        int ks = K / gridDim.z;
        kbeg = blockIdx.z * ks;
        kend = kbeg + ks;
        C2 = (void*)((float*)Cv + (size_t)blockIdx.z * M * N);
        gemm64_body<0>(lds, A, B2, C2, nullptr, M, N, K, blockIdx.x, blockIdx.y, kbeg, kend);
    } else {
        B2 = Bt + (size_t)blockIdx.z * N * K;
        if (EPI <= 1) C2 = (void*)((float*)Cv + (size_t)blockIdx.z * M * N);
        gemm64_body<EPI>(lds, A, B2, C2, R, M, N, K, blockIdx.x, blockIdx.y, kbeg, kend);
    }
}

// ---------------------------------------------------------------- embeddings
__global__ void embed_ln_kernel(const int* __restrict__ ids,
                                const float* __restrict__ emb,
                                float* __restrict__ xn, bf16* __restrict__ xn_bf) {
    int row = blockIdx.x;
    int tid = threadIdx.x;
    const float* r = emb + (size_t)ids[row] * H_;
    float x0 = r[tid], x1 = r[tid + 256];
    float s = x0 + x1, sq = x0 * x0 + x1 * x1;
    #pragma unroll
    for (int off = 32; off; off >>= 1) {
        s  += __shfl_xor(s,  off);
        sq += __shfl_xor(sq, off);
    }
    __shared__ float ls[4], lq[4];
    int w = tid >> 6;
    if ((tid & 63) == 0) { ls[w] = s; lq[w] = sq; }
    __syncthreads();
    float S = ls[0] + ls[1] + ls[2] + ls[3];
    float Q = lq[0] + lq[1] + lq[2] + lq[3];
    float mean = S * (1.0f / H_);
    float var  = Q * (1.0f / H_) - mean * mean;
    float inv  = rsqrtf(var + 1e-5f);
    float y0 = (x0 - mean) * inv, y1 = (x1 - mean) * inv;
    xn[(size_t)row * H_ + tid]       = y0;
    xn[(size_t)row * H_ + tid + 256] = y1;
    xn_bf[(size_t)row * H_ + tid]       = f2bf(y0);
    xn_bf[(size_t)row * H_ + tid + 256] = f2bf(y1);
}

// -------- layer-0 ew factorization: E0[t] = bond_emb[t] @ Wew[0]  (8x512)
__global__ void ew0_precompute(const float* __restrict__ bond_emb,
                               const bf16* __restrict__ ewt0, bf16* __restrict__ E0) {
    int t = blockIdx.x, cb = blockIdx.y, lane = threadIdx.x;
    int c = cb * 64 + lane;
    __shared__ float be[512];
    for (int h = lane; h < 512; h += 64) be[h] = bond_emb[t * 512 + h];
    __syncthreads();
    const bf16* wr = ewt0 + (size_t)c * 512;
    float acc = 0.f;
    for (int h8 = 0; h8 < 64; ++h8) {
        uint4 u = *(const uint4*)(wr + h8 * 8);
        float wf[8];
        unpack8(u, wf);
        const float* b = &be[h8 * 8];
        acc += b[0]*wf[0] + b[1]*wf[1] + b[2]*wf[2] + b[3]*wf[3]
             + b[4]*wf[4] + b[5]*wf[5] + b[6]*wf[6] + b[7]*wf[7];
    }
    E0[t * 512 + c] = f2bf(acc);
}

__global__ void ew0_gather(const int* __restrict__ adj, const bf16* __restrict__ E0,
                           bf16* __restrict__ ew) {
    int gid = blockIdx.x * 256 + threadIdx.x;   // 2,097,152
    int pair = gid >> 6;
    int c    = gid & 63;
    uint4 v = *(const uint4*)(E0 + (size_t)adj[pair] * H_ + c * 8);
    *(uint4*)(ew + (size_t)pair * H_ + c * 8) = v;
}

// ------------------------------------------------- weight transpose + cast
__global__ void transpose_sq(const float* __restrict__ Wq, const float* __restrict__ Wk,
                             const float* __restrict__ Wv, const float* __restrict__ Wew,
                             const float* __restrict__ Wst,
                             bf16* __restrict__ qkvt, bf16* __restrict__ ewt,
                             bf16* __restrict__ stackt) {
    const size_t KN = (size_t)H_ * H_;
    int z = blockIdx.z;
    const float* W; bf16* Wt;
    if (z < 12) {
        int s = z >> 2, l = z & 3;
        W  = (s == 0 ? Wq : s == 1 ? Wk : Wv) + (size_t)l * KN;
        Wt = qkvt + (size_t)l * 3 * KN + (size_t)s * KN;
    } else if (z < 16) {
        int l = z - 12;
        W = Wew + (size_t)l * KN; Wt = ewt + (size_t)l * KN;
    } else {
        int l = z - 16;
        W = Wst + (size_t)l * KN; Wt = stackt + (size_t)l * KN;
    }
    __shared__ float t[32][33];
    int k0 = blockIdx.x * 32, n0 = blockIdx.y * 32;
    int tx = threadIdx.x, ty = threadIdx.y;  // 32, 8
    #pragma unroll
    for (int r = ty; r < 32; r += 8)
        t[r][tx] = W[(size_t)(k0 + r) * H_ + n0 + tx];
    __syncthreads();
    #pragma unroll
    for (int r = ty; r < 32; r += 8)
        Wt[(size_t)(n0 + r) * H_ + k0 + tx] = f2bf(t[tx][r]);
}

__global__ void transpose_rect(const float* __restrict__ Wf1, const float* __restrict__ Wf2,
                               bf16* __restrict__ f1t, bf16* __restrict__ f2t) {
    const size_t KN4 = (size_t)4 * H_ * H_;
    int z = blockIdx.z;
    const float* W; bf16* Wt; int K, N;
    if (z < 4) {
        if (blockIdx.x >= 16) return;          // K=512 -> 16 tiles
        W = Wf1 + (size_t)z * KN4; Wt = f1t + (size_t)z * KN4; K = 512; N = 2048;
    } else {
        if (blockIdx.y >= 16) return;          // N=512 -> 16 tiles
        W = Wf2 + (size_t)(z - 4) * KN4; Wt = f2t + (size_t)(z - 4) * KN4; K = 2048; N = 512;
    }
    __shared__ float t[32][33];
    int k0 = blockIdx.x * 32, n0 = blockIdx.y * 32;
    int tx = threadIdx.x, ty = threadIdx.y;
    #pragma unroll
    for (int r = ty; r < 32; r += 8)
        t[r][tx] = W[(size_t)(k0 + r) * N + n0 + tx];
    __syncthreads();
    #pragma unroll
    for (int r = ty; r < 32; r += 8)
        Wt[(size_t)(n0 + r) * K + k0 + tx] = f2bf(t[tx][r]);
}

// ---------------------- split-K reduce + residual + LN variants
// resid = base + sum_s part[s]; ffin_bf = LN(resid)  (stack GEMM + FF LN fused)
__global__ void reduce_stack_ln(const float* __restrict__ part, const float* __restrict__ base,
                                float* __restrict__ resid, bf16* __restrict__ ffin_bf) {
    const int MN = 512 * H_;
    int row = blockIdx.x;
    int tid = threadIdx.x;
    size_t b0 = (size_t)row * H_;
    float v0 = base[b0 + tid], v1 = base[b0 + tid + 256];
    #pragma unroll
    for (int s = 0; s < 4; ++s) {
        v0 += part[(size_t)s * MN + b0 + tid];
        v1 += part[(size_t)s * MN + b0 + tid + 256];
    }
    resid[b0 + tid] = v0;
    resid[b0 + tid + 256] = v1;
    float s = v0 + v1, sq = v0 * v0 + v1 * v1;
    #pragma unroll
    for (int off = 32; off; off >>= 1) {
        s  += __shfl_xor(s,  off);
        sq += __shfl_xor(sq, off);
    }
    __shared__ float ls[4], lq[4];
    int w = tid >> 6;
    if ((tid & 63) == 0) { ls[w] = s; lq[w] = sq; }
    __syncthreads();
    float S = ls[0] + ls[1] + ls[2] + ls[3];
    float Q = lq[0] + lq[1] + lq[2] + lq[3];
    float mean = S * (1.0f / H_);
    float var  = Q * (1.0f / H_) - mean * mean;
    float inv  = rsqrtf(var + 1e-5f);
    ffin_bf[b0 + tid]       = f2bf((v0 - mean) * inv);
    ffin_bf[b0 + tid + 256] = f2bf((v1 - mean) * inv);
}

// x = resid + sum_s part[s]; if DO_LN also xn, xn_bf = LN(x)
template <bool DO_LN>
__global__ void reduce_ln_kernel(const float* __restrict__ part, const float* __restrict__ resid,
                                 float* __restrict__ x, float* __restrict__ xn,
                                 bf16* __restrict__ xn_bf) {
    const int MN = 512 * H_;
    int row = blockIdx.x;
    int tid = threadIdx.x;
    size_t base = (size_t)row * H_;
    float v0 = resid[base + tid], v1 = resid[base + tid + 256];
    #pragma unroll
    for (int s = 0; s < 4; ++s) {
        v0 += part[(size_t)s * MN + base + tid];
        v1 += part[(size_t)s * MN + base + tid + 256];
    }
    x[base + tid] = v0;
    x[base + tid + 256] = v1;
    if (DO_LN) {
        float s = v0 + v1, sq = v0 * v0 + v1 * v1;
        #pragma unroll
        for (int off = 32; off; off >>= 1) {
            s  += __shfl_xor(s,  off);
            sq += __shfl_xor(sq, off);
        }
        __shared__ float ls[4], lq[4];
        int w = tid >> 6;
        if ((tid & 63) == 0) { ls[w] = s; lq[w] = sq; }
        __syncthreads();
        float S = ls[0] + ls[1] + ls[2] + ls[3];
        float Q = lq[0] + lq[1] + lq[2] + lq[3];
        float mean = S * (1.0f / H_);
        float var  = Q * (1.0f / H_) - mean * mean;
        float inv  = rsqrtf(var + 1e-5f);
        float y0 = (v0 - mean) * inv, y1 = (v1 - mean) * inv;
        xn[base + tid]       = y0;
        xn[base + tid + 256] = y1;
        xn_bf[base + tid]       = f2bf(y0);
        xn_bf[base + tid + 256] = f2bf(y1);
    }
}

// ---------------------------------------------------------------- attention
__global__ void attn_kernel(const float* __restrict__ qkv, const bf16* __restrict__ ew,
                            const int* __restrict__ adj, bf16* __restrict__ o) {
    const float* q = qkv;
    const float* k = qkv + (size_t)512 * H_;
    const float* v = qkv + (size_t)1024 * H_;
    int bi = blockIdx.x;           // b*64 + i
    int b  = bi >> 6;
    int ty = threadIdx.y;
    int h  = blockIdx.y * 4 + ty;
    int lane = threadIdx.x;        // 64
    __shared__ float qs[4][64], as[4][64];
    qs[ty][lane] = q[(size_t)bi * H_ + h * 64 + lane];
    __syncthreads();

    int j = lane;
    const float4* k4 = (const float4*)(k + (size_t)(b * 64 + j) * H_ + h * 64);
    const uint4*  w4 = (const uint4*)(ew + ((size_t)bi * 64 + j) * H_ + h * 64);
    float acc = 0.f;
    #pragma unroll
    for (int t = 0; t < 8; ++t) {
        uint4 wu = w4[t];
        float4 ka = k4[2 * t], kb = k4[2 * t + 1];
        float wf[8];
        unpack8(wu, wf);
        const float* qq = &qs[ty][t * 8];
        acc += qq[0] * (ka.x + wf[0]) + qq[1] * (ka.y + wf[1])
             + qq[2] * (ka.z + wf[2]) + qq[3] * (ka.w + wf[3])
             + qq[4] * (kb.x + wf[4]) + qq[5] * (kb.y + wf[5])
             + qq[6] * (kb.z + wf[6]) + qq[7] * (kb.w + wf[7]);
    }
    float logit = acc * INV_SCALE;
    if (adj[(size_t)bi * 64 + j] <= 0) logit = -INFINITY;

    float m = logit;
    #pragma unroll
    for (int off = 32; off; off >>= 1) m = fmaxf(m, __shfl_xor(m, off));
    float p = expf(logit - m);
    float s = p;
    #pragma unroll
    for (int off = 32; off; off >>= 1) s += __shfl_xor(s, off);
    as[ty][lane] = p / s;
    __syncthreads();

    const float* vbase = v + (size_t)(b * 64) * H_ + h * 64;
    float oacc = 0.f;
    int d = lane;
    #pragma unroll 8
    for (int jj = 0; jj < 64; ++jj)
        oacc += as[ty][jj] * vbase[(size_t)jj * H_ + d];
    o[(size_t)bi * H_ + h * 64 + d] = __float2bfloat16(oacc);
}

// ---------------------------------------------------------------- edge update
__global__ void edge_kernel(const bf16* __restrict__ ew, const float* __restrict__ x,
                            bf16* __restrict__ bond) {
    int pair = blockIdx.x * 4 + threadIdx.y;   // (b*64+i)*64 + j
    int b = pair >> 12;
    int i = (pair >> 6) & 63;
    int j = pair & 63;
    int lane = threadIdx.x;
    const uint4*  e4  = (const uint4*)(ew + (size_t)pair * H_);
    const float4* xi4 = (const float4*)(x + (size_t)(b * 64 + i) * H_);
    const float4* xj4 = (const float4*)(x + (size_t)(b * 64 + j) * H_);
    uint4  eu = e4[lane];
    float4 a0 = xi4[lane * 2], a1 = xi4[lane * 2 + 1];
    float4 c0 = xj4[lane * 2], c1 = xj4[lane * 2 + 1];
    float ef[8], af[8], cf[8];
    unpack8(eu, ef);
    af[0] = a0.x; af[1] = a0.y; af[2] = a0.z; af[3] = a0.w;
    af[4] = a1.x; af[5] = a1.y; af[6] = a1.z; af[7] = a1.w;
    cf[0] = c0.x; cf[1] = c0.y; cf[2] = c0.z; cf[3] = c0.w;
    cf[4] = c1.x; cf[5] = c1.y; cf[6] = c1.z; cf[7] = c1.w;
    float s0 = 0.f, s1 = 0.f, s2 = 0.f;
    #pragma unroll
    for (int t = 0; t < 8; ++t) {
        s0 += ef[t] * ef[t]; s1 += ef[t] * af[t]; s2 += ef[t] * cf[t];
    }
    #pragma unroll
    for (int off = 32; off; off >>= 1) {
        s0 += __shfl_xor(s0, off);
        s1 += __shfl_xor(s1, off);
        s2 += __shfl_xor(s2, off);
    }
    float t0 = s0 * INV_SCALE, t1 = s1 * INV_SCALE, t2 = s2 * INV_SCALE;
    float m = fmaxf(t0, fmaxf(t1, t2));
    float e0 = expf(t0 - m), e1 = expf(t1 - m), e2 = expf(t2 - m);
    float inv = 1.0f / (e0 + e1 + e2);
    float w0 = e0 * inv, w1 = e1 * inv, w2 = e2 * inv;
    __align__(16) bf16 ob[8];
    #pragma unroll
    for (int t = 0; t < 8; ++t)
        ob[t] = __float2bfloat16(w0 * ef[t] + w1 * af[t] + w2 * cf[t]);
    *(uint4*)(bond + (size_t)pair * H_ + lane * 8) = *(const uint4*)ob;
}

// ---------------------------------------------------------------- head
__global__ void cls_part_kernel(const float* __restrict__ x, const float* __restrict__ Wout,
                                float* __restrict__ clspart) {
    int b  = blockIdx.x;
    int cb = blockIdx.y;
    int ks = blockIdx.z;
    int tid = threadIdx.x;
    int c  = cb * 64 + (tid & 63);
    int kk = tid >> 6;
    const float* xr = x + (size_t)(b * 64) * H_;   // x[b,0,:]
    int h0 = ks * 128 + kk * 32;
    float acc = 0.f;
    #pragma unroll
    for (int h = 0; h < 32; ++h)
        acc += xr[h0 + h] * Wout[(size_t)(h0 + h) * H_ + c];
    __shared__ float red[4][64];
    red[kk][tid & 63] = acc;
    __syncthreads();
    if (tid < 64) {
        float v = red[0][tid] + red[1][tid] + red[2][tid] + red[3][tid];
        clspart[((size_t)ks * 8 + b) * H_ + cb * 64 + tid] = v;
    }
}

__global__ void cls_pred2_kernel(const float* __restrict__ clspart,
                                 const float* __restrict__ Wpred,
                                 const float* __restrict__ bpred,
                                 float* __restrict__ out) {
    int b = blockIdx.x;
    int tid = threadIdx.x;
    __shared__ float red0[4], red1[4];
    float a0 = 0.f, a1 = 0.f;
    #pragma unroll
    for (int t = 0; t < 2; ++t) {
        int c = tid + t * 256;
        float v = clspart[((size_t)0 * 8 + b) * H_ + c]
                + clspart[((size_t)1 * 8 + b) * H_ + c]
                + clspart[((size_t)2 * 8 + b) * H_ + c]
                + clspart[((size_t)3 * 8 + b) * H_ + c];
        float tv = tanhf(v);
        a0 += tv * Wpred[c * 2 + 0];
        a1 += tv * Wpred[c * 2 + 1];
    }
    #pragma unroll
    for (int off = 32; off; off >>= 1) {
        a0 += __shfl_xor(a0, off);
        a1 += __shfl_xor(a1, off);
    }
    int w = tid >> 6;
    if ((tid & 63) == 0) { red0[w] = a0; red1[w] = a1; }
    __syncthreads();
    if (tid == 0) {
        float s0 = red0[0] + red0[1] + red0[2] + red0[3] + bpred[0];
        float s1 = red1[0] + red1[1] + red1[2] + red1[3] + bpred[1];
        float m = fmaxf(s0, s1);
        float e0 = expf(s0 - m), e1 = expf(s1 - m);
        float inv = 1.0f / (e0 + e1);
        out[b * 2 + 0] = e0 * inv;
        out[b * 2 + 1] = e1 * inv;
    }
}

// ---------------------------------------------------------------- launch
extern "C" void kernel_launch(void* const* d_in, const int* in_sizes, int n_in,
                              void* d_out, int out_size, void* d_ws, size_t ws_size,
                              hipStream_t stream) {
    const int*   ids      = (const int*)d_in[0];
    const int*   adj      = (const int*)d_in[1];
    const float* atom_emb = (const float*)d_in[2];
    const float* bond_emb = (const float*)d_in[3];
    const float* Wq     = (const float*)d_in[4];
    const float* Wk     = (const float*)d_in[5];
    const float* Wv     = (const float*)d_in[6];
    const float* Wew    = (const float*)d_in[7];
    const float* Wstack = (const float*)d_in[8];
    const float* Wf1    = (const float*)d_in[9];
    const float* Wf2    = (const float*)d_in[10];
    const float* Wout   = (const float*)d_in[11];
    const float* Wpred  = (const float*)d_in[12];
    const float* bpred  = (const float*)d_in[13];

    char* ws = (char*)d_ws;
    size_t off = 0;
    auto alloc = [&](size_t bytes) {
        size_t o = off;
        off += (bytes + 255) & ~(size_t)255;
        return o;
    };
    const size_t ROWS  = (size_t)B_ * N_;           // 512
    const size_t PAIRS = (size_t)B_ * N_ * N_;      // 32768
    const size_t KN    = (size_t)H_ * H_;           // 262144

    float* x       = (float*)(ws + alloc(ROWS * H_ * 4));
    float* xn      = (float*)(ws + alloc(ROWS * H_ * 4));
    bf16*  xn_bf   = (bf16*) (ws + alloc(ROWS * H_ * 2));
    float* qkv     = (float*)(ws + alloc(3 * ROWS * H_ * 4));
    bf16*  o_bf    = (bf16*) (ws + alloc(ROWS * H_ * 2));
    float* resid   = (float*)(ws + alloc(ROWS * H_ * 4));
    bf16*  ffin_bf = (bf16*) (ws + alloc(ROWS * H_ * 2));
    bf16*  ffh_bf  = (bf16*) (ws + alloc(ROWS * 4 * H_ * 2));
    float* part    = (float*)(ws + alloc(4 * ROWS * H_ * 4));   // split-K partials
    float* clspart = (float*)(ws + alloc(4 * 8 * H_ * 4));      // head partials
    bf16*  E0      = (bf16*) (ws + alloc(8 * H_ * 2));
    bf16*  bond    = (bf16*) (ws + alloc(PAIRS * H_ * 2));      // 32 MB
    bf16*  ew      = (bf16*) (ws + alloc(PAIRS * H_ * 2));      // 32 MB
    bf16*  qkvt    = (bf16*) (ws + alloc((size_t)L_ * 3 * KN * 2));
    bf16*  ewt     = (bf16*) (ws + alloc((size_t)L_ * KN * 2));
    bf16*  stackt  = (bf16*) (ws + alloc((size_t)L_ * KN * 2));
    bf16*  f1t     = (bf16*) (ws + alloc((size_t)L_ * 4 * KN * 2));
    bf16*  f2t     = (bf16*) (ws + alloc((size_t)L_ * 4 * KN * 2));
    (void)ws_size;

    embed_ln_kernel<<<512, 256, 0, stream>>>(ids, atom_emb, xn, xn_bf);

    // one-time weight transpose + bf16 cast
    dim3 tb(32, 8);
    transpose_sq<<<dim3(16, 16, 20), tb, 0, stream>>>(Wq, Wk, Wv, Wew, Wstack,
                                                      qkvt, ewt, stackt);
    transpose_rect<<<dim3(64, 64, 8), tb, 0, stream>>>(Wf1, Wf2, f1t, f2t);

    // layer-0 ew factorization: 8 distinct bond rows -> precompute + gather
    ew0_precompute<<<dim3(8, 8), 64, 0, stream>>>(bond_emb, ewt, E0);
    ew0_gather<<<8192, 256, 0, stream>>>(adj, E0, ew);

    for (int l = 0; l < L_; ++l) {
        if (l == 0) {
            // ew comes from the gather; qkv alone
            mfma_gemm_s<0, false><<<dim3(8, 8, 3), 256, 0, stream>>>(
                xn_bf, qkvt, qkv, nullptr, 512, 512, 512);
        } else {
            // combined: ew = bond @ Wew (1024 blocks) + fused qkv (192 blocks)
            qkv_ew_kernel<<<1216, 256, 0, stream>>>(
                bond, ewt + (size_t)l * KN, ew,
                xn_bf, qkvt + (size_t)l * 3 * KN, qkv);
        }
        attn_kernel<<<dim3(512, 2), dim3(64, 4), 0, stream>>>(qkv, ew, adj, o_bf);
        // part = o @ Wstack (split-K x4, 256 blocks)
        mfma_gemm_s<0, true><<<dim3(8, 8, 4), 256, 0, stream>>>(
            o_bf, stackt + (size_t)l * KN, part, nullptr, 512, 512, 512);
        // resid = xn + sum(part); ffin = LN(resid)
        reduce_stack_ln<<<512, 256, 0, stream>>>(part, xn, resid, ffin_bf);
        // ffh = relu(ffin @ Wf1)
        mfma_gemm_s<2, false><<<dim3(8, 32), 256, 0, stream>>>(
            ffin_bf, f1t + (size_t)l * 4 * KN, ffh_bf, nullptr, 512, 2048, 512);
        // part = ffh @ Wf2 (split-K x4)
        mfma_gemm_s<0, true><<<dim3(8, 8, 4), 256, 0, stream>>>(
            ffh_bf, f2t + (size_t)l * 4 * KN, part, nullptr, 512, 512, 2048);
        if (l < L_ - 1)
            reduce_ln_kernel<true><<<512, 256, 0, stream>>>(part, resid, x, xn, xn_bf);
        else
            reduce_ln_kernel<false><<<512, 256, 0, stream>>>(part, resid, x, xn, xn_bf);
        if (l < L_ - 1)
            edge_kernel<<<8192, dim3(64, 4), 0, stream>>>(ew, x, bond);
    }

    cls_part_kernel<<<dim3(8, 8, 4), 256, 0, stream>>>(x, Wout, clspart);
    cls_pred2_kernel<<<8, 256, 0, stream>>>(clspart, Wpred, bpred, (float*)d_out);
}